// Round 3
// baseline (252.314 us; speedup 1.0000x reference)
//
#include <hip/hip_runtime.h>
#include <hip/hip_bf16.h>
#include <math.h>

// Problem constants
#define Bq  2
#define Sq  2048
#define Hq  1024
#define Nq  16
#define HNq 64
#define Mq  (Bq*Sq)        // 4096 rows
#define H3q (3*Hq)         // 3072

#define LOG2E 1.44269504088896340736f

typedef __attribute__((ext_vector_type(8))) short           short8;
typedef __attribute__((ext_vector_type(4))) short           short4s;
typedef __attribute__((ext_vector_type(8))) unsigned short  ushortx8;
typedef __attribute__((ext_vector_type(4))) unsigned short  ushortx4;
typedef __attribute__((ext_vector_type(4))) float           floatx4;

__device__ __forceinline__ unsigned short f2bf(float f) {
    union { float f; unsigned int u; } x; x.f = f;
    unsigned int r = (x.u + 0x7fffu + ((x.u >> 16) & 1u)) >> 16;
    return (unsigned short)r;
}

// packed fp32x2 -> bf16x2 (v_cvt_pk_bf16_f32 on gfx950); a in low 16 bits
__device__ __forceinline__ unsigned int pkbf(float a, float b) {
    float2 t; t.x = a; t.y = b;
    __hip_bfloat162 h = __float22bfloat162_rn(t);
    union { __hip_bfloat162 h; unsigned int u; } c; c.h = h;
    return c.u;
}

__device__ __forceinline__ float bf2f(unsigned short v) {
    union { unsigned int u; float f; } x; x.u = (unsigned int)v << 16;
    return x.f;
}

// async global->LDS, 16B per lane; LDS dest = wave-uniform base + lane*16
__device__ __forceinline__ void gload16(const unsigned short* g, unsigned short* l) {
    __builtin_amdgcn_global_load_lds(
        (__attribute__((address_space(1))) void*)(unsigned long long)(g),
        (__attribute__((address_space(3))) void*)(unsigned int)(unsigned long long)(l),
        16, 0, 0);
}

// LDS bank swizzle: granule' = granule ^ swz(row mod 16); 2-way max conflict
__device__ __forceinline__ int swz(int r) { return (r ^ (r >> 2)) & 3; }

// ---------------------------------------------------------------------------
// Fused fp32 -> bf16 cast for hidden | W_qkv | W_out (contiguous bf16 dst)
// ---------------------------------------------------------------------------
#define N_HID ((size_t)Mq * Hq)          // 4194304
#define N_HW  (N_HID + (size_t)H3q * Hq) // 7340032
#define N_ALL (N_HW + (size_t)Hq * Hq)   // 8388608

__global__ __launch_bounds__(256) void cvt_all(
    const float* __restrict__ hidden, const float* __restrict__ wqkv,
    const float* __restrict__ wout, unsigned short* __restrict__ dst)
{
    size_t i = ((size_t)blockIdx.x * 256 + threadIdx.x) * 8;
    const float* src;
    if (i < N_HID)      src = hidden + i;
    else if (i < N_HW)  src = wqkv + (i - N_HID);
    else                src = wout + (i - N_HW);
    float4 a = *(const float4*)(src);
    float4 b = *(const float4*)(src + 4);
    union { unsigned int u[4]; ushortx8 s; } o;
    o.u[0] = pkbf(a.x, a.y); o.u[1] = pkbf(a.z, a.w);
    o.u[2] = pkbf(b.x, b.y); o.u[3] = pkbf(b.z, b.w);
    *(ushortx8*)(dst + i) = o.s;
}

// em2: e^mask in PERMUTED mf-fragment order so attention's l-MFMA A-fragment
// is a direct 16B load.  em2[((b*32+kt)*2+ks)*32 + quad*8 + hi*4 + r]
//   = exp(mask[b][kt*64 + (2ks+hi)*16 + quad*4 + r])
__global__ __launch_bounds__(256) void cvt_mask(
    const float* __restrict__ mask, unsigned short* __restrict__ em2)
{
    const int t0   = (blockIdx.x * 256 + threadIdx.x) * 8;   // 4096 outputs
    const int b    = t0 >> 11;
    const int t2   = t0 & 2047;
    const int kt   = t2 >> 6;
    const int t3   = t2 & 63;
    const int ks   = t3 >> 5;
    const int quad = (t3 >> 3) & 3;
    const int kb   = kt * 64 + ks * 32 + quad * 4;
    const float* mp = mask + (size_t)b * Sq + kb;
    float4 m0 = *(const float4*)(mp);
    float4 m1 = *(const float4*)(mp + 16);
    union { unsigned int u[4]; ushortx8 s; } o;
    o.u[0] = pkbf(exp2f(m0.x * LOG2E), exp2f(m0.y * LOG2E));
    o.u[1] = pkbf(exp2f(m0.z * LOG2E), exp2f(m0.w * LOG2E));
    o.u[2] = pkbf(exp2f(m1.x * LOG2E), exp2f(m1.y * LOG2E));
    o.u[3] = pkbf(exp2f(m1.z * LOG2E), exp2f(m1.w * LOG2E));
    *(ushortx8*)(em2 + t0) = o.s;
}

// ---------------------------------------------------------------------------
// MFMA GEMM core: 128x128 tile, BK=32, 4 waves each computing 64x64.
// ---------------------------------------------------------------------------
#define TM 128
#define TN 128
#define TK 32

// GEMM1: QKV projection. Outputs:
//   Qb [row][1024]  Q * 0.125*log2e (bf16)
//   Kd [row][1024]  K (bf16), dense rows for contiguous global_load_lds
//   V5 fragment-packed V'^T (e^mask folded): element (b,n,kt32,s,d) at
//     ((b*16+n)*32+kt32)*4096 + (ks*16+dt*4+q2)*128 + dl*8 + hi*4 + r
//     with kg=s>>2, r=s&3, ks=kg>>3, q2=kg&3, hi=(kg>>2)&1, dt=d>>4, dl=d&15.
//   => attention's PV A-fragments are direct 16B loads in final MFMA order.
__global__ __launch_bounds__(256) void gemm_mfma_qkv(
    const unsigned short* __restrict__ A, const unsigned short* __restrict__ Bw,
    const float* __restrict__ bias, const float* __restrict__ mask,
    unsigned short* __restrict__ Qb, unsigned short* __restrict__ Kd,
    unsigned short* __restrict__ V5, int K)
{
    __shared__ unsigned short As[TM][TK];
    __shared__ unsigned short Bs[TN][TK];

    const int tid = threadIdx.x;
    const int w = tid >> 6, lane = tid & 63;
    const int l15 = lane & 15, quad = lane >> 4;
    const int wr = (w & 1) * 64;
    const int wc = (w >> 1) * 64;
    const int row0 = blockIdx.y * TM;
    const int col0 = blockIdx.x * TN;

    const int srow16 = lane >> 2;
    const int sgd    = lane & 3;
    const int sgsrc  = (sgd ^ swz(srow16)) * 8;

    floatx4 acc[4][4];
    #pragma unroll
    for (int i = 0; i < 4; i++)
        #pragma unroll
        for (int j = 0; j < 4; j++) acc[i][j] = (floatx4){0.f,0.f,0.f,0.f};

    const int aswz = swz(l15) * 8;

    for (int k0 = 0; k0 < K; k0 += TK) {
        __syncthreads();
        #pragma unroll
        for (int c = 0; c < 2; c++) {
            int seg = w * 2 + c;
            int r = seg * 16 + srow16;
            gload16(A  + (size_t)(row0 + r) * K + k0 + sgsrc, &As[seg * 16][0]);
            gload16(Bw + (size_t)(col0 + r) * K + k0 + sgsrc, &Bs[seg * 16][0]);
        }
        __syncthreads();

        short8 af[4], bf[4];
        #pragma unroll
        for (int i = 0; i < 4; i++)
            af[i] = *(const short8*)&As[wr + i * 16 + l15][(quad * 8) ^ aswz];
        #pragma unroll
        for (int j = 0; j < 4; j++)
            bf[j] = *(const short8*)&Bs[wc + j * 16 + l15][(quad * 8) ^ aswz];
        #pragma unroll
        for (int i = 0; i < 4; i++)
            #pragma unroll
            for (int j = 0; j < 4; j++)
                acc[i][j] = __builtin_amdgcn_mfma_f32_16x16x32_bf16(af[i], bf[j], acc[i][j], 0, 0, 0);
    }

    const int cls = col0 >> 10;    // 0=Q, 1=K, 2=V; uniform per block

    if (cls == 2) {
        #pragma unroll
        for (int i = 0; i < 4; i++) {
            const int rb = row0 + wr + i * 16 + quad * 4;
            const int b  = rb >> 11;
            const int s  = rb & (Sq - 1);
            const int kt32 = s >> 6;
            const int sw   = s & 63;
            const int kg   = sw >> 2;          // s&3 == 0 (rb % 4 == 0)
            const int ks   = kg >> 3;
            const int q2   = kg & 3;
            const int hi   = (kg >> 2) & 1;
            float expm[4];
            #pragma unroll
            for (int rr = 0; rr < 4; rr++)
                expm[rr] = exp2f(mask[(size_t)b * Sq + s + rr] * LOG2E);
            #pragma unroll
            for (int j = 0; j < 4; j++) {
                const int c  = col0 + wc + j * 16 + l15;
                const int c2 = c - 2 * Hq;           // n*64+d
                const int n  = c2 >> 6, d = c2 & 63;
                const int dt = d >> 4, dl = d & 15;
                const float bia = bias[c];
                ushortx4 o;
                #pragma unroll
                for (int rr = 0; rr < 4; rr++)
                    o[rr] = f2bf((acc[i][j][rr] + bia) * expm[rr]);
                const size_t off = (((size_t)(b * Nq + n) * 32 + kt32) << 12)
                                 + (size_t)((ks * 16 + dt * 4 + q2) * 128 + dl * 8 + hi * 4);
                *(ushortx4*)&V5[off] = o;
            }
        }
    } else {
        unsigned short* __restrict__ dst = (cls == 0) ? Qb : Kd;
        const int cshift = (cls == 0) ? 0 : Hq;
        const float qs = (cls == 0) ? (0.125f * LOG2E) : 1.0f;
        #pragma unroll
        for (int i = 0; i < 4; i++) {
            const int rb = row0 + wr + i * 16 + quad * 4;
            #pragma unroll
            for (int j = 0; j < 4; j++) {
                const int c = col0 + wc + j * 16 + l15;
                const float bia = bias[c];
                #pragma unroll
                for (int rr = 0; rr < 4; rr++)
                    dst[(size_t)(rb + rr) * Hq + (c - cshift)] =
                        f2bf((acc[i][j][rr] + bia) * qs);
            }
        }
    }
}

// GEMM2: x = A*Bw^T + bias + residual -> bf16 (LN reads bf16, stats in fp32)
__global__ __launch_bounds__(256) void gemm_mfma_out(
    const unsigned short* __restrict__ A, const unsigned short* __restrict__ Bw,
    const float* __restrict__ bias, const float* __restrict__ res,
    unsigned short* __restrict__ X, int M, int Nd, int K)
{
    __shared__ unsigned short As[TM][TK];
    __shared__ unsigned short Bs[TN][TK];

    const int tid = threadIdx.x;
    const int w = tid >> 6, lane = tid & 63;
    const int l15 = lane & 15, quad = lane >> 4;
    const int wr = (w & 1) * 64;
    const int wc = (w >> 1) * 64;
    const int row0 = blockIdx.y * TM;
    const int col0 = blockIdx.x * TN;

    const int srow16 = lane >> 2;
    const int sgd    = lane & 3;
    const int sgsrc  = (sgd ^ swz(srow16)) * 8;

    floatx4 acc[4][4];
    #pragma unroll
    for (int i = 0; i < 4; i++)
        #pragma unroll
        for (int j = 0; j < 4; j++) acc[i][j] = (floatx4){0.f,0.f,0.f,0.f};

    const int aswz = swz(l15) * 8;

    for (int k0 = 0; k0 < K; k0 += TK) {
        __syncthreads();
        #pragma unroll
        for (int c = 0; c < 2; c++) {
            int seg = w * 2 + c;
            int r = seg * 16 + srow16;
            gload16(A  + (size_t)(row0 + r) * K + k0 + sgsrc, &As[seg * 16][0]);
            gload16(Bw + (size_t)(col0 + r) * K + k0 + sgsrc, &Bs[seg * 16][0]);
        }
        __syncthreads();

        short8 af[4], bf[4];
        #pragma unroll
        for (int i = 0; i < 4; i++)
            af[i] = *(const short8*)&As[wr + i * 16 + l15][(quad * 8) ^ aswz];
        #pragma unroll
        for (int j = 0; j < 4; j++)
            bf[j] = *(const short8*)&Bs[wc + j * 16 + l15][(quad * 8) ^ aswz];
        #pragma unroll
        for (int i = 0; i < 4; i++)
            #pragma unroll
            for (int j = 0; j < 4; j++)
                acc[i][j] = __builtin_amdgcn_mfma_f32_16x16x32_bf16(af[i], bf[j], acc[i][j], 0, 0, 0);
    }

    #pragma unroll
    for (int i = 0; i < 4; i++) {
        const int rb = row0 + wr + i * 16 + quad * 4;
        #pragma unroll
        for (int j = 0; j < 4; j++) {
            const int c = col0 + wc + j * 16 + l15;
            const float bia = bias[c];
            #pragma unroll
            for (int rr = 0; rr < 4; rr++) {
                X[(size_t)(rb + rr) * Nd + c] =
                    f2bf(acc[i][j][rr] + bia + res[(size_t)(rb + rr) * Nd + c]);
            }
        }
    }
}

// ---------------------------------------------------------------------------
// Grid-split-K MFMA flash attention, z-split x4 (8 tiles/block, 2048 blocks
// => 8 blocks/CU nominal, doubling resident waves vs z=2). Cross-tile
// software pipeline: body(kt) = { wait K(kt) [vmcnt(10)]; barrier; prefetch
// K(kt+1); QK(kt); softmax(kt)->pfW; l+PV(kt-1) from pfR+vf(kt-1); load
// vf(kt) }.
// ---------------------------------------------------------------------------
#define KTILES 8    // 64-key tiles per z-quarter

__device__ __forceinline__ floatx4 mfma16(short8 a, short8 b, floatx4 c) {
    return __builtin_amdgcn_mfma_f32_16x16x32_bf16(a, b, c, 0, 0, 0);
}

// l-MFMA + PV for the PREVIOUS tile (pf/mf/vf all in final fragment order)
__device__ __forceinline__ void do_lpv(
    const short8 (&pf0)[2], const short8 (&pf1)[2], const short8 (&mf)[2],
    const short8 (&vf)[8],
    floatx4 (&oacc0)[4], floatx4 (&oacc1)[4],
    floatx4 &lacc0, floatx4 &lacc1)
{
    __builtin_amdgcn_s_setprio(1);
    lacc0 = mfma16(mf[0], pf0[0], lacc0);
    lacc0 = mfma16(mf[1], pf0[1], lacc0);
    lacc1 = mfma16(mf[0], pf1[0], lacc1);
    lacc1 = mfma16(mf[1], pf1[1], lacc1);
    #pragma unroll
    for (int dt = 0; dt < 4; dt++) {
        oacc0[dt] = mfma16(vf[dt],     pf0[0], oacc0[dt]);
        oacc1[dt] = mfma16(vf[dt],     pf1[0], oacc1[dt]);
        oacc0[dt] = mfma16(vf[4 + dt], pf0[1], oacc0[dt]);
        oacc1[dt] = mfma16(vf[4 + dt], pf1[1], oacc1[dt]);
    }
    __builtin_amdgcn_s_setprio(0);
}

template<bool HAVER, bool PREF, int VWAIT>
__device__ __forceinline__ void attn_body(
    int kt,
    unsigned short (&KsL)[2][64][64],
    const unsigned short* kp, size_t kstep,
    const unsigned short* Vb, const unsigned short* e2b,
    int w, int l15, int quad,
    const short8 (&qf0)[2], const short8 (&qf1)[2],
    short8 (&vf)[8],
    const short8 (&pfR0)[2], const short8 (&pfR1)[2], const short8 (&mfR)[2],
    short8 (&pfW0)[2], short8 (&pfW1)[2], short8 (&mfW)[2],
    floatx4 (&oacc0)[4], floatx4 (&oacc1)[4],
    floatx4 &lacc0, floatx4 &lacc1)
{
    asm volatile("s_waitcnt vmcnt(%0)" :: "i"(VWAIT) : "memory");
    __builtin_amdgcn_s_barrier();
    __builtin_amdgcn_sched_barrier(0);

    const int cur = kt & 1;
    if (PREF) {
        const unsigned short* kpn = kp + (size_t)(kt + 1) * kstep;
        gload16(kpn,                  &KsL[cur ^ 1][w * 16][0]);
        gload16(kpn + (size_t)8 * Hq, &KsL[cur ^ 1][w * 16 + 8][0]);
    }
    __builtin_amdgcn_sched_barrier(0);   // pin K-DMAs as oldest outstanding

    // mf for THIS tile (consumed next body): direct loads, final order
    const unsigned short* ep = e2b + kt * 64;
    mfW[0] = *(const short8*)(ep + quad * 8);
    mfW[1] = *(const short8*)(ep + 32 + quad * 8);

    // ---- QK(kt): S^T = K Q^T for both subtiles
    floatx4 s0[4], s1[4];
    #pragma unroll
    for (int ct = 0; ct < 4; ct++) {
        s0[ct] = (floatx4){0.f,0.f,0.f,0.f};
        s1[ct] = (floatx4){0.f,0.f,0.f,0.f};
    }
    __builtin_amdgcn_s_setprio(1);
    #pragma unroll
    for (int ks = 0; ks < 2; ks++) {
        #pragma unroll
        for (int ct = 0; ct < 4; ct++) {
            short8 af = *(const short8*)&KsL[cur][ct * 16 + l15][((4 * ks + quad) ^ (l15 & 7)) * 8];
            s0[ct] = mfma16(af, qf0[ks], s0[ct]);
            s1[ct] = mfma16(af, qf1[ks], s1[ct]);
        }
    }
    __builtin_amdgcn_s_setprio(0);

    // ---- softmax(kt) -> pfW (exp2-only; mask folded into V'/mf)
    #pragma unroll
    for (int ks = 0; ks < 2; ks++) {
        union { unsigned int u[4]; short8 s; } pk;
        #pragma unroll
        for (int h = 0; h < 2; h++) {
            const int ct = ks * 2 + h;
            pk.u[h * 2]     = pkbf(exp2f(s0[ct][0]), exp2f(s0[ct][1]));
            pk.u[h * 2 + 1] = pkbf(exp2f(s0[ct][2]), exp2f(s0[ct][3]));
        }
        pfW0[ks] = pk.s;
    }
    #pragma unroll
    for (int ks = 0; ks < 2; ks++) {
        union { unsigned int u[4]; short8 s; } pk;
        #pragma unroll
        for (int h = 0; h < 2; h++) {
            const int ct = ks * 2 + h;
            pk.u[h * 2]     = pkbf(exp2f(s1[ct][0]), exp2f(s1[ct][1]));
            pk.u[h * 2 + 1] = pkbf(exp2f(s1[ct][2]), exp2f(s1[ct][3]));
        }
        pfW1[ks] = pk.s;
    }

    // ---- l + PV for tile kt-1 (overlaps the exp2 chain above)
    if (HAVER)
        do_lpv(pfR0, pfR1, mfR, vf, oacc0, oacc1, lacc0, lacc1);

    // ---- vf(kt): direct fragment loads (consumed next body => full cover)
    const unsigned short* vt = Vb + (size_t)kt * 4096 + quad * 128 + l15 * 8;
    vf[0] = *(const short8*)(vt);
    vf[1] = *(const short8*)(vt + 512);
    vf[2] = *(const short8*)(vt + 1024);
    vf[3] = *(const short8*)(vt + 1536);
    vf[4] = *(const short8*)(vt + 2048);
    vf[5] = *(const short8*)(vt + 2560);
    vf[6] = *(const short8*)(vt + 3072);
    vf[7] = *(const short8*)(vt + 3584);
}

__global__ __launch_bounds__(256) void attn_mfma(
    const unsigned short* __restrict__ Qb, const unsigned short* __restrict__ Kd,
    const unsigned short* __restrict__ V5, const unsigned short* __restrict__ em2,
    unsigned short* __restrict__ Opart, float* __restrict__ Lpart)
{
    __shared__ unsigned short Ks[2][64][64];   // [buf][key][d], src-granule swizzled

    const int tid  = threadIdx.x;
    const int w    = tid >> 6;
    const int lane = tid & 63;
    const int l15  = lane & 15;
    const int quad = lane >> 4;

    const int qtile = blockIdx.x;     // 0..15 (128 queries each)
    const int bn    = blockIdx.y;
    const int z     = blockIdx.z;     // 0..3 (512 keys each)
    const int n     = bn & 15;
    const int b     = bn >> 4;

    const int kbase = z * (KTILES * 64);

    // Q B-fragments for both subtiles (n=l15 -> query row, k=quad*8+j)
    short8 qf0[2], qf1[2];
    {
        const int qrow0 = qtile * 128 + w * 16 + l15;
        const unsigned short* qp = Qb + (size_t)(b * Sq + qrow0) * Hq + n * HNq + quad * 8;
        qf0[0] = *(const short8*)(qp);
        qf0[1] = *(const short8*)(qp + 32);
        qp += (size_t)64 * Hq;
        qf1[0] = *(const short8*)(qp);
        qf1[1] = *(const short8*)(qp + 32);
    }

    floatx4 oacc0[4], oacc1[4];   // O^T per subtile: d = dt*16+quad*4+r, q=l15
    #pragma unroll
    for (int dt = 0; dt < 4; dt++) {
        oacc0[dt] = (floatx4){0.f,0.f,0.f,0.f};
        oacc1[dt] = (floatx4){0.f,0.f,0.f,0.f};
    }
    floatx4 lacc0 = (floatx4){0.f,0.f,0.f,0.f};
    floatx4 lacc1 = (floatx4){0.f,0.f,0.f,0.f};

    // K DMA geometry: wave w stages rows w*16..w*16+15 via 2 global_load_lds.
    const int krow8 = lane >> 3;               // 0..7
    const int kgr   = (lane & 7) ^ (krow8 & 7);
    const unsigned short* kp = Kd + (size_t)(b * Sq + kbase + w * 16 + krow8) * Hq
                                  + n * HNq + kgr * 8;
    const size_t kstep = (size_t)64 * Hq;

    // prologue: K tile 0 -> Ks[0]
    gload16(kp,                  &Ks[0][w * 16][0]);
    gload16(kp + (size_t)8 * Hq, &Ks[0][w * 16 + 8][0]);

    // fragment-packed V base + permuted mask base
    const unsigned short* Vb  = V5 + ((size_t)(b * Nq + n) * 32 + z * KTILES) * 4096;
    const unsigned short* e2b = em2 + (size_t)(b * 32 + z * KTILES) * 64;

    // pipeline state (two named stages, no dynamic indexing)
    short8 vf[8];
    short8 pfA0[2], pfA1[2], mfA[2];
    short8 pfB0[2], pfB1[2], mfB[2];

    // peel kt=0: fills stage A + vf(0); no PV yet
    attn_body<false, true, 0>(0, Ks, kp, kstep, Vb, e2b, w, l15, quad,
        qf0, qf1, vf, pfB0, pfB1, mfB, pfA0, pfA1, mfA, oacc0, oacc1, lacc0, lacc1);

    #pragma unroll 1
    for (int kt = 1; kt < KTILES - 1; kt += 2) {
        attn_body<true, true, 10>(kt, Ks, kp, kstep, Vb, e2b, w, l15, quad,
            qf0, qf1, vf, pfA0, pfA1, mfA, pfB0, pfB1, mfB, oacc0, oacc1, lacc0, lacc1);
        attn_body<true, true, 10>(kt + 1, Ks, kp, kstep, Vb, e2b, w, l15, quad,
            qf0, qf1, vf, pfB0, pfB1, mfB, pfA0, pfA1, mfA, oacc0, oacc1, lacc0, lacc1);
    }
    // kt = KTILES-1 (odd): reads A, writes B, no K prefetch
    attn_body<true, false, 10>(KTILES - 1, Ks, kp, kstep, Vb, e2b, w, l15, quad,
        qf0, qf1, vf, pfA0, pfA1, mfA, pfB0, pfB1, mfB, oacc0, oacc1, lacc0, lacc1);
    // drain: l + PV of the last tile (stage B, vf(last))
    do_lpv(pfB0, pfB1, mfB, vf, oacc0, oacc1, lacc0, lacc1);

    // ---- epilogue: un-normalized partial O (bf16) + per-query l (no shfls:
    // every row of lacc holds l_q for q=l15)
    unsigned short* Ow = Opart + (size_t)z * Mq * Hq;
    #pragma unroll
    for (int sub = 0; sub < 2; sub++) {
        const float l_i = sub ? lacc1[0] : lacc0[0];
        const int qrow = qtile * 128 + sub * 64 + w * 16 + l15;
        if (quad == 0)
            Lpart[(size_t)z * Mq * Nq + (size_t)(b * Sq + qrow) * Nq + n] = l_i;
        #pragma unroll
        for (int dt = 0; dt < 4; dt++) {
            const floatx4 oa = sub ? oacc1[dt] : oacc0[dt];
            union { unsigned int u[2]; ushortx4 s; } o;
            o.u[0] = pkbf(oa[0], oa[1]);
            o.u[1] = pkbf(oa[2], oa[3]);
            const int col = n * HNq + dt * 16 + quad * 4;
            *(ushortx4*)&Ow[(size_t)(b * Sq + qrow) * Hq + col] = o.s;
        }
    }
}

// ---------------------------------------------------------------------------
// Merge the four split-K quarters: ctx = (O0+O1+O2+O3) / (l0+l1+l2+l3).
// ---------------------------------------------------------------------------
__global__ __launch_bounds__(256) void attn_merge(
    const unsigned short* __restrict__ Opart, const float* __restrict__ Lpart,
    unsigned short* __restrict__ ctx)
{
    const size_t idx = ((size_t)blockIdx.x * 256 + threadIdx.x) * 4;
    const int row = (int)(idx >> 10);          // b*Sq + s
    const int n   = ((int)idx >> 6) & 15;
    const size_t lidx = (size_t)row * Nq + n;
    const float l = Lpart[lidx]
                  + Lpart[(size_t)Mq * Nq + lidx]
                  + Lpart[2 * (size_t)Mq * Nq + lidx]
                  + Lpart[3 * (size_t)Mq * Nq + lidx];
    const float inv = 1.0f / l;
    ushortx4 a0 = *(const ushortx4*)(Opart + idx);
    ushortx4 a1 = *(const ushortx4*)(Opart + (size_t)Mq * Hq + idx);
    ushortx4 a2 = *(const ushortx4*)(Opart + 2 * (size_t)Mq * Hq + idx);
    ushortx4 a3 = *(const ushortx4*)(Opart + 3 * (size_t)Mq * Hq + idx);
    union { unsigned int u[2]; ushortx4 s; } o;
    o.u[0] = pkbf((bf2f(a0[0]) + bf2f(a1[0]) + bf2f(a2[0]) + bf2f(a3[0])) * inv,
                  (bf2f(a0[1]) + bf2f(a1[1]) + bf2f(a2[1]) + bf2f(a3[1])) * inv);
    o.u[1] = pkbf((bf2f(a0[2]) + bf2f(a1[2]) + bf2f(a2[2]) + bf2f(a3[2])) * inv,
                  (bf2f(a0[3]) + bf2f(a1[3]) + bf2f(a2[3]) + bf2f(a3[3])) * inv);
    *(ushortx4*)(ctx + idx) = o.s;
}

// ---------------------------------------------------------------------------
// Row LayerNorm over H=1024, bf16 input, fp32 stats, fp32 output.
// ---------------------------------------------------------------------------
__global__ __launch_bounds__(256) void ln_kernel(
    const unsigned short* __restrict__ X, const float* __restrict__ gamma,
    const float* __restrict__ beta, float* __restrict__ out)
{
    const int row = blockIdx.x;
    const int c0  = threadIdx.x * 4;
    ushortx4 xv = *(const ushortx4*)(X + (size_t)row * Hq + c0);
    float vals[4];
    float lsum = 0.0f;
    #pragma unroll
    for (int i = 0; i < 4; i++) { vals[i] = bf2f(xv[i]); lsum += vals[i]; }

    __shared__ float red[8];
    const int wid = threadIdx.x >> 6, lane = threadIdx.x & 63;

    float s = lsum;
    #pragma unroll
    for (int off = 32; off >= 1; off >>= 1) s += __shfl_xor(s, off, 64);
    if (lane == 0) red[wid] = s;
    __syncthreads();
    const float mean = (red[0] + red[1] + red[2] + red[3]) * (1.0f / Hq);

    float v = 0.0f;
    #pragma unroll
    for (int i = 0; i < 4; i++) { float d = vals[i] - mean; v += d * d; }
    #pragma unroll
    for (int off = 32; off >= 1; off >>= 1) v += __shfl_xor(v, off, 64);
    if (lane == 0) red[4 + wid] = v;
    __syncthreads();
    const float var  = (red[4] + red[5] + red[6] + red[7]) * (1.0f / Hq);
    const float rstd = rsqrtf(var + 1e-12f);

    float4 gm = *(const float4*)(gamma + c0);
    float4 bt = *(const float4*)(beta + c0);
    float4 o;
    o.x = (vals[0] - mean) * rstd * gm.x + bt.x;
    o.y = (vals[1] - mean) * rstd * gm.y + bt.y;
    o.z = (vals[2] - mean) * rstd * gm.z + bt.z;
    o.w = (vals[3] - mean) * rstd * gm.w + bt.w;
    *(float4*)(out + (size_t)row * Hq + c0) = o;
}

// ---------------------------------------------------------------------------
// Workspace layout (72 MB + eps; dead-buffer aliasing keeps z=4 in budget):
//   [0,4M)    hidden_bf   (dead after GEMM1)  -> reused as ctx_bf by merge
//   [4M,7M)   Wqkv_bf     (dead after GEMM1)  -> reused as Lpart by attn
//   [7M,8M)   Wout_bf     (live through GEMM2)
//   [8M,12M)  Qb
//   [12M,16M) Kd
//   [16M,20M) V5
//   [20M,36M) Opart x4    (dead after merge)  -> part0 reused as x_bf
//   [36M,..)  em2 (8 KB)
// ---------------------------------------------------------------------------
extern "C" void kernel_launch(void* const* d_in, const int* in_sizes, int n_in,
                              void* d_out, int out_size, void* d_ws, size_t ws_size,
                              hipStream_t stream)
{
    const float* hidden = (const float*)d_in[0];
    const float* mask   = (const float*)d_in[1];
    const float* W_qkv  = (const float*)d_in[2];
    const float* b_qkv  = (const float*)d_in[3];
    const float* W_out  = (const float*)d_in[4];
    const float* b_out  = (const float*)d_in[5];
    const float* gamma  = (const float*)d_in[6];
    const float* beta   = (const float*)d_in[7];
    float* out = (float*)d_out;

    const size_t nHid  = (size_t)Mq * Hq;        // 4 M
    const size_t nWq   = (size_t)H3q * Hq;       // 3 M
    const size_t nWo   = (size_t)Hq * Hq;        // 1 M

    unsigned short* hidden_bf = (unsigned short*)d_ws;
    unsigned short* Wqkv_bf   = hidden_bf + nHid;
    unsigned short* Wout_bf   = Wqkv_bf + nWq;
    unsigned short* qb        = Wout_bf + nWo;          // Q  [4096][1024]
    unsigned short* kd        = qb + nHid;              // K  [4096][1024]
    unsigned short* v5        = kd + nHid;              // V' fragment-packed, 4 M
    unsigned short* opart     = v5 + nHid;              // 4 * 4M bf16 = 32 MB
    unsigned short* em2       = opart + 4 * nHid;       // 8 KB

    unsigned short* ctx_bf    = hidden_bf;              // alias (dead after GEMM1)
    float*          lpart     = (float*)Wqkv_bf;        // alias (dead after GEMM1)
    unsigned short* x_bf      = opart;                  // alias (dead after merge)

    dim3 blk(256);

    // 0) fused fp32 -> bf16 cast + permuted expmask table
    cvt_all<<<dim3((int)(N_ALL / 2048)), blk, 0, stream>>>(
        hidden, W_qkv, W_out, hidden_bf);
    cvt_mask<<<dim3(2), blk, 0, stream>>>(mask, em2);

    // 1) QKV projection (MFMA) -> Qb / Kd / V5 (e^mask folded into V')
    gemm_mfma_qkv<<<dim3(H3q / TN, Mq / TM), blk, 0, stream>>>(
        hidden_bf, Wqkv_bf, b_qkv, mask, qb, kd, v5, Hq);

    // 2) Pipelined grid-split-K (x4) MFMA flash attention -> partial O/l
    attn_mfma<<<dim3(Sq / 128, Bq * Nq, 4), blk, 0, stream>>>(
        qb, kd, v5, em2, opart, lpart);

    // 2b) merge quarters -> ctx bf16
    attn_merge<<<dim3((int)(nHid / 1024)), blk, 0, stream>>>(
        opart, lpart, ctx_bf);

    // 3) Output projection (MFMA) + bias + residual -> x bf16
    gemm_mfma_out<<<dim3(Hq / TN, Mq / TM), blk, 0, stream>>>(
        ctx_bf, Wout_bf, b_out, hidden, x_bf, Mq, Hq, Hq);

    // 4) LayerNorm: bf16 x -> fp32 out
    ln_kernel<<<dim3(Mq), blk, 0, stream>>>(x_bf, gamma, beta, out);
}

// Round 4
// 228.413 us; speedup vs baseline: 1.1046x; 1.1046x over previous
//
#include <hip/hip_runtime.h>
#include <hip/hip_bf16.h>
#include <math.h>

// Problem constants
#define Bq  2
#define Sq  2048
#define Hq  1024
#define Nq  16
#define HNq 64
#define Mq  (Bq*Sq)        // 4096 rows
#define H3q (3*Hq)         // 3072

#define LOG2E 1.44269504088896340736f

typedef __attribute__((ext_vector_type(8))) short           short8;
typedef __attribute__((ext_vector_type(4))) short           short4s;
typedef __attribute__((ext_vector_type(8))) unsigned short  ushortx8;
typedef __attribute__((ext_vector_type(4))) unsigned short  ushortx4;
typedef __attribute__((ext_vector_type(4))) float           floatx4;

__device__ __forceinline__ unsigned short f2bf(float f) {
    union { float f; unsigned int u; } x; x.f = f;
    unsigned int r = (x.u + 0x7fffu + ((x.u >> 16) & 1u)) >> 16;
    return (unsigned short)r;
}

// packed fp32x2 -> bf16x2 (v_cvt_pk_bf16_f32 on gfx950); a in low 16 bits
__device__ __forceinline__ unsigned int pkbf(float a, float b) {
    float2 t; t.x = a; t.y = b;
    __hip_bfloat162 h = __float22bfloat162_rn(t);
    union { __hip_bfloat162 h; unsigned int u; } c; c.h = h;
    return c.u;
}

__device__ __forceinline__ float bf2f(unsigned short v) {
    union { unsigned int u; float f; } x; x.u = (unsigned int)v << 16;
    return x.f;
}

// async global->LDS, 16B per lane; LDS dest = wave-uniform base + lane*16
__device__ __forceinline__ void gload16(const unsigned short* g, unsigned short* l) {
    __builtin_amdgcn_global_load_lds(
        (__attribute__((address_space(1))) void*)(unsigned long long)(g),
        (__attribute__((address_space(3))) void*)(unsigned int)(unsigned long long)(l),
        16, 0, 0);
}

// LDS bank swizzle: granule' = granule ^ swz(row mod 16); 2-way max conflict
__device__ __forceinline__ int swz(int r) { return (r ^ (r >> 2)) & 3; }

// ---------------------------------------------------------------------------
// Fused fp32 -> bf16 cast for hidden | W_qkv | W_out (contiguous bf16 dst)
// ---------------------------------------------------------------------------
#define N_HID ((size_t)Mq * Hq)          // 4194304
#define N_HW  (N_HID + (size_t)H3q * Hq) // 7340032
#define N_ALL (N_HW + (size_t)Hq * Hq)   // 8388608

__global__ __launch_bounds__(256) void cvt_all(
    const float* __restrict__ hidden, const float* __restrict__ wqkv,
    const float* __restrict__ wout, unsigned short* __restrict__ dst)
{
    size_t i = ((size_t)blockIdx.x * 256 + threadIdx.x) * 8;
    const float* src;
    if (i < N_HID)      src = hidden + i;
    else if (i < N_HW)  src = wqkv + (i - N_HID);
    else                src = wout + (i - N_HW);
    float4 a = *(const float4*)(src);
    float4 b = *(const float4*)(src + 4);
    union { unsigned int u[4]; ushortx8 s; } o;
    o.u[0] = pkbf(a.x, a.y); o.u[1] = pkbf(a.z, a.w);
    o.u[2] = pkbf(b.x, b.y); o.u[3] = pkbf(b.z, b.w);
    *(ushortx8*)(dst + i) = o.s;
}

// em2: e^mask in PERMUTED mf-fragment order so attention's l-MFMA A-fragment
// is a direct 16B load.  em2[((b*32+kt)*2+ks)*32 + quad*8 + hi*4 + r]
//   = exp(mask[b][kt*64 + (2ks+hi)*16 + quad*4 + r])
__global__ __launch_bounds__(256) void cvt_mask(
    const float* __restrict__ mask, unsigned short* __restrict__ em2)
{
    const int t0   = (blockIdx.x * 256 + threadIdx.x) * 8;   // 4096 outputs
    const int b    = t0 >> 11;
    const int t2   = t0 & 2047;
    const int kt   = t2 >> 6;
    const int t3   = t2 & 63;
    const int ks   = t3 >> 5;
    const int quad = (t3 >> 3) & 3;
    const int kb   = kt * 64 + ks * 32 + quad * 4;
    const float* mp = mask + (size_t)b * Sq + kb;
    float4 m0 = *(const float4*)(mp);
    float4 m1 = *(const float4*)(mp + 16);
    union { unsigned int u[4]; ushortx8 s; } o;
    o.u[0] = pkbf(exp2f(m0.x * LOG2E), exp2f(m0.y * LOG2E));
    o.u[1] = pkbf(exp2f(m0.z * LOG2E), exp2f(m0.w * LOG2E));
    o.u[2] = pkbf(exp2f(m1.x * LOG2E), exp2f(m1.y * LOG2E));
    o.u[3] = pkbf(exp2f(m1.z * LOG2E), exp2f(m1.w * LOG2E));
    *(ushortx8*)(em2 + t0) = o.s;
}

// ---------------------------------------------------------------------------
// MFMA GEMM core: 128x128 tile, BK=32, 4 waves each computing 64x64.
// Double-buffered LDS + single raw barrier per K-step (attn-style pipeline):
// the DMA for step k+1 is issued right after the barrier and waited one full
// compute-step later => staging latency hidden under 16 MFMAs + ds_reads.
// ---------------------------------------------------------------------------
#define TM 128
#define TN 128
#define TK 32

// GEMM1: QKV projection. Outputs:
//   Qb [row][1024]  Q * 0.125*log2e (bf16)
//   Kd [row][1024]  K (bf16), dense rows for contiguous global_load_lds
//   V5 fragment-packed V'^T (e^mask folded): element (b,n,kt32,s,d) at
//     ((b*16+n)*32+kt32)*4096 + (ks*16+dt*4+q2)*128 + dl*8 + hi*4 + r
//     with kg=s>>2, r=s&3, ks=kg>>3, q2=kg&3, hi=(kg>>2)&1, dt=d>>4, dl=d&15.
//   => attention's PV A-fragments are direct 16B loads in final MFMA order.
__global__ __launch_bounds__(256) void gemm_mfma_qkv(
    const unsigned short* __restrict__ A, const unsigned short* __restrict__ Bw,
    const float* __restrict__ bias, const float* __restrict__ mask,
    unsigned short* __restrict__ Qb, unsigned short* __restrict__ Kd,
    unsigned short* __restrict__ V5, int K)
{
    __shared__ unsigned short As[2][TM][TK];
    __shared__ unsigned short Bs[2][TN][TK];

    const int tid = threadIdx.x;
    const int w = tid >> 6, lane = tid & 63;
    const int l15 = lane & 15, quad = lane >> 4;
    const int wr = (w & 1) * 64;
    const int wc = (w >> 1) * 64;
    const int row0 = blockIdx.y * TM;
    const int col0 = blockIdx.x * TN;

    const int srow16 = lane >> 2;
    const int sgd    = lane & 3;
    const int sgsrc  = (sgd ^ swz(srow16)) * 8;

    floatx4 acc[4][4];
    #pragma unroll
    for (int i = 0; i < 4; i++)
        #pragma unroll
        for (int j = 0; j < 4; j++) acc[i][j] = (floatx4){0.f,0.f,0.f,0.f};

    const int aswz = swz(l15) * 8;
    const int NK = K / TK;

    // prologue: stage tile 0 into buffer 0
    #pragma unroll
    for (int c = 0; c < 2; c++) {
        int seg = w * 2 + c;
        int r = seg * 16 + srow16;
        gload16(A  + (size_t)(row0 + r) * K + sgsrc, &As[0][seg * 16][0]);
        gload16(Bw + (size_t)(col0 + r) * K + sgsrc, &Bs[0][seg * 16][0]);
    }

    #pragma unroll 2
    for (int k = 0; k < NK; ++k) {
        asm volatile("s_waitcnt vmcnt(0)" ::: "memory");   // own tile-k DMAs landed
        __builtin_amdgcn_s_barrier();                      // all waves' DMAs landed
        __builtin_amdgcn_sched_barrier(0);

        const int cur = k & 1;
        if (k + 1 < NK) {                                  // prefetch tile k+1
            const int k0n = (k + 1) * TK;
            #pragma unroll
            for (int c = 0; c < 2; c++) {
                int seg = w * 2 + c;
                int r = seg * 16 + srow16;
                gload16(A  + (size_t)(row0 + r) * K + k0n + sgsrc, &As[cur ^ 1][seg * 16][0]);
                gload16(Bw + (size_t)(col0 + r) * K + k0n + sgsrc, &Bs[cur ^ 1][seg * 16][0]);
            }
        }
        __builtin_amdgcn_sched_barrier(0);

        short8 af[4], bf[4];
        #pragma unroll
        for (int i = 0; i < 4; i++)
            af[i] = *(const short8*)&As[cur][wr + i * 16 + l15][(quad * 8) ^ aswz];
        #pragma unroll
        for (int j = 0; j < 4; j++)
            bf[j] = *(const short8*)&Bs[cur][wc + j * 16 + l15][(quad * 8) ^ aswz];
        __builtin_amdgcn_s_setprio(1);
        #pragma unroll
        for (int i = 0; i < 4; i++)
            #pragma unroll
            for (int j = 0; j < 4; j++)
                acc[i][j] = __builtin_amdgcn_mfma_f32_16x16x32_bf16(af[i], bf[j], acc[i][j], 0, 0, 0);
        __builtin_amdgcn_s_setprio(0);
    }

    const int cls = col0 >> 10;    // 0=Q, 1=K, 2=V; uniform per block

    if (cls == 2) {
        #pragma unroll
        for (int i = 0; i < 4; i++) {
            const int rb = row0 + wr + i * 16 + quad * 4;
            const int b  = rb >> 11;
            const int s  = rb & (Sq - 1);
            const int kt32 = s >> 6;
            const int sw   = s & 63;
            const int kg   = sw >> 2;          // s&3 == 0 (rb % 4 == 0)
            const int ks   = kg >> 3;
            const int q2   = kg & 3;
            const int hi   = (kg >> 2) & 1;
            float expm[4];
            #pragma unroll
            for (int rr = 0; rr < 4; rr++)
                expm[rr] = exp2f(mask[(size_t)b * Sq + s + rr] * LOG2E);
            #pragma unroll
            for (int j = 0; j < 4; j++) {
                const int c  = col0 + wc + j * 16 + l15;
                const int c2 = c - 2 * Hq;           // n*64+d
                const int n  = c2 >> 6, d = c2 & 63;
                const int dt = d >> 4, dl = d & 15;
                const float bia = bias[c];
                ushortx4 o;
                #pragma unroll
                for (int rr = 0; rr < 4; rr++)
                    o[rr] = f2bf((acc[i][j][rr] + bia) * expm[rr]);
                const size_t off = (((size_t)(b * Nq + n) * 32 + kt32) << 12)
                                 + (size_t)((ks * 16 + dt * 4 + q2) * 128 + dl * 8 + hi * 4);
                *(ushortx4*)&V5[off] = o;
            }
        }
    } else {
        unsigned short* __restrict__ dst = (cls == 0) ? Qb : Kd;
        const int cshift = (cls == 0) ? 0 : Hq;
        const float qs = (cls == 0) ? (0.125f * LOG2E) : 1.0f;
        #pragma unroll
        for (int i = 0; i < 4; i++) {
            const int rb = row0 + wr + i * 16 + quad * 4;
            #pragma unroll
            for (int j = 0; j < 4; j++) {
                const int c = col0 + wc + j * 16 + l15;
                const float bia = bias[c];
                #pragma unroll
                for (int rr = 0; rr < 4; rr++)
                    dst[(size_t)(rb + rr) * Hq + (c - cshift)] =
                        f2bf((acc[i][j][rr] + bia) * qs);
            }
        }
    }
}

// GEMM2: x = A*Bw^T + bias + residual -> bf16 (LN reads bf16, stats in fp32)
__global__ __launch_bounds__(256) void gemm_mfma_out(
    const unsigned short* __restrict__ A, const unsigned short* __restrict__ Bw,
    const float* __restrict__ bias, const float* __restrict__ res,
    unsigned short* __restrict__ X, int M, int Nd, int K)
{
    __shared__ unsigned short As[2][TM][TK];
    __shared__ unsigned short Bs[2][TN][TK];

    const int tid = threadIdx.x;
    const int w = tid >> 6, lane = tid & 63;
    const int l15 = lane & 15, quad = lane >> 4;
    const int wr = (w & 1) * 64;
    const int wc = (w >> 1) * 64;
    const int row0 = blockIdx.y * TM;
    const int col0 = blockIdx.x * TN;

    const int srow16 = lane >> 2;
    const int sgd    = lane & 3;
    const int sgsrc  = (sgd ^ swz(srow16)) * 8;

    floatx4 acc[4][4];
    #pragma unroll
    for (int i = 0; i < 4; i++)
        #pragma unroll
        for (int j = 0; j < 4; j++) acc[i][j] = (floatx4){0.f,0.f,0.f,0.f};

    const int aswz = swz(l15) * 8;
    const int NK = K / TK;

    #pragma unroll
    for (int c = 0; c < 2; c++) {
        int seg = w * 2 + c;
        int r = seg * 16 + srow16;
        gload16(A  + (size_t)(row0 + r) * K + sgsrc, &As[0][seg * 16][0]);
        gload16(Bw + (size_t)(col0 + r) * K + sgsrc, &Bs[0][seg * 16][0]);
    }

    #pragma unroll 2
    for (int k = 0; k < NK; ++k) {
        asm volatile("s_waitcnt vmcnt(0)" ::: "memory");
        __builtin_amdgcn_s_barrier();
        __builtin_amdgcn_sched_barrier(0);

        const int cur = k & 1;
        if (k + 1 < NK) {
            const int k0n = (k + 1) * TK;
            #pragma unroll
            for (int c = 0; c < 2; c++) {
                int seg = w * 2 + c;
                int r = seg * 16 + srow16;
                gload16(A  + (size_t)(row0 + r) * K + k0n + sgsrc, &As[cur ^ 1][seg * 16][0]);
                gload16(Bw + (size_t)(col0 + r) * K + k0n + sgsrc, &Bs[cur ^ 1][seg * 16][0]);
            }
        }
        __builtin_amdgcn_sched_barrier(0);

        short8 af[4], bf[4];
        #pragma unroll
        for (int i = 0; i < 4; i++)
            af[i] = *(const short8*)&As[cur][wr + i * 16 + l15][(quad * 8) ^ aswz];
        #pragma unroll
        for (int j = 0; j < 4; j++)
            bf[j] = *(const short8*)&Bs[cur][wc + j * 16 + l15][(quad * 8) ^ aswz];
        __builtin_amdgcn_s_setprio(1);
        #pragma unroll
        for (int i = 0; i < 4; i++)
            #pragma unroll
            for (int j = 0; j < 4; j++)
                acc[i][j] = __builtin_amdgcn_mfma_f32_16x16x32_bf16(af[i], bf[j], acc[i][j], 0, 0, 0);
        __builtin_amdgcn_s_setprio(0);
    }

    #pragma unroll
    for (int i = 0; i < 4; i++) {
        const int rb = row0 + wr + i * 16 + quad * 4;
        #pragma unroll
        for (int j = 0; j < 4; j++) {
            const int c = col0 + wc + j * 16 + l15;
            const float bia = bias[c];
            #pragma unroll
            for (int rr = 0; rr < 4; rr++) {
                X[(size_t)(rb + rr) * Nd + c] =
                    f2bf(acc[i][j][rr] + bia + res[(size_t)(rb + rr) * Nd + c]);
            }
        }
    }
}

// ---------------------------------------------------------------------------
// Grid-split-K MFMA flash attention (z=2, round-2 config: measured best).
// Cross-tile software pipeline: body(kt) = { wait K(kt) [vmcnt(10)]; barrier;
// prefetch K(kt+1); QK(kt); softmax(kt)->pfW; l+PV(kt-1) from pfR+vf(kt-1);
// load vf(kt) }.
// ---------------------------------------------------------------------------
#define KTILES 16   // 64-key tiles per z-half

__device__ __forceinline__ floatx4 mfma16(short8 a, short8 b, floatx4 c) {
    return __builtin_amdgcn_mfma_f32_16x16x32_bf16(a, b, c, 0, 0, 0);
}

// l-MFMA + PV for the PREVIOUS tile (pf/mf/vf all in final fragment order)
__device__ __forceinline__ void do_lpv(
    const short8 (&pf0)[2], const short8 (&pf1)[2], const short8 (&mf)[2],
    const short8 (&vf)[8],
    floatx4 (&oacc0)[4], floatx4 (&oacc1)[4],
    floatx4 &lacc0, floatx4 &lacc1)
{
    __builtin_amdgcn_s_setprio(1);
    lacc0 = mfma16(mf[0], pf0[0], lacc0);
    lacc0 = mfma16(mf[1], pf0[1], lacc0);
    lacc1 = mfma16(mf[0], pf1[0], lacc1);
    lacc1 = mfma16(mf[1], pf1[1], lacc1);
    #pragma unroll
    for (int dt = 0; dt < 4; dt++) {
        oacc0[dt] = mfma16(vf[dt],     pf0[0], oacc0[dt]);
        oacc1[dt] = mfma16(vf[dt],     pf1[0], oacc1[dt]);
        oacc0[dt] = mfma16(vf[4 + dt], pf0[1], oacc0[dt]);
        oacc1[dt] = mfma16(vf[4 + dt], pf1[1], oacc1[dt]);
    }
    __builtin_amdgcn_s_setprio(0);
}

template<bool HAVER, bool PREF, int VWAIT>
__device__ __forceinline__ void attn_body(
    int kt,
    unsigned short (&KsL)[2][64][64],
    const unsigned short* kp, size_t kstep,
    const unsigned short* Vb, const unsigned short* e2b,
    int w, int l15, int quad,
    const short8 (&qf0)[2], const short8 (&qf1)[2],
    short8 (&vf)[8],
    const short8 (&pfR0)[2], const short8 (&pfR1)[2], const short8 (&mfR)[2],
    short8 (&pfW0)[2], short8 (&pfW1)[2], short8 (&mfW)[2],
    floatx4 (&oacc0)[4], floatx4 (&oacc1)[4],
    floatx4 &lacc0, floatx4 &lacc1)
{
    asm volatile("s_waitcnt vmcnt(%0)" :: "i"(VWAIT) : "memory");
    __builtin_amdgcn_s_barrier();
    __builtin_amdgcn_sched_barrier(0);

    const int cur = kt & 1;
    if (PREF) {
        const unsigned short* kpn = kp + (size_t)(kt + 1) * kstep;
        gload16(kpn,                  &KsL[cur ^ 1][w * 16][0]);
        gload16(kpn + (size_t)8 * Hq, &KsL[cur ^ 1][w * 16 + 8][0]);
    }
    __builtin_amdgcn_sched_barrier(0);   // pin K-DMAs as oldest outstanding

    // mf for THIS tile (consumed next body): direct loads, final order
    const unsigned short* ep = e2b + kt * 64;
    mfW[0] = *(const short8*)(ep + quad * 8);
    mfW[1] = *(const short8*)(ep + 32 + quad * 8);

    // ---- QK(kt): S^T = K Q^T for both subtiles
    floatx4 s0[4], s1[4];
    #pragma unroll
    for (int ct = 0; ct < 4; ct++) {
        s0[ct] = (floatx4){0.f,0.f,0.f,0.f};
        s1[ct] = (floatx4){0.f,0.f,0.f,0.f};
    }
    __builtin_amdgcn_s_setprio(1);
    #pragma unroll
    for (int ks = 0; ks < 2; ks++) {
        #pragma unroll
        for (int ct = 0; ct < 4; ct++) {
            short8 af = *(const short8*)&KsL[cur][ct * 16 + l15][((4 * ks + quad) ^ (l15 & 7)) * 8];
            s0[ct] = mfma16(af, qf0[ks], s0[ct]);
            s1[ct] = mfma16(af, qf1[ks], s1[ct]);
        }
    }
    __builtin_amdgcn_s_setprio(0);

    // ---- softmax(kt) -> pfW (exp2-only; mask folded into V'/mf)
    #pragma unroll
    for (int ks = 0; ks < 2; ks++) {
        union { unsigned int u[4]; short8 s; } pk;
        #pragma unroll
        for (int h = 0; h < 2; h++) {
            const int ct = ks * 2 + h;
            pk.u[h * 2]     = pkbf(exp2f(s0[ct][0]), exp2f(s0[ct][1]));
            pk.u[h * 2 + 1] = pkbf(exp2f(s0[ct][2]), exp2f(s0[ct][3]));
        }
        pfW0[ks] = pk.s;
    }
    #pragma unroll
    for (int ks = 0; ks < 2; ks++) {
        union { unsigned int u[4]; short8 s; } pk;
        #pragma unroll
        for (int h = 0; h < 2; h++) {
            const int ct = ks * 2 + h;
            pk.u[h * 2]     = pkbf(exp2f(s1[ct][0]), exp2f(s1[ct][1]));
            pk.u[h * 2 + 1] = pkbf(exp2f(s1[ct][2]), exp2f(s1[ct][3]));
        }
        pfW1[ks] = pk.s;
    }

    // ---- l + PV for tile kt-1 (overlaps the exp2 chain above)
    if (HAVER)
        do_lpv(pfR0, pfR1, mfR, vf, oacc0, oacc1, lacc0, lacc1);

    // ---- vf(kt): direct fragment loads (consumed next body => full cover)
    const unsigned short* vt = Vb + (size_t)kt * 4096 + quad * 128 + l15 * 8;
    vf[0] = *(const short8*)(vt);
    vf[1] = *(const short8*)(vt + 512);
    vf[2] = *(const short8*)(vt + 1024);
    vf[3] = *(const short8*)(vt + 1536);
    vf[4] = *(const short8*)(vt + 2048);
    vf[5] = *(const short8*)(vt + 2560);
    vf[6] = *(const short8*)(vt + 3072);
    vf[7] = *(const short8*)(vt + 3584);
}

__global__ __launch_bounds__(256) void attn_mfma(
    const unsigned short* __restrict__ Qb, const unsigned short* __restrict__ Kd,
    const unsigned short* __restrict__ V5, const unsigned short* __restrict__ em2,
    unsigned short* __restrict__ Opart, float* __restrict__ Lpart)
{
    __shared__ unsigned short Ks[2][64][64];   // [buf][key][d], src-granule swizzled

    const int tid  = threadIdx.x;
    const int w    = tid >> 6;
    const int lane = tid & 63;
    const int l15  = lane & 15;
    const int quad = lane >> 4;

    const int qtile = blockIdx.x;     // 0..15 (128 queries each)
    const int bn    = blockIdx.y;
    const int z     = blockIdx.z;
    const int n     = bn & 15;
    const int b     = bn >> 4;

    const int kbase = z * (KTILES * 64);

    // Q B-fragments for both subtiles (n=l15 -> query row, k=quad*8+j)
    short8 qf0[2], qf1[2];
    {
        const int qrow0 = qtile * 128 + w * 16 + l15;
        const unsigned short* qp = Qb + (size_t)(b * Sq + qrow0) * Hq + n * HNq + quad * 8;
        qf0[0] = *(const short8*)(qp);
        qf0[1] = *(const short8*)(qp + 32);
        qp += (size_t)64 * Hq;
        qf1[0] = *(const short8*)(qp);
        qf1[1] = *(const short8*)(qp + 32);
    }

    floatx4 oacc0[4], oacc1[4];   // O^T per subtile: d = dt*16+quad*4+r, q=l15
    #pragma unroll
    for (int dt = 0; dt < 4; dt++) {
        oacc0[dt] = (floatx4){0.f,0.f,0.f,0.f};
        oacc1[dt] = (floatx4){0.f,0.f,0.f,0.f};
    }
    floatx4 lacc0 = (floatx4){0.f,0.f,0.f,0.f};
    floatx4 lacc1 = (floatx4){0.f,0.f,0.f,0.f};

    // K DMA geometry: wave w stages rows w*16..w*16+15 via 2 global_load_lds.
    const int krow8 = lane >> 3;               // 0..7
    const int kgr   = (lane & 7) ^ (krow8 & 7);
    const unsigned short* kp = Kd + (size_t)(b * Sq + kbase + w * 16 + krow8) * Hq
                                  + n * HNq + kgr * 8;
    const size_t kstep = (size_t)64 * Hq;

    // prologue: K tile 0 -> Ks[0]
    gload16(kp,                  &Ks[0][w * 16][0]);
    gload16(kp + (size_t)8 * Hq, &Ks[0][w * 16 + 8][0]);

    // fragment-packed V base + permuted mask base
    const unsigned short* Vb  = V5 + ((size_t)(b * Nq + n) * 32 + z * KTILES) * 4096;
    const unsigned short* e2b = em2 + (size_t)(b * 32 + z * KTILES) * 64;

    // pipeline state (two named stages, no dynamic indexing)
    short8 vf[8];
    short8 pfA0[2], pfA1[2], mfA[2];
    short8 pfB0[2], pfB1[2], mfB[2];

    // peel kt=0: fills stage A + vf(0); no PV yet
    attn_body<false, true, 0>(0, Ks, kp, kstep, Vb, e2b, w, l15, quad,
        qf0, qf1, vf, pfB0, pfB1, mfB, pfA0, pfA1, mfA, oacc0, oacc1, lacc0, lacc1);

    #pragma unroll 1
    for (int kt = 1; kt < KTILES - 1; kt += 2) {
        attn_body<true, true, 10>(kt, Ks, kp, kstep, Vb, e2b, w, l15, quad,
            qf0, qf1, vf, pfA0, pfA1, mfA, pfB0, pfB1, mfB, oacc0, oacc1, lacc0, lacc1);
        attn_body<true, true, 10>(kt + 1, Ks, kp, kstep, Vb, e2b, w, l15, quad,
            qf0, qf1, vf, pfB0, pfB1, mfB, pfA0, pfA1, mfA, oacc0, oacc1, lacc0, lacc1);
    }
    // kt = 15 (odd): reads A, writes B, no K prefetch
    attn_body<true, false, 10>(KTILES - 1, Ks, kp, kstep, Vb, e2b, w, l15, quad,
        qf0, qf1, vf, pfA0, pfA1, mfA, pfB0, pfB1, mfB, oacc0, oacc1, lacc0, lacc1);
    // drain: l + PV of the last tile (stage B, vf(15))
    do_lpv(pfB0, pfB1, mfB, vf, oacc0, oacc1, lacc0, lacc1);

    // ---- epilogue: un-normalized partial O (bf16) + per-query l (no shfls:
    // every row of lacc holds l_q for q=l15)
    unsigned short* Ow = Opart + (size_t)z * Mq * Hq;
    #pragma unroll
    for (int sub = 0; sub < 2; sub++) {
        const float l_i = sub ? lacc1[0] : lacc0[0];
        const int qrow = qtile * 128 + sub * 64 + w * 16 + l15;
        if (quad == 0)
            Lpart[(size_t)z * Mq * Nq + (size_t)(b * Sq + qrow) * Nq + n] = l_i;
        #pragma unroll
        for (int dt = 0; dt < 4; dt++) {
            const floatx4 oa = sub ? oacc1[dt] : oacc0[dt];
            union { unsigned int u[2]; ushortx4 s; } o;
            o.u[0] = pkbf(oa[0], oa[1]);
            o.u[1] = pkbf(oa[2], oa[3]);
            const int col = n * HNq + dt * 16 + quad * 4;
            *(ushortx4*)&Ow[(size_t)(b * Sq + qrow) * Hq + col] = o.s;
        }
    }
}

// ---------------------------------------------------------------------------
// Merge the two split-K halves: ctx = (O0 + O1) / (l0 + l1), bf16 out.
// ---------------------------------------------------------------------------
__global__ __launch_bounds__(256) void attn_merge(
    const unsigned short* __restrict__ Opart, const float* __restrict__ Lpart,
    unsigned short* __restrict__ ctx)
{
    const size_t idx = ((size_t)blockIdx.x * 256 + threadIdx.x) * 4;
    const int row = (int)(idx >> 10);          // b*Sq + s
    const int n   = ((int)idx >> 6) & 15;
    const float l = Lpart[(size_t)row * Nq + n]
                  + Lpart[(size_t)Mq * Nq + (size_t)row * Nq + n];
    const float inv = 1.0f / l;
    ushortx4 a = *(const ushortx4*)(Opart + idx);
    ushortx4 c = *(const ushortx4*)(Opart + (size_t)Mq * Hq + idx);
    union { unsigned int u[2]; ushortx4 s; } o;
    o.u[0] = pkbf((bf2f(a[0]) + bf2f(c[0])) * inv, (bf2f(a[1]) + bf2f(c[1])) * inv);
    o.u[1] = pkbf((bf2f(a[2]) + bf2f(c[2])) * inv, (bf2f(a[3]) + bf2f(c[3])) * inv);
    *(ushortx4*)(ctx + idx) = o.s;
}

// ---------------------------------------------------------------------------
// Row LayerNorm over H=1024, bf16 input, fp32 stats, fp32 output.
// ---------------------------------------------------------------------------
__global__ __launch_bounds__(256) void ln_kernel(
    const unsigned short* __restrict__ X, const float* __restrict__ gamma,
    const float* __restrict__ beta, float* __restrict__ out)
{
    const int row = blockIdx.x;
    const int c0  = threadIdx.x * 4;
    ushortx4 xv = *(const ushortx4*)(X + (size_t)row * Hq + c0);
    float vals[4];
    float lsum = 0.0f;
    #pragma unroll
    for (int i = 0; i < 4; i++) { vals[i] = bf2f(xv[i]); lsum += vals[i]; }

    __shared__ float red[8];
    const int wid = threadIdx.x >> 6, lane = threadIdx.x & 63;

    float s = lsum;
    #pragma unroll
    for (int off = 32; off >= 1; off >>= 1) s += __shfl_xor(s, off, 64);
    if (lane == 0) red[wid] = s;
    __syncthreads();
    const float mean = (red[0] + red[1] + red[2] + red[3]) * (1.0f / Hq);

    float v = 0.0f;
    #pragma unroll
    for (int i = 0; i < 4; i++) { float d = vals[i] - mean; v += d * d; }
    #pragma unroll
    for (int off = 32; off >= 1; off >>= 1) v += __shfl_xor(v, off, 64);
    if (lane == 0) red[4 + wid] = v;
    __syncthreads();
    const float var  = (red[4] + red[5] + red[6] + red[7]) * (1.0f / Hq);
    const float rstd = rsqrtf(var + 1e-12f);

    float4 gm = *(const float4*)(gamma + c0);
    float4 bt = *(const float4*)(beta + c0);
    float4 o;
    o.x = (vals[0] - mean) * rstd * gm.x + bt.x;
    o.y = (vals[1] - mean) * rstd * gm.y + bt.y;
    o.z = (vals[2] - mean) * rstd * gm.z + bt.z;
    o.w = (vals[3] - mean) * rstd * gm.w + bt.w;
    *(float4*)(out + (size_t)row * Hq + c0) = o;
}

// ---------------------------------------------------------------------------
extern "C" void kernel_launch(void* const* d_in, const int* in_sizes, int n_in,
                              void* d_out, int out_size, void* d_ws, size_t ws_size,
                              hipStream_t stream)
{
    const float* hidden = (const float*)d_in[0];
    const float* mask   = (const float*)d_in[1];
    const float* W_qkv  = (const float*)d_in[2];
    const float* b_qkv  = (const float*)d_in[3];
    const float* W_out  = (const float*)d_in[4];
    const float* b_out  = (const float*)d_in[5];
    const float* gamma  = (const float*)d_in[6];
    const float* beta   = (const float*)d_in[7];
    float* out = (float*)d_out;

    const size_t nHid  = (size_t)Mq * Hq;        // 4 M
    const size_t nWq   = (size_t)H3q * Hq;       // 3 M
    const size_t nWo   = (size_t)Hq * Hq;        // 1 M
    const size_t nCtx  = (size_t)Mq * Hq;        // 4 M

    unsigned short* hidden_bf = (unsigned short*)d_ws;
    unsigned short* Wqkv_bf   = hidden_bf + nHid;
    unsigned short* Wout_bf   = Wqkv_bf + nWq;
    unsigned short* qb        = Wout_bf + nWo;          // Q  [4096][1024]
    unsigned short* kd        = qb + nHid;              // K  [4096][1024]
    unsigned short* v5        = kd + nHid;              // V' fragment-packed, 4 M
    unsigned short* ctx_bf    = v5 + nHid;
    unsigned short* x_bf      = ctx_bf + nCtx;
    unsigned short* opart     = x_bf + nHid;            // 2 * 4M bf16 = 16 MB
    float*          lpart     = (float*)(opart + 2 * nHid);  // 2*64K floats
    unsigned short* em2       = (unsigned short*)(lpart + 2 * (size_t)Mq * Nq);

    dim3 blk(256);

    // 0) fused fp32 -> bf16 cast + permuted expmask table
    cvt_all<<<dim3((int)(N_ALL / 2048)), blk, 0, stream>>>(
        hidden, W_qkv, W_out, hidden_bf);
    cvt_mask<<<dim3(2), blk, 0, stream>>>(mask, em2);

    // 1) QKV projection (MFMA, pipelined staging) -> Qb / Kd / V5
    gemm_mfma_qkv<<<dim3(H3q / TN, Mq / TM), blk, 0, stream>>>(
        hidden_bf, Wqkv_bf, b_qkv, mask, qb, kd, v5, Hq);

    // 2) Pipelined grid-split-K MFMA flash attention -> partial O/l
    attn_mfma<<<dim3(Sq / 128, Bq * Nq, 2), blk, 0, stream>>>(
        qb, kd, v5, em2, opart, lpart);

    // 2b) merge halves -> ctx bf16
    attn_merge<<<dim3((int)(nCtx / 1024)), blk, 0, stream>>>(
        opart, lpart, ctx_bf);

    // 3) Output projection (MFMA, pipelined staging) + bias + residual -> x bf16
    gemm_mfma_out<<<dim3(Hq / TN, Mq / TM), blk, 0, stream>>>(
        ctx_bf, Wout_bf, b_out, hidden, x_bf, Mq, Hq, Hq);

    // 4) LayerNorm: bf16 x -> fp32 out
    ln_kernel<<<dim3(Mq), blk, 0, stream>>>(x_bf, gamma, beta, out);
}

// Round 5
// 218.769 us; speedup vs baseline: 1.1533x; 1.0441x over previous
//
#include <hip/hip_runtime.h>
#include <hip/hip_bf16.h>
#include <math.h>

// Problem constants
#define Bq  2
#define Sq  2048
#define Hq  1024
#define Nq  16
#define HNq 64
#define Mq  (Bq*Sq)        // 4096 rows
#define H3q (3*Hq)         // 3072

#define LOG2E 1.44269504088896340736f

typedef __attribute__((ext_vector_type(8))) short           short8;
typedef __attribute__((ext_vector_type(4))) short           short4s;
typedef __attribute__((ext_vector_type(8))) unsigned short  ushortx8;
typedef __attribute__((ext_vector_type(4))) unsigned short  ushortx4;
typedef __attribute__((ext_vector_type(4))) float           floatx4;

__device__ __forceinline__ unsigned short f2bf(float f) {
    union { float f; unsigned int u; } x; x.f = f;
    unsigned int r = (x.u + 0x7fffu + ((x.u >> 16) & 1u)) >> 16;
    return (unsigned short)r;
}

// packed fp32x2 -> bf16x2 (v_cvt_pk_bf16_f32 on gfx950); a in low 16 bits
__device__ __forceinline__ unsigned int pkbf(float a, float b) {
    float2 t; t.x = a; t.y = b;
    __hip_bfloat162 h = __float22bfloat162_rn(t);
    union { __hip_bfloat162 h; unsigned int u; } c; c.h = h;
    return c.u;
}

__device__ __forceinline__ float bf2f(unsigned short v) {
    union { unsigned int u; float f; } x; x.u = (unsigned int)v << 16;
    return x.f;
}

// async global->LDS, 16B per lane; LDS dest = wave-uniform base + lane*16
__device__ __forceinline__ void gload16(const unsigned short* g, unsigned short* l) {
    __builtin_amdgcn_global_load_lds(
        (__attribute__((address_space(1))) void*)(unsigned long long)(g),
        (__attribute__((address_space(3))) void*)(unsigned int)(unsigned long long)(l),
        16, 0, 0);
}

// LDS bank swizzle: granule' = granule ^ swz(row mod 16); 2-way max conflict
__device__ __forceinline__ int swz(int r) { return (r ^ (r >> 2)) & 3; }

// ---------------------------------------------------------------------------
// Fused fp32 -> bf16 cast for hidden | W_qkv | W_out + permuted e^mask table
// (mask blocks appended to the same grid: one fewer launch).
// em2[((b*32+kt)*2+ks)*32 + quad*8 + hi*4 + r]
//   = exp(mask[b][kt*64 + (2ks+hi)*16 + quad*4 + r])
// ---------------------------------------------------------------------------
#define N_HID ((size_t)Mq * Hq)          // 4194304
#define N_HW  (N_HID + (size_t)H3q * Hq) // 7340032
#define N_ALL (N_HW + (size_t)Hq * Hq)   // 8388608
#define CVT_BLKS ((int)(N_ALL / 2048))   // 4096

__global__ __launch_bounds__(256) void cvt_all(
    const float* __restrict__ hidden, const float* __restrict__ wqkv,
    const float* __restrict__ wout, const float* __restrict__ mask,
    unsigned short* __restrict__ dst, unsigned short* __restrict__ em2)
{
    const int bid = blockIdx.x;
    if (bid >= CVT_BLKS) {
        // ---- permuted e^mask table (2 blocks, 4096 outputs)
        const int t0   = ((bid - CVT_BLKS) * 256 + threadIdx.x) * 8;
        const int b    = t0 >> 11;
        const int t2   = t0 & 2047;
        const int kt   = t2 >> 6;
        const int t3   = t2 & 63;
        const int ks   = t3 >> 5;
        const int quad = (t3 >> 3) & 3;
        const int kb   = kt * 64 + ks * 32 + quad * 4;
        const float* mp = mask + (size_t)b * Sq + kb;
        float4 m0 = *(const float4*)(mp);
        float4 m1 = *(const float4*)(mp + 16);
        union { unsigned int u[4]; ushortx8 s; } o;
        o.u[0] = pkbf(exp2f(m0.x * LOG2E), exp2f(m0.y * LOG2E));
        o.u[1] = pkbf(exp2f(m0.z * LOG2E), exp2f(m0.w * LOG2E));
        o.u[2] = pkbf(exp2f(m1.x * LOG2E), exp2f(m1.y * LOG2E));
        o.u[3] = pkbf(exp2f(m1.z * LOG2E), exp2f(m1.w * LOG2E));
        *(ushortx8*)(em2 + t0) = o.s;
        return;
    }
    size_t i = ((size_t)bid * 256 + threadIdx.x) * 8;
    const float* src;
    if (i < N_HID)      src = hidden + i;
    else if (i < N_HW)  src = wqkv + (i - N_HID);
    else                src = wout + (i - N_HW);
    float4 a = *(const float4*)(src);
    float4 b = *(const float4*)(src + 4);
    union { unsigned int u[4]; ushortx8 s; } o;
    o.u[0] = pkbf(a.x, a.y); o.u[1] = pkbf(a.z, a.w);
    o.u[2] = pkbf(b.x, b.y); o.u[3] = pkbf(b.z, b.w);
    *(ushortx8*)(dst + i) = o.s;
}

// ---------------------------------------------------------------------------
// MFMA GEMM core: 128x128 tile, BK=32, 4 waves each computing 64x64.
// TRIPLE-buffered LDS, prefetch depth 2 (T3/T4): at the top of iter k the
// tile-k DMAs are TWO compute bodies old (~matches HBM latency), and the
// wait is counted vmcnt(4) -- tile k+1's loads stay in flight across the
// barrier. Buffer (k+2)%3 overwrite is safe: the barrier is reached only
// after all waves consumed buffer (k-1)%3 into registers.
// ---------------------------------------------------------------------------
#define TM 128
#define TN 128
#define TK 32

// GEMM1: QKV projection. Outputs:
//   Qb [row][1024]  Q * 0.125*log2e (bf16)
//   Kd [row][1024]  K (bf16), dense rows for contiguous global_load_lds
//   V5 fragment-packed V'^T (e^mask folded): element (b,n,kt32,s,d) at
//     ((b*16+n)*32+kt32)*4096 + (ks*16+dt*4+q2)*128 + dl*8 + hi*4 + r
//     with kg=s>>2, r=s&3, ks=kg>>3, q2=kg&3, hi=(kg>>2)&1, dt=d>>4, dl=d&15.
//   => attention's PV A-fragments are direct 16B loads in final MFMA order.
__global__ __launch_bounds__(256) void gemm_mfma_qkv(
    const unsigned short* __restrict__ A, const unsigned short* __restrict__ Bw,
    const float* __restrict__ bias, const float* __restrict__ mask,
    unsigned short* __restrict__ Qb, unsigned short* __restrict__ Kd,
    unsigned short* __restrict__ V5, int K)
{
    __shared__ unsigned short As[3][TM][TK];   // 24 KB
    __shared__ unsigned short Bs[3][TN][TK];   // 24 KB

    const int tid = threadIdx.x;
    const int w = tid >> 6, lane = tid & 63;
    const int l15 = lane & 15, quad = lane >> 4;
    const int wr = (w & 1) * 64;
    const int wc = (w >> 1) * 64;
    const int row0 = blockIdx.y * TM;
    const int col0 = blockIdx.x * TN;

    const int srow16 = lane >> 2;
    const int sgd    = lane & 3;
    const int sgsrc  = (sgd ^ swz(srow16)) * 8;

    floatx4 acc[4][4];
    #pragma unroll
    for (int i = 0; i < 4; i++)
        #pragma unroll
        for (int j = 0; j < 4; j++) acc[i][j] = (floatx4){0.f,0.f,0.f,0.f};

    const int aswz = swz(l15) * 8;
    const int NK = K / TK;

    // prologue: stage tiles 0,1 into buffers 0,1
    #pragma unroll
    for (int t = 0; t < 2; t++) {
        #pragma unroll
        for (int c = 0; c < 2; c++) {
            int seg = w * 2 + c;
            int r = seg * 16 + srow16;
            gload16(A  + (size_t)(row0 + r) * K + t * TK + sgsrc, &As[t][seg * 16][0]);
            gload16(Bw + (size_t)(col0 + r) * K + t * TK + sgsrc, &Bs[t][seg * 16][0]);
        }
    }

    #pragma unroll 1
    for (int k = 0; k < NK; ++k) {
        if (k + 1 < NK) asm volatile("s_waitcnt vmcnt(4)" ::: "memory");
        else            asm volatile("s_waitcnt vmcnt(0)" ::: "memory");
        __builtin_amdgcn_s_barrier();
        __builtin_amdgcn_sched_barrier(0);

        const int cur = k % 3;
        if (k + 2 < NK) {                                  // prefetch tile k+2
            const int nb  = (k + 2) % 3;
            const int k0n = (k + 2) * TK;
            #pragma unroll
            for (int c = 0; c < 2; c++) {
                int seg = w * 2 + c;
                int r = seg * 16 + srow16;
                gload16(A  + (size_t)(row0 + r) * K + k0n + sgsrc, &As[nb][seg * 16][0]);
                gload16(Bw + (size_t)(col0 + r) * K + k0n + sgsrc, &Bs[nb][seg * 16][0]);
            }
        }
        __builtin_amdgcn_sched_barrier(0);

        short8 af[4], bf[4];
        #pragma unroll
        for (int i = 0; i < 4; i++)
            af[i] = *(const short8*)&As[cur][wr + i * 16 + l15][(quad * 8) ^ aswz];
        #pragma unroll
        for (int j = 0; j < 4; j++)
            bf[j] = *(const short8*)&Bs[cur][wc + j * 16 + l15][(quad * 8) ^ aswz];
        __builtin_amdgcn_s_setprio(1);
        #pragma unroll
        for (int i = 0; i < 4; i++)
            #pragma unroll
            for (int j = 0; j < 4; j++)
                acc[i][j] = __builtin_amdgcn_mfma_f32_16x16x32_bf16(af[i], bf[j], acc[i][j], 0, 0, 0);
        __builtin_amdgcn_s_setprio(0);
    }

    const int cls = col0 >> 10;    // 0=Q, 1=K, 2=V; uniform per block

    if (cls == 2) {
        #pragma unroll
        for (int i = 0; i < 4; i++) {
            const int rb = row0 + wr + i * 16 + quad * 4;
            const int b  = rb >> 11;
            const int s  = rb & (Sq - 1);
            const int kt32 = s >> 6;
            const int sw   = s & 63;
            const int kg   = sw >> 2;          // s&3 == 0 (rb % 4 == 0)
            const int ks   = kg >> 3;
            const int q2   = kg & 3;
            const int hi   = (kg >> 2) & 1;
            float expm[4];
            #pragma unroll
            for (int rr = 0; rr < 4; rr++)
                expm[rr] = exp2f(mask[(size_t)b * Sq + s + rr] * LOG2E);
            #pragma unroll
            for (int j = 0; j < 4; j++) {
                const int c  = col0 + wc + j * 16 + l15;
                const int c2 = c - 2 * Hq;           // n*64+d
                const int n  = c2 >> 6, d = c2 & 63;
                const int dt = d >> 4, dl = d & 15;
                const float bia = bias[c];
                ushortx4 o;
                #pragma unroll
                for (int rr = 0; rr < 4; rr++)
                    o[rr] = f2bf((acc[i][j][rr] + bia) * expm[rr]);
                const size_t off = (((size_t)(b * Nq + n) * 32 + kt32) << 12)
                                 + (size_t)((ks * 16 + dt * 4 + q2) * 128 + dl * 8 + hi * 4);
                *(ushortx4*)&V5[off] = o;
            }
        }
    } else {
        unsigned short* __restrict__ dst = (cls == 0) ? Qb : Kd;
        const int cshift = (cls == 0) ? 0 : Hq;
        const float qs = (cls == 0) ? (0.125f * LOG2E) : 1.0f;
        #pragma unroll
        for (int i = 0; i < 4; i++) {
            const int rb = row0 + wr + i * 16 + quad * 4;
            #pragma unroll
            for (int j = 0; j < 4; j++) {
                const int c = col0 + wc + j * 16 + l15;
                const float bia = bias[c];
                #pragma unroll
                for (int rr = 0; rr < 4; rr++)
                    dst[(size_t)(rb + rr) * Hq + (c - cshift)] =
                        f2bf((acc[i][j][rr] + bia) * qs);
            }
        }
    }
}

// GEMM2: x = A*Bw^T + bias + residual -> bf16 (LN reads bf16, stats in fp32)
__global__ __launch_bounds__(256) void gemm_mfma_out(
    const unsigned short* __restrict__ A, const unsigned short* __restrict__ Bw,
    const float* __restrict__ bias, const float* __restrict__ res,
    unsigned short* __restrict__ X, int M, int Nd, int K)
{
    __shared__ unsigned short As[3][TM][TK];
    __shared__ unsigned short Bs[3][TN][TK];

    const int tid = threadIdx.x;
    const int w = tid >> 6, lane = tid & 63;
    const int l15 = lane & 15, quad = lane >> 4;
    const int wr = (w & 1) * 64;
    const int wc = (w >> 1) * 64;
    const int row0 = blockIdx.y * TM;
    const int col0 = blockIdx.x * TN;

    const int srow16 = lane >> 2;
    const int sgd    = lane & 3;
    const int sgsrc  = (sgd ^ swz(srow16)) * 8;

    floatx4 acc[4][4];
    #pragma unroll
    for (int i = 0; i < 4; i++)
        #pragma unroll
        for (int j = 0; j < 4; j++) acc[i][j] = (floatx4){0.f,0.f,0.f,0.f};

    const int aswz = swz(l15) * 8;
    const int NK = K / TK;

    #pragma unroll
    for (int t = 0; t < 2; t++) {
        #pragma unroll
        for (int c = 0; c < 2; c++) {
            int seg = w * 2 + c;
            int r = seg * 16 + srow16;
            gload16(A  + (size_t)(row0 + r) * K + t * TK + sgsrc, &As[t][seg * 16][0]);
            gload16(Bw + (size_t)(col0 + r) * K + t * TK + sgsrc, &Bs[t][seg * 16][0]);
        }
    }

    #pragma unroll 1
    for (int k = 0; k < NK; ++k) {
        if (k + 1 < NK) asm volatile("s_waitcnt vmcnt(4)" ::: "memory");
        else            asm volatile("s_waitcnt vmcnt(0)" ::: "memory");
        __builtin_amdgcn_s_barrier();
        __builtin_amdgcn_sched_barrier(0);

        const int cur = k % 3;
        if (k + 2 < NK) {
            const int nb  = (k + 2) % 3;
            const int k0n = (k + 2) * TK;
            #pragma unroll
            for (int c = 0; c < 2; c++) {
                int seg = w * 2 + c;
                int r = seg * 16 + srow16;
                gload16(A  + (size_t)(row0 + r) * K + k0n + sgsrc, &As[nb][seg * 16][0]);
                gload16(Bw + (size_t)(col0 + r) * K + k0n + sgsrc, &Bs[nb][seg * 16][0]);
            }
        }
        __builtin_amdgcn_sched_barrier(0);

        short8 af[4], bf[4];
        #pragma unroll
        for (int i = 0; i < 4; i++)
            af[i] = *(const short8*)&As[cur][wr + i * 16 + l15][(quad * 8) ^ aswz];
        #pragma unroll
        for (int j = 0; j < 4; j++)
            bf[j] = *(const short8*)&Bs[cur][wc + j * 16 + l15][(quad * 8) ^ aswz];
        __builtin_amdgcn_s_setprio(1);
        #pragma unroll
        for (int i = 0; i < 4; i++)
            #pragma unroll
            for (int j = 0; j < 4; j++)
                acc[i][j] = __builtin_amdgcn_mfma_f32_16x16x32_bf16(af[i], bf[j], acc[i][j], 0, 0, 0);
        __builtin_amdgcn_s_setprio(0);
    }

    #pragma unroll
    for (int i = 0; i < 4; i++) {
        const int rb = row0 + wr + i * 16 + quad * 4;
        #pragma unroll
        for (int j = 0; j < 4; j++) {
            const int c = col0 + wc + j * 16 + l15;
            const float bia = bias[c];
            #pragma unroll
            for (int rr = 0; rr < 4; rr++) {
                X[(size_t)(rb + rr) * Nd + c] =
                    f2bf(acc[i][j][rr] + bia + res[(size_t)(rb + rr) * Nd + c]);
            }
        }
    }
}

// ---------------------------------------------------------------------------
// Grid-split-K MFMA flash attention (z=2, round-2 config: measured best).
// Cross-tile software pipeline: body(kt) = { wait K(kt) [vmcnt(10)]; barrier;
// prefetch K(kt+1); QK(kt); softmax(kt)->pfW; l+PV(kt-1) from pfR+vf(kt-1);
// load vf(kt) }.
// ---------------------------------------------------------------------------
#define KTILES 16   // 64-key tiles per z-half

__device__ __forceinline__ floatx4 mfma16(short8 a, short8 b, floatx4 c) {
    return __builtin_amdgcn_mfma_f32_16x16x32_bf16(a, b, c, 0, 0, 0);
}

// l-MFMA + PV for the PREVIOUS tile (pf/mf/vf all in final fragment order)
__device__ __forceinline__ void do_lpv(
    const short8 (&pf0)[2], const short8 (&pf1)[2], const short8 (&mf)[2],
    const short8 (&vf)[8],
    floatx4 (&oacc0)[4], floatx4 (&oacc1)[4],
    floatx4 &lacc0, floatx4 &lacc1)
{
    __builtin_amdgcn_s_setprio(1);
    lacc0 = mfma16(mf[0], pf0[0], lacc0);
    lacc0 = mfma16(mf[1], pf0[1], lacc0);
    lacc1 = mfma16(mf[0], pf1[0], lacc1);
    lacc1 = mfma16(mf[1], pf1[1], lacc1);
    #pragma unroll
    for (int dt = 0; dt < 4; dt++) {
        oacc0[dt] = mfma16(vf[dt],     pf0[0], oacc0[dt]);
        oacc1[dt] = mfma16(vf[dt],     pf1[0], oacc1[dt]);
        oacc0[dt] = mfma16(vf[4 + dt], pf0[1], oacc0[dt]);
        oacc1[dt] = mfma16(vf[4 + dt], pf1[1], oacc1[dt]);
    }
    __builtin_amdgcn_s_setprio(0);
}

template<bool HAVER, bool PREF, int VWAIT>
__device__ __forceinline__ void attn_body(
    int kt,
    unsigned short (&KsL)[2][64][64],
    const unsigned short* kp, size_t kstep,
    const unsigned short* Vb, const unsigned short* e2b,
    int w, int l15, int quad,
    const short8 (&qf0)[2], const short8 (&qf1)[2],
    short8 (&vf)[8],
    const short8 (&pfR0)[2], const short8 (&pfR1)[2], const short8 (&mfR)[2],
    short8 (&pfW0)[2], short8 (&pfW1)[2], short8 (&mfW)[2],
    floatx4 (&oacc0)[4], floatx4 (&oacc1)[4],
    floatx4 &lacc0, floatx4 &lacc1)
{
    asm volatile("s_waitcnt vmcnt(%0)" :: "i"(VWAIT) : "memory");
    __builtin_amdgcn_s_barrier();
    __builtin_amdgcn_sched_barrier(0);

    const int cur = kt & 1;
    if (PREF) {
        const unsigned short* kpn = kp + (size_t)(kt + 1) * kstep;
        gload16(kpn,                  &KsL[cur ^ 1][w * 16][0]);
        gload16(kpn + (size_t)8 * Hq, &KsL[cur ^ 1][w * 16 + 8][0]);
    }
    __builtin_amdgcn_sched_barrier(0);   // pin K-DMAs as oldest outstanding

    // mf for THIS tile (consumed next body): direct loads, final order
    const unsigned short* ep = e2b + kt * 64;
    mfW[0] = *(const short8*)(ep + quad * 8);
    mfW[1] = *(const short8*)(ep + 32 + quad * 8);

    // ---- QK(kt): S^T = K Q^T for both subtiles
    floatx4 s0[4], s1[4];
    #pragma unroll
    for (int ct = 0; ct < 4; ct++) {
        s0[ct] = (floatx4){0.f,0.f,0.f,0.f};
        s1[ct] = (floatx4){0.f,0.f,0.f,0.f};
    }
    __builtin_amdgcn_s_setprio(1);
    #pragma unroll
    for (int ks = 0; ks < 2; ks++) {
        #pragma unroll
        for (int ct = 0; ct < 4; ct++) {
            short8 af = *(const short8*)&KsL[cur][ct * 16 + l15][((4 * ks + quad) ^ (l15 & 7)) * 8];
            s0[ct] = mfma16(af, qf0[ks], s0[ct]);
            s1[ct] = mfma16(af, qf1[ks], s1[ct]);
        }
    }
    __builtin_amdgcn_s_setprio(0);

    // ---- softmax(kt) -> pfW (exp2-only; mask folded into V'/mf)
    #pragma unroll
    for (int ks = 0; ks < 2; ks++) {
        union { unsigned int u[4]; short8 s; } pk;
        #pragma unroll
        for (int h = 0; h < 2; h++) {
            const int ct = ks * 2 + h;
            pk.u[h * 2]     = pkbf(exp2f(s0[ct][0]), exp2f(s0[ct][1]));
            pk.u[h * 2 + 1] = pkbf(exp2f(s0[ct][2]), exp2f(s0[ct][3]));
        }
        pfW0[ks] = pk.s;
    }
    #pragma unroll
    for (int ks = 0; ks < 2; ks++) {
        union { unsigned int u[4]; short8 s; } pk;
        #pragma unroll
        for (int h = 0; h < 2; h++) {
            const int ct = ks * 2 + h;
            pk.u[h * 2]     = pkbf(exp2f(s1[ct][0]), exp2f(s1[ct][1]));
            pk.u[h * 2 + 1] = pkbf(exp2f(s1[ct][2]), exp2f(s1[ct][3]));
        }
        pfW1[ks] = pk.s;
    }

    // ---- l + PV for tile kt-1 (overlaps the exp2 chain above)
    if (HAVER)
        do_lpv(pfR0, pfR1, mfR, vf, oacc0, oacc1, lacc0, lacc1);

    // ---- vf(kt): direct fragment loads (consumed next body => full cover)
    const unsigned short* vt = Vb + (size_t)kt * 4096 + quad * 128 + l15 * 8;
    vf[0] = *(const short8*)(vt);
    vf[1] = *(const short8*)(vt + 512);
    vf[2] = *(const short8*)(vt + 1024);
    vf[3] = *(const short8*)(vt + 1536);
    vf[4] = *(const short8*)(vt + 2048);
    vf[5] = *(const short8*)(vt + 2560);
    vf[6] = *(const short8*)(vt + 3072);
    vf[7] = *(const short8*)(vt + 3584);
}

__global__ __launch_bounds__(256) void attn_mfma(
    const unsigned short* __restrict__ Qb, const unsigned short* __restrict__ Kd,
    const unsigned short* __restrict__ V5, const unsigned short* __restrict__ em2,
    unsigned short* __restrict__ Opart, float* __restrict__ Lpart)
{
    __shared__ unsigned short Ks[2][64][64];   // [buf][key][d], src-granule swizzled

    const int tid  = threadIdx.x;
    const int w    = tid >> 6;
    const int lane = tid & 63;
    const int l15  = lane & 15;
    const int quad = lane >> 4;

    const int qtile = blockIdx.x;     // 0..15 (128 queries each)
    const int bn    = blockIdx.y;
    const int z     = blockIdx.z;
    const int n     = bn & 15;
    const int b     = bn >> 4;

    const int kbase = z * (KTILES * 64);

    // Q B-fragments for both subtiles (n=l15 -> query row, k=quad*8+j)
    short8 qf0[2], qf1[2];
    {
        const int qrow0 = qtile * 128 + w * 16 + l15;
        const unsigned short* qp = Qb + (size_t)(b * Sq + qrow0) * Hq + n * HNq + quad * 8;
        qf0[0] = *(const short8*)(qp);
        qf0[1] = *(const short8*)(qp + 32);
        qp += (size_t)64 * Hq;
        qf1[0] = *(const short8*)(qp);
        qf1[1] = *(const short8*)(qp + 32);
    }

    floatx4 oacc0[4], oacc1[4];   // O^T per subtile: d = dt*16+quad*4+r, q=l15
    #pragma unroll
    for (int dt = 0; dt < 4; dt++) {
        oacc0[dt] = (floatx4){0.f,0.f,0.f,0.f};
        oacc1[dt] = (floatx4){0.f,0.f,0.f,0.f};
    }
    floatx4 lacc0 = (floatx4){0.f,0.f,0.f,0.f};
    floatx4 lacc1 = (floatx4){0.f,0.f,0.f,0.f};

    // K DMA geometry: wave w stages rows w*16..w*16+15 via 2 global_load_lds.
    const int krow8 = lane >> 3;               // 0..7
    const int kgr   = (lane & 7) ^ (krow8 & 7);
    const unsigned short* kp = Kd + (size_t)(b * Sq + kbase + w * 16 + krow8) * Hq
                                  + n * HNq + kgr * 8;
    const size_t kstep = (size_t)64 * Hq;

    // prologue: K tile 0 -> Ks[0]
    gload16(kp,                  &Ks[0][w * 16][0]);
    gload16(kp + (size_t)8 * Hq, &Ks[0][w * 16 + 8][0]);

    // fragment-packed V base + permuted mask base
    const unsigned short* Vb  = V5 + ((size_t)(b * Nq + n) * 32 + z * KTILES) * 4096;
    const unsigned short* e2b = em2 + (size_t)(b * 32 + z * KTILES) * 64;

    // pipeline state (two named stages, no dynamic indexing)
    short8 vf[8];
    short8 pfA0[2], pfA1[2], mfA[2];
    short8 pfB0[2], pfB1[2], mfB[2];

    // peel kt=0: fills stage A + vf(0); no PV yet
    attn_body<false, true, 0>(0, Ks, kp, kstep, Vb, e2b, w, l15, quad,
        qf0, qf1, vf, pfB0, pfB1, mfB, pfA0, pfA1, mfA, oacc0, oacc1, lacc0, lacc1);

    #pragma unroll 1
    for (int kt = 1; kt < KTILES - 1; kt += 2) {
        attn_body<true, true, 10>(kt, Ks, kp, kstep, Vb, e2b, w, l15, quad,
            qf0, qf1, vf, pfA0, pfA1, mfA, pfB0, pfB1, mfB, oacc0, oacc1, lacc0, lacc1);
        attn_body<true, true, 10>(kt + 1, Ks, kp, kstep, Vb, e2b, w, l15, quad,
            qf0, qf1, vf, pfB0, pfB1, mfB, pfA0, pfA1, mfA, oacc0, oacc1, lacc0, lacc1);
    }
    // kt = 15 (odd): reads A, writes B, no K prefetch
    attn_body<true, false, 10>(KTILES - 1, Ks, kp, kstep, Vb, e2b, w, l15, quad,
        qf0, qf1, vf, pfA0, pfA1, mfA, pfB0, pfB1, mfB, oacc0, oacc1, lacc0, lacc1);
    // drain: l + PV of the last tile (stage B, vf(15))
    do_lpv(pfB0, pfB1, mfB, vf, oacc0, oacc1, lacc0, lacc1);

    // ---- epilogue: un-normalized partial O (bf16) + per-query l (no shfls:
    // every row of lacc holds l_q for q=l15)
    unsigned short* Ow = Opart + (size_t)z * Mq * Hq;
    #pragma unroll
    for (int sub = 0; sub < 2; sub++) {
        const float l_i = sub ? lacc1[0] : lacc0[0];
        const int qrow = qtile * 128 + sub * 64 + w * 16 + l15;
        if (quad == 0)
            Lpart[(size_t)z * Mq * Nq + (size_t)(b * Sq + qrow) * Nq + n] = l_i;
        #pragma unroll
        for (int dt = 0; dt < 4; dt++) {
            const floatx4 oa = sub ? oacc1[dt] : oacc0[dt];
            union { unsigned int u[2]; ushortx4 s; } o;
            o.u[0] = pkbf(oa[0], oa[1]);
            o.u[1] = pkbf(oa[2], oa[3]);
            const int col = n * HNq + dt * 16 + quad * 4;
            *(ushortx4*)&Ow[(size_t)(b * Sq + qrow) * Hq + col] = o.s;
        }
    }
}

// ---------------------------------------------------------------------------
// Merge the two split-K halves: ctx = (O0 + O1) / (l0 + l1), bf16 out.
// ---------------------------------------------------------------------------
__global__ __launch_bounds__(256) void attn_merge(
    const unsigned short* __restrict__ Opart, const float* __restrict__ Lpart,
    unsigned short* __restrict__ ctx)
{
    const size_t idx = ((size_t)blockIdx.x * 256 + threadIdx.x) * 4;
    const int row = (int)(idx >> 10);          // b*Sq + s
    const int n   = ((int)idx >> 6) & 15;
    const float l = Lpart[(size_t)row * Nq + n]
                  + Lpart[(size_t)Mq * Nq + (size_t)row * Nq + n];
    const float inv = 1.0f / l;
    ushortx4 a = *(const ushortx4*)(Opart + idx);
    ushortx4 c = *(const ushortx4*)(Opart + (size_t)Mq * Hq + idx);
    union { unsigned int u[2]; ushortx4 s; } o;
    o.u[0] = pkbf((bf2f(a[0]) + bf2f(c[0])) * inv, (bf2f(a[1]) + bf2f(c[1])) * inv);
    o.u[1] = pkbf((bf2f(a[2]) + bf2f(c[2])) * inv, (bf2f(a[3]) + bf2f(c[3])) * inv);
    *(ushortx4*)(ctx + idx) = o.s;
}

// ---------------------------------------------------------------------------
// Row LayerNorm over H=1024, bf16 input, fp32 stats, fp32 output.
// ---------------------------------------------------------------------------
__global__ __launch_bounds__(256) void ln_kernel(
    const unsigned short* __restrict__ X, const float* __restrict__ gamma,
    const float* __restrict__ beta, float* __restrict__ out)
{
    const int row = blockIdx.x;
    const int c0  = threadIdx.x * 4;
    ushortx4 xv = *(const ushortx4*)(X + (size_t)row * Hq + c0);
    float vals[4];
    float lsum = 0.0f;
    #pragma unroll
    for (int i = 0; i < 4; i++) { vals[i] = bf2f(xv[i]); lsum += vals[i]; }

    __shared__ float red[8];
    const int wid = threadIdx.x >> 6, lane = threadIdx.x & 63;

    float s = lsum;
    #pragma unroll
    for (int off = 32; off >= 1; off >>= 1) s += __shfl_xor(s, off, 64);
    if (lane == 0) red[wid] = s;
    __syncthreads();
    const float mean = (red[0] + red[1] + red[2] + red[3]) * (1.0f / Hq);

    float v = 0.0f;
    #pragma unroll
    for (int i = 0; i < 4; i++) { float d = vals[i] - mean; v += d * d; }
    #pragma unroll
    for (int off = 32; off >= 1; off >>= 1) v += __shfl_xor(v, off, 64);
    if (lane == 0) red[4 + wid] = v;
    __syncthreads();
    const float var  = (red[4] + red[5] + red[6] + red[7]) * (1.0f / Hq);
    const float rstd = rsqrtf(var + 1e-12f);

    float4 gm = *(const float4*)(gamma + c0);
    float4 bt = *(const float4*)(beta + c0);
    float4 o;
    o.x = (vals[0] - mean) * rstd * gm.x + bt.x;
    o.y = (vals[1] - mean) * rstd * gm.y + bt.y;
    o.z = (vals[2] - mean) * rstd * gm.z + bt.z;
    o.w = (vals[3] - mean) * rstd * gm.w + bt.w;
    *(float4*)(out + (size_t)row * Hq + c0) = o;
}

// ---------------------------------------------------------------------------
extern "C" void kernel_launch(void* const* d_in, const int* in_sizes, int n_in,
                              void* d_out, int out_size, void* d_ws, size_t ws_size,
                              hipStream_t stream)
{
    const float* hidden = (const float*)d_in[0];
    const float* mask   = (const float*)d_in[1];
    const float* W_qkv  = (const float*)d_in[2];
    const float* b_qkv  = (const float*)d_in[3];
    const float* W_out  = (const float*)d_in[4];
    const float* b_out  = (const float*)d_in[5];
    const float* gamma  = (const float*)d_in[6];
    const float* beta   = (const float*)d_in[7];
    float* out = (float*)d_out;

    const size_t nHid  = (size_t)Mq * Hq;        // 4 M
    const size_t nWq   = (size_t)H3q * Hq;       // 3 M
    const size_t nWo   = (size_t)Hq * Hq;        // 1 M
    const size_t nCtx  = (size_t)Mq * Hq;        // 4 M

    unsigned short* hidden_bf = (unsigned short*)d_ws;
    unsigned short* Wqkv_bf   = hidden_bf + nHid;
    unsigned short* Wout_bf   = Wqkv_bf + nWq;
    unsigned short* qb        = Wout_bf + nWo;          // Q  [4096][1024]
    unsigned short* kd        = qb + nHid;              // K  [4096][1024]
    unsigned short* v5        = kd + nHid;              // V' fragment-packed, 4 M
    unsigned short* ctx_bf    = v5 + nHid;
    unsigned short* x_bf      = ctx_bf + nCtx;
    unsigned short* opart     = x_bf + nHid;            // 2 * 4M bf16 = 16 MB
    float*          lpart     = (float*)(opart + 2 * nHid);  // 2*64K floats
    unsigned short* em2       = (unsigned short*)(lpart + 2 * (size_t)Mq * Nq);

    dim3 blk(256);

    // 0) fused fp32 -> bf16 cast + permuted expmask table (one kernel)
    cvt_all<<<dim3(CVT_BLKS + 2), blk, 0, stream>>>(
        hidden, W_qkv, W_out, mask, hidden_bf, em2);

    // 1) QKV projection (MFMA, depth-2 pipelined staging) -> Qb / Kd / V5
    gemm_mfma_qkv<<<dim3(H3q / TN, Mq / TM), blk, 0, stream>>>(
        hidden_bf, Wqkv_bf, b_qkv, mask, qb, kd, v5, Hq);

    // 2) Pipelined grid-split-K MFMA flash attention -> partial O/l
    attn_mfma<<<dim3(Sq / 128, Bq * Nq, 2), blk, 0, stream>>>(
        qb, kd, v5, em2, opart, lpart);

    // 2b) merge halves -> ctx bf16
    attn_merge<<<dim3((int)(nCtx / 1024)), blk, 0, stream>>>(
        opart, lpart, ctx_bf);

    // 3) Output projection (MFMA, depth-2 pipelined staging) + residual -> x bf16
    gemm_mfma_out<<<dim3(Hq / TN, Mq / TM), blk, 0, stream>>>(
        ctx_bf, Wout_bf, b_out, hidden, x_bf, Mq, Hq, Hq);

    // 4) LayerNorm: bf16 x -> fp32 out
    ln_kernel<<<dim3(Mq), blk, 0, stream>>>(x_bf, gamma, beta, out);
}

// Round 6
// 205.178 us; speedup vs baseline: 1.2297x; 1.0662x over previous
//
#include <hip/hip_runtime.h>
#include <hip/hip_bf16.h>
#include <math.h>

// Problem constants
#define Bq  2
#define Sq  2048
#define Hq  1024
#define Nq  16
#define HNq 64
#define Mq  (Bq*Sq)        // 4096 rows
#define H3q (3*Hq)         // 3072

#define LOG2E 1.44269504088896340736f

typedef __attribute__((ext_vector_type(8))) short           short8;
typedef __attribute__((ext_vector_type(4))) short           short4s;
typedef __attribute__((ext_vector_type(8))) unsigned short  ushortx8;
typedef __attribute__((ext_vector_type(4))) unsigned short  ushortx4;
typedef __attribute__((ext_vector_type(4))) float           floatx4;

__device__ __forceinline__ unsigned short f2bf(float f) {
    union { float f; unsigned int u; } x; x.f = f;
    unsigned int r = (x.u + 0x7fffu + ((x.u >> 16) & 1u)) >> 16;
    return (unsigned short)r;
}

// packed fp32x2 -> bf16x2 (v_cvt_pk_bf16_f32 on gfx950); a in low 16 bits
__device__ __forceinline__ unsigned int pkbf(float a, float b) {
    float2 t; t.x = a; t.y = b;
    __hip_bfloat162 h = __float22bfloat162_rn(t);
    union { __hip_bfloat162 h; unsigned int u; } c; c.h = h;
    return c.u;
}

__device__ __forceinline__ float bf2f(unsigned short v) {
    union { unsigned int u; float f; } x; x.u = (unsigned int)v << 16;
    return x.f;
}

// raw v_exp_f32 (D = 2^S0): ONE transcendental op. libm exp2f without
// fast-math expands to a guarded ~10-op sequence -- that was the hidden
// VALU hog (32 calls/wave/tile in attn).
__device__ __forceinline__ float fexp2(float x) {
    float r;
    asm("v_exp_f32 %0, %1" : "=v"(r) : "v"(x));
    return r;
}

// async global->LDS, 16B per lane; LDS dest = wave-uniform base + lane*16
__device__ __forceinline__ void gload16(const unsigned short* g, unsigned short* l) {
    __builtin_amdgcn_global_load_lds(
        (__attribute__((address_space(1))) void*)(unsigned long long)(g),
        (__attribute__((address_space(3))) void*)(unsigned int)(unsigned long long)(l),
        16, 0, 0);
}

// LDS bank swizzle: granule' = granule ^ swz(row mod 16); 2-way max conflict
__device__ __forceinline__ int swz(int r) { return (r ^ (r >> 2)) & 3; }

// ---------------------------------------------------------------------------
// Fused fp32 -> bf16 cast for hidden | W_qkv | W_out + permuted e^mask table
// (mask blocks appended to the same grid: one fewer launch).
// em2[((b*32+kt)*2+ks)*32 + quad*8 + hi*4 + r]
//   = exp(mask[b][kt*64 + (2ks+hi)*16 + quad*4 + r])
// ---------------------------------------------------------------------------
#define N_HID ((size_t)Mq * Hq)          // 4194304
#define N_HW  (N_HID + (size_t)H3q * Hq) // 7340032
#define N_ALL (N_HW + (size_t)Hq * Hq)   // 8388608
#define CVT_BLKS ((int)(N_ALL / 2048))   // 4096

__global__ __launch_bounds__(256) void cvt_all(
    const float* __restrict__ hidden, const float* __restrict__ wqkv,
    const float* __restrict__ wout, const float* __restrict__ mask,
    unsigned short* __restrict__ dst, unsigned short* __restrict__ em2)
{
    const int bid = blockIdx.x;
    if (bid >= CVT_BLKS) {
        // ---- permuted e^mask table (2 blocks, 4096 outputs)
        const int t0   = ((bid - CVT_BLKS) * 256 + threadIdx.x) * 8;
        const int b    = t0 >> 11;
        const int t2   = t0 & 2047;
        const int kt   = t2 >> 6;
        const int t3   = t2 & 63;
        const int ks   = t3 >> 5;
        const int quad = (t3 >> 3) & 3;
        const int kb   = kt * 64 + ks * 32 + quad * 4;
        const float* mp = mask + (size_t)b * Sq + kb;
        float4 m0 = *(const float4*)(mp);
        float4 m1 = *(const float4*)(mp + 16);
        union { unsigned int u[4]; ushortx8 s; } o;
        o.u[0] = pkbf(fexp2(m0.x * LOG2E), fexp2(m0.y * LOG2E));
        o.u[1] = pkbf(fexp2(m0.z * LOG2E), fexp2(m0.w * LOG2E));
        o.u[2] = pkbf(fexp2(m1.x * LOG2E), fexp2(m1.y * LOG2E));
        o.u[3] = pkbf(fexp2(m1.z * LOG2E), fexp2(m1.w * LOG2E));
        *(ushortx8*)(em2 + t0) = o.s;
        return;
    }
    size_t i = ((size_t)bid * 256 + threadIdx.x) * 8;
    const float* src;
    if (i < N_HID)      src = hidden + i;
    else if (i < N_HW)  src = wqkv + (i - N_HID);
    else                src = wout + (i - N_HW);
    float4 a = *(const float4*)(src);
    float4 b = *(const float4*)(src + 4);
    union { unsigned int u[4]; ushortx8 s; } o;
    o.u[0] = pkbf(a.x, a.y); o.u[1] = pkbf(a.z, a.w);
    o.u[2] = pkbf(b.x, b.y); o.u[3] = pkbf(b.z, b.w);
    *(ushortx8*)(dst + i) = o.s;
}

// ---------------------------------------------------------------------------
// MFMA GEMM core: 128x128 tile, BK=32, 4 waves each computing 64x64.
// TRIPLE-buffered LDS, prefetch depth 2 (T3/T4): at the top of iter k the
// tile-k DMAs are TWO compute bodies old (~matches HBM latency), and the
// wait is counted vmcnt(4) -- tile k+1's loads stay in flight across the
// barrier. Buffer (k+2)%3 overwrite is safe: the barrier is reached only
// after all waves consumed buffer (k-1)%3 into registers.
// ---------------------------------------------------------------------------
#define TM 128
#define TN 128
#define TK 32

// GEMM1: QKV projection. Outputs:
//   Qb [row][1024]  Q * 0.125*log2e (bf16)
//   Kd [row][1024]  K (bf16), dense rows for contiguous global_load_lds
//   V5 fragment-packed V'^T (e^mask folded): element (b,n,kt32,s,d) at
//     ((b*16+n)*32+kt32)*4096 + (ks*16+dt*4+q2)*128 + dl*8 + hi*4 + r
//     with kg=s>>2, r=s&3, ks=kg>>3, q2=kg&3, hi=(kg>>2)&1, dt=d>>4, dl=d&15.
//   => attention's PV A-fragments are direct 16B loads in final MFMA order.
__global__ __launch_bounds__(256) void gemm_mfma_qkv(
    const unsigned short* __restrict__ A, const unsigned short* __restrict__ Bw,
    const float* __restrict__ bias, const float* __restrict__ mask,
    unsigned short* __restrict__ Qb, unsigned short* __restrict__ Kd,
    unsigned short* __restrict__ V5, int K)
{
    __shared__ unsigned short As[3][TM][TK];   // 24 KB
    __shared__ unsigned short Bs[3][TN][TK];   // 24 KB

    const int tid = threadIdx.x;
    const int w = tid >> 6, lane = tid & 63;
    const int l15 = lane & 15, quad = lane >> 4;
    const int wr = (w & 1) * 64;
    const int wc = (w >> 1) * 64;
    const int row0 = blockIdx.y * TM;
    const int col0 = blockIdx.x * TN;

    const int srow16 = lane >> 2;
    const int sgd    = lane & 3;
    const int sgsrc  = (sgd ^ swz(srow16)) * 8;

    floatx4 acc[4][4];
    #pragma unroll
    for (int i = 0; i < 4; i++)
        #pragma unroll
        for (int j = 0; j < 4; j++) acc[i][j] = (floatx4){0.f,0.f,0.f,0.f};

    const int aswz = swz(l15) * 8;
    const int NK = K / TK;

    // prologue: stage tiles 0,1 into buffers 0,1
    #pragma unroll
    for (int t = 0; t < 2; t++) {
        #pragma unroll
        for (int c = 0; c < 2; c++) {
            int seg = w * 2 + c;
            int r = seg * 16 + srow16;
            gload16(A  + (size_t)(row0 + r) * K + t * TK + sgsrc, &As[t][seg * 16][0]);
            gload16(Bw + (size_t)(col0 + r) * K + t * TK + sgsrc, &Bs[t][seg * 16][0]);
        }
    }

    #pragma unroll 1
    for (int k = 0; k < NK; ++k) {
        if (k + 1 < NK) asm volatile("s_waitcnt vmcnt(4)" ::: "memory");
        else            asm volatile("s_waitcnt vmcnt(0)" ::: "memory");
        __builtin_amdgcn_s_barrier();
        __builtin_amdgcn_sched_barrier(0);

        const int cur = k % 3;
        if (k + 2 < NK) {                                  // prefetch tile k+2
            const int nb  = (k + 2) % 3;
            const int k0n = (k + 2) * TK;
            #pragma unroll
            for (int c = 0; c < 2; c++) {
                int seg = w * 2 + c;
                int r = seg * 16 + srow16;
                gload16(A  + (size_t)(row0 + r) * K + k0n + sgsrc, &As[nb][seg * 16][0]);
                gload16(Bw + (size_t)(col0 + r) * K + k0n + sgsrc, &Bs[nb][seg * 16][0]);
            }
        }
        __builtin_amdgcn_sched_barrier(0);

        short8 af[4], bf[4];
        #pragma unroll
        for (int i = 0; i < 4; i++)
            af[i] = *(const short8*)&As[cur][wr + i * 16 + l15][(quad * 8) ^ aswz];
        #pragma unroll
        for (int j = 0; j < 4; j++)
            bf[j] = *(const short8*)&Bs[cur][wc + j * 16 + l15][(quad * 8) ^ aswz];
        __builtin_amdgcn_s_setprio(1);
        #pragma unroll
        for (int i = 0; i < 4; i++)
            #pragma unroll
            for (int j = 0; j < 4; j++)
                acc[i][j] = __builtin_amdgcn_mfma_f32_16x16x32_bf16(af[i], bf[j], acc[i][j], 0, 0, 0);
        __builtin_amdgcn_s_setprio(0);
    }

    const int cls = col0 >> 10;    // 0=Q, 1=K, 2=V; uniform per block

    if (cls == 2) {
        #pragma unroll
        for (int i = 0; i < 4; i++) {
            const int rb = row0 + wr + i * 16 + quad * 4;
            const int b  = rb >> 11;
            const int s  = rb & (Sq - 1);
            const int kt32 = s >> 6;
            const int sw   = s & 63;
            const int kg   = sw >> 2;          // s&3 == 0 (rb % 4 == 0)
            const int ks   = kg >> 3;
            const int q2   = kg & 3;
            const int hi   = (kg >> 2) & 1;
            float expm[4];
            #pragma unroll
            for (int rr = 0; rr < 4; rr++)
                expm[rr] = fexp2(mask[(size_t)b * Sq + s + rr] * LOG2E);
            #pragma unroll
            for (int j = 0; j < 4; j++) {
                const int c  = col0 + wc + j * 16 + l15;
                const int c2 = c - 2 * Hq;           // n*64+d
                const int n  = c2 >> 6, d = c2 & 63;
                const int dt = d >> 4, dl = d & 15;
                const float bia = bias[c];
                ushortx4 o;
                #pragma unroll
                for (int rr = 0; rr < 4; rr++)
                    o[rr] = f2bf((acc[i][j][rr] + bia) * expm[rr]);
                const size_t off = (((size_t)(b * Nq + n) * 32 + kt32) << 12)
                                 + (size_t)((ks * 16 + dt * 4 + q2) * 128 + dl * 8 + hi * 4);
                *(ushortx4*)&V5[off] = o;
            }
        }
    } else {
        unsigned short* __restrict__ dst = (cls == 0) ? Qb : Kd;
        const int cshift = (cls == 0) ? 0 : Hq;
        const float qs = (cls == 0) ? (0.125f * LOG2E) : 1.0f;
        #pragma unroll
        for (int i = 0; i < 4; i++) {
            const int rb = row0 + wr + i * 16 + quad * 4;
            #pragma unroll
            for (int j = 0; j < 4; j++) {
                const int c = col0 + wc + j * 16 + l15;
                const float bia = bias[c];
                #pragma unroll
                for (int rr = 0; rr < 4; rr++)
                    dst[(size_t)(rb + rr) * Hq + (c - cshift)] =
                        f2bf((acc[i][j][rr] + bia) * qs);
            }
        }
    }
}

// GEMM2: x = A*Bw^T + bias + residual -> bf16 (LN reads bf16, stats in fp32)
__global__ __launch_bounds__(256) void gemm_mfma_out(
    const unsigned short* __restrict__ A, const unsigned short* __restrict__ Bw,
    const float* __restrict__ bias, const float* __restrict__ res,
    unsigned short* __restrict__ X, int M, int Nd, int K)
{
    __shared__ unsigned short As[3][TM][TK];
    __shared__ unsigned short Bs[3][TN][TK];

    const int tid = threadIdx.x;
    const int w = tid >> 6, lane = tid & 63;
    const int l15 = lane & 15, quad = lane >> 4;
    const int wr = (w & 1) * 64;
    const int wc = (w >> 1) * 64;
    const int row0 = blockIdx.y * TM;
    const int col0 = blockIdx.x * TN;

    const int srow16 = lane >> 2;
    const int sgd    = lane & 3;
    const int sgsrc  = (sgd ^ swz(srow16)) * 8;

    floatx4 acc[4][4];
    #pragma unroll
    for (int i = 0; i < 4; i++)
        #pragma unroll
        for (int j = 0; j < 4; j++) acc[i][j] = (floatx4){0.f,0.f,0.f,0.f};

    const int aswz = swz(l15) * 8;
    const int NK = K / TK;

    #pragma unroll
    for (int t = 0; t < 2; t++) {
        #pragma unroll
        for (int c = 0; c < 2; c++) {
            int seg = w * 2 + c;
            int r = seg * 16 + srow16;
            gload16(A  + (size_t)(row0 + r) * K + t * TK + sgsrc, &As[t][seg * 16][0]);
            gload16(Bw + (size_t)(col0 + r) * K + t * TK + sgsrc, &Bs[t][seg * 16][0]);
        }
    }

    #pragma unroll 1
    for (int k = 0; k < NK; ++k) {
        if (k + 1 < NK) asm volatile("s_waitcnt vmcnt(4)" ::: "memory");
        else            asm volatile("s_waitcnt vmcnt(0)" ::: "memory");
        __builtin_amdgcn_s_barrier();
        __builtin_amdgcn_sched_barrier(0);

        const int cur = k % 3;
        if (k + 2 < NK) {
            const int nb  = (k + 2) % 3;
            const int k0n = (k + 2) * TK;
            #pragma unroll
            for (int c = 0; c < 2; c++) {
                int seg = w * 2 + c;
                int r = seg * 16 + srow16;
                gload16(A  + (size_t)(row0 + r) * K + k0n + sgsrc, &As[nb][seg * 16][0]);
                gload16(Bw + (size_t)(col0 + r) * K + k0n + sgsrc, &Bs[nb][seg * 16][0]);
            }
        }
        __builtin_amdgcn_sched_barrier(0);

        short8 af[4], bf[4];
        #pragma unroll
        for (int i = 0; i < 4; i++)
            af[i] = *(const short8*)&As[cur][wr + i * 16 + l15][(quad * 8) ^ aswz];
        #pragma unroll
        for (int j = 0; j < 4; j++)
            bf[j] = *(const short8*)&Bs[cur][wc + j * 16 + l15][(quad * 8) ^ aswz];
        __builtin_amdgcn_s_setprio(1);
        #pragma unroll
        for (int i = 0; i < 4; i++)
            #pragma unroll
            for (int j = 0; j < 4; j++)
                acc[i][j] = __builtin_amdgcn_mfma_f32_16x16x32_bf16(af[i], bf[j], acc[i][j], 0, 0, 0);
        __builtin_amdgcn_s_setprio(0);
    }

    #pragma unroll
    for (int i = 0; i < 4; i++) {
        const int rb = row0 + wr + i * 16 + quad * 4;
        #pragma unroll
        for (int j = 0; j < 4; j++) {
            const int c = col0 + wc + j * 16 + l15;
            const float bia = bias[c];
            #pragma unroll
            for (int rr = 0; rr < 4; rr++) {
                X[(size_t)(rb + rr) * Nd + c] =
                    f2bf(acc[i][j][rr] + bia + res[(size_t)(rb + rr) * Nd + c]);
            }
        }
    }
}

// ---------------------------------------------------------------------------
// Grid-split-K MFMA flash attention (z=2, round-2 config: measured best).
// Cross-tile software pipeline: body(kt) = { wait K(kt) [vmcnt(10)]; barrier;
// prefetch K(kt+1); QK(kt); softmax(kt)->pfW; l+PV(kt-1) from pfR+vf(kt-1);
// load vf(kt) }.
// ---------------------------------------------------------------------------
#define KTILES 16   // 64-key tiles per z-half

__device__ __forceinline__ floatx4 mfma16(short8 a, short8 b, floatx4 c) {
    return __builtin_amdgcn_mfma_f32_16x16x32_bf16(a, b, c, 0, 0, 0);
}

// l-MFMA + PV for the PREVIOUS tile (pf/mf/vf all in final fragment order)
__device__ __forceinline__ void do_lpv(
    const short8 (&pf0)[2], const short8 (&pf1)[2], const short8 (&mf)[2],
    const short8 (&vf)[8],
    floatx4 (&oacc0)[4], floatx4 (&oacc1)[4],
    floatx4 &lacc0, floatx4 &lacc1)
{
    __builtin_amdgcn_s_setprio(1);
    lacc0 = mfma16(mf[0], pf0[0], lacc0);
    lacc0 = mfma16(mf[1], pf0[1], lacc0);
    lacc1 = mfma16(mf[0], pf1[0], lacc1);
    lacc1 = mfma16(mf[1], pf1[1], lacc1);
    #pragma unroll
    for (int dt = 0; dt < 4; dt++) {
        oacc0[dt] = mfma16(vf[dt],     pf0[0], oacc0[dt]);
        oacc1[dt] = mfma16(vf[dt],     pf1[0], oacc1[dt]);
        oacc0[dt] = mfma16(vf[4 + dt], pf0[1], oacc0[dt]);
        oacc1[dt] = mfma16(vf[4 + dt], pf1[1], oacc1[dt]);
    }
    __builtin_amdgcn_s_setprio(0);
}

template<bool HAVER, bool PREF, int VWAIT>
__device__ __forceinline__ void attn_body(
    int kt,
    unsigned short (&KsL)[2][64][64],
    const unsigned short* kp, size_t kstep,
    const unsigned short* Vb, const unsigned short* e2b,
    int w, int l15, int quad,
    const short8 (&qf0)[2], const short8 (&qf1)[2],
    short8 (&vf)[8],
    const short8 (&pfR0)[2], const short8 (&pfR1)[2], const short8 (&mfR)[2],
    short8 (&pfW0)[2], short8 (&pfW1)[2], short8 (&mfW)[2],
    floatx4 (&oacc0)[4], floatx4 (&oacc1)[4],
    floatx4 &lacc0, floatx4 &lacc1)
{
    asm volatile("s_waitcnt vmcnt(%0)" :: "i"(VWAIT) : "memory");
    __builtin_amdgcn_s_barrier();
    __builtin_amdgcn_sched_barrier(0);

    const int cur = kt & 1;
    if (PREF) {
        const unsigned short* kpn = kp + (size_t)(kt + 1) * kstep;
        gload16(kpn,                  &KsL[cur ^ 1][w * 16][0]);
        gload16(kpn + (size_t)8 * Hq, &KsL[cur ^ 1][w * 16 + 8][0]);
    }
    __builtin_amdgcn_sched_barrier(0);   // pin K-DMAs as oldest outstanding

    // mf for THIS tile (consumed next body): direct loads, final order
    const unsigned short* ep = e2b + kt * 64;
    mfW[0] = *(const short8*)(ep + quad * 8);
    mfW[1] = *(const short8*)(ep + 32 + quad * 8);

    // ---- QK(kt): S^T = K Q^T for both subtiles
    floatx4 s0[4], s1[4];
    #pragma unroll
    for (int ct = 0; ct < 4; ct++) {
        s0[ct] = (floatx4){0.f,0.f,0.f,0.f};
        s1[ct] = (floatx4){0.f,0.f,0.f,0.f};
    }
    __builtin_amdgcn_s_setprio(1);
    #pragma unroll
    for (int ks = 0; ks < 2; ks++) {
        #pragma unroll
        for (int ct = 0; ct < 4; ct++) {
            short8 af = *(const short8*)&KsL[cur][ct * 16 + l15][((4 * ks + quad) ^ (l15 & 7)) * 8];
            s0[ct] = mfma16(af, qf0[ks], s0[ct]);
            s1[ct] = mfma16(af, qf1[ks], s1[ct]);
        }
    }
    __builtin_amdgcn_s_setprio(0);

    // ---- softmax(kt) -> pfW (exp2-only via raw v_exp_f32; mask in V'/mf)
    #pragma unroll
    for (int ks = 0; ks < 2; ks++) {
        union { unsigned int u[4]; short8 s; } pk;
        #pragma unroll
        for (int h = 0; h < 2; h++) {
            const int ct = ks * 2 + h;
            pk.u[h * 2]     = pkbf(fexp2(s0[ct][0]), fexp2(s0[ct][1]));
            pk.u[h * 2 + 1] = pkbf(fexp2(s0[ct][2]), fexp2(s0[ct][3]));
        }
        pfW0[ks] = pk.s;
    }
    #pragma unroll
    for (int ks = 0; ks < 2; ks++) {
        union { unsigned int u[4]; short8 s; } pk;
        #pragma unroll
        for (int h = 0; h < 2; h++) {
            const int ct = ks * 2 + h;
            pk.u[h * 2]     = pkbf(fexp2(s1[ct][0]), fexp2(s1[ct][1]));
            pk.u[h * 2 + 1] = pkbf(fexp2(s1[ct][2]), fexp2(s1[ct][3]));
        }
        pfW1[ks] = pk.s;
    }

    // ---- l + PV for tile kt-1 (overlaps the exp2 chain above)
    if (HAVER)
        do_lpv(pfR0, pfR1, mfR, vf, oacc0, oacc1, lacc0, lacc1);

    // ---- vf(kt): direct fragment loads (consumed next body => full cover)
    const unsigned short* vt = Vb + (size_t)kt * 4096 + quad * 128 + l15 * 8;
    vf[0] = *(const short8*)(vt);
    vf[1] = *(const short8*)(vt + 512);
    vf[2] = *(const short8*)(vt + 1024);
    vf[3] = *(const short8*)(vt + 1536);
    vf[4] = *(const short8*)(vt + 2048);
    vf[5] = *(const short8*)(vt + 2560);
    vf[6] = *(const short8*)(vt + 3072);
    vf[7] = *(const short8*)(vt + 3584);
}

__global__ __launch_bounds__(256) void attn_mfma(
    const unsigned short* __restrict__ Qb, const unsigned short* __restrict__ Kd,
    const unsigned short* __restrict__ V5, const unsigned short* __restrict__ em2,
    unsigned short* __restrict__ Opart, float* __restrict__ Lpart)
{
    __shared__ unsigned short Ks[2][64][64];   // [buf][key][d], src-granule swizzled

    const int tid  = threadIdx.x;
    const int w    = tid >> 6;
    const int lane = tid & 63;
    const int l15  = lane & 15;
    const int quad = lane >> 4;

    const int qtile = blockIdx.x;     // 0..15 (128 queries each)
    const int bn    = blockIdx.y;
    const int z     = blockIdx.z;
    const int n     = bn & 15;
    const int b     = bn >> 4;

    const int kbase = z * (KTILES * 64);

    // Q B-fragments for both subtiles (n=l15 -> query row, k=quad*8+j)
    short8 qf0[2], qf1[2];
    {
        const int qrow0 = qtile * 128 + w * 16 + l15;
        const unsigned short* qp = Qb + (size_t)(b * Sq + qrow0) * Hq + n * HNq + quad * 8;
        qf0[0] = *(const short8*)(qp);
        qf0[1] = *(const short8*)(qp + 32);
        qp += (size_t)64 * Hq;
        qf1[0] = *(const short8*)(qp);
        qf1[1] = *(const short8*)(qp + 32);
    }

    floatx4 oacc0[4], oacc1[4];   // O^T per subtile: d = dt*16+quad*4+r, q=l15
    #pragma unroll
    for (int dt = 0; dt < 4; dt++) {
        oacc0[dt] = (floatx4){0.f,0.f,0.f,0.f};
        oacc1[dt] = (floatx4){0.f,0.f,0.f,0.f};
    }
    floatx4 lacc0 = (floatx4){0.f,0.f,0.f,0.f};
    floatx4 lacc1 = (floatx4){0.f,0.f,0.f,0.f};

    // K DMA geometry: wave w stages rows w*16..w*16+15 via 2 global_load_lds.
    const int krow8 = lane >> 3;               // 0..7
    const int kgr   = (lane & 7) ^ (krow8 & 7);
    const unsigned short* kp = Kd + (size_t)(b * Sq + kbase + w * 16 + krow8) * Hq
                                  + n * HNq + kgr * 8;
    const size_t kstep = (size_t)64 * Hq;

    // prologue: K tile 0 -> Ks[0]
    gload16(kp,                  &Ks[0][w * 16][0]);
    gload16(kp + (size_t)8 * Hq, &Ks[0][w * 16 + 8][0]);

    // fragment-packed V base + permuted mask base
    const unsigned short* Vb  = V5 + ((size_t)(b * Nq + n) * 32 + z * KTILES) * 4096;
    const unsigned short* e2b = em2 + (size_t)(b * 32 + z * KTILES) * 64;

    // pipeline state (two named stages, no dynamic indexing)
    short8 vf[8];
    short8 pfA0[2], pfA1[2], mfA[2];
    short8 pfB0[2], pfB1[2], mfB[2];

    // peel kt=0: fills stage A + vf(0); no PV yet
    attn_body<false, true, 0>(0, Ks, kp, kstep, Vb, e2b, w, l15, quad,
        qf0, qf1, vf, pfB0, pfB1, mfB, pfA0, pfA1, mfA, oacc0, oacc1, lacc0, lacc1);

    #pragma unroll 1
    for (int kt = 1; kt < KTILES - 1; kt += 2) {
        attn_body<true, true, 10>(kt, Ks, kp, kstep, Vb, e2b, w, l15, quad,
            qf0, qf1, vf, pfA0, pfA1, mfA, pfB0, pfB1, mfB, oacc0, oacc1, lacc0, lacc1);
        attn_body<true, true, 10>(kt + 1, Ks, kp, kstep, Vb, e2b, w, l15, quad,
            qf0, qf1, vf, pfB0, pfB1, mfB, pfA0, pfA1, mfA, oacc0, oacc1, lacc0, lacc1);
    }
    // kt = 15 (odd): reads A, writes B, no K prefetch
    attn_body<true, false, 10>(KTILES - 1, Ks, kp, kstep, Vb, e2b, w, l15, quad,
        qf0, qf1, vf, pfA0, pfA1, mfA, pfB0, pfB1, mfB, oacc0, oacc1, lacc0, lacc1);
    // drain: l + PV of the last tile (stage B, vf(15))
    do_lpv(pfB0, pfB1, mfB, vf, oacc0, oacc1, lacc0, lacc1);

    // ---- epilogue: un-normalized partial O (bf16) + per-query l (no shfls:
    // every row of lacc holds l_q for q=l15)
    unsigned short* Ow = Opart + (size_t)z * Mq * Hq;
    #pragma unroll
    for (int sub = 0; sub < 2; sub++) {
        const float l_i = sub ? lacc1[0] : lacc0[0];
        const int qrow = qtile * 128 + sub * 64 + w * 16 + l15;
        if (quad == 0)
            Lpart[(size_t)z * Mq * Nq + (size_t)(b * Sq + qrow) * Nq + n] = l_i;
        #pragma unroll
        for (int dt = 0; dt < 4; dt++) {
            const floatx4 oa = sub ? oacc1[dt] : oacc0[dt];
            union { unsigned int u[2]; ushortx4 s; } o;
            o.u[0] = pkbf(oa[0], oa[1]);
            o.u[1] = pkbf(oa[2], oa[3]);
            const int col = n * HNq + dt * 16 + quad * 4;
            *(ushortx4*)&Ow[(size_t)(b * Sq + qrow) * Hq + col] = o.s;
        }
    }
}

// ---------------------------------------------------------------------------
// Merge the two split-K halves: ctx = (O0 + O1) / (l0 + l1), bf16 out.
// ---------------------------------------------------------------------------
__global__ __launch_bounds__(256) void attn_merge(
    const unsigned short* __restrict__ Opart, const float* __restrict__ Lpart,
    unsigned short* __restrict__ ctx)
{
    const size_t idx = ((size_t)blockIdx.x * 256 + threadIdx.x) * 4;
    const int row = (int)(idx >> 10);          // b*Sq + s
    const int n   = ((int)idx >> 6) & 15;
    const float l = Lpart[(size_t)row * Nq + n]
                  + Lpart[(size_t)Mq * Nq + (size_t)row * Nq + n];
    const float inv = 1.0f / l;
    ushortx4 a = *(const ushortx4*)(Opart + idx);
    ushortx4 c = *(const ushortx4*)(Opart + (size_t)Mq * Hq + idx);
    union { unsigned int u[2]; ushortx4 s; } o;
    o.u[0] = pkbf((bf2f(a[0]) + bf2f(c[0])) * inv, (bf2f(a[1]) + bf2f(c[1])) * inv);
    o.u[1] = pkbf((bf2f(a[2]) + bf2f(c[2])) * inv, (bf2f(a[3]) + bf2f(c[3])) * inv);
    *(ushortx4*)(ctx + idx) = o.s;
}

// ---------------------------------------------------------------------------
// Row LayerNorm over H=1024, bf16 input, fp32 stats, fp32 output.
// ---------------------------------------------------------------------------
__global__ __launch_bounds__(256) void ln_kernel(
    const unsigned short* __restrict__ X, const float* __restrict__ gamma,
    const float* __restrict__ beta, float* __restrict__ out)
{
    const int row = blockIdx.x;
    const int c0  = threadIdx.x * 4;
    ushortx4 xv = *(const ushortx4*)(X + (size_t)row * Hq + c0);
    float vals[4];
    float lsum = 0.0f;
    #pragma unroll
    for (int i = 0; i < 4; i++) { vals[i] = bf2f(xv[i]); lsum += vals[i]; }

    __shared__ float red[8];
    const int wid = threadIdx.x >> 6, lane = threadIdx.x & 63;

    float s = lsum;
    #pragma unroll
    for (int off = 32; off >= 1; off >>= 1) s += __shfl_xor(s, off, 64);
    if (lane == 0) red[wid] = s;
    __syncthreads();
    const float mean = (red[0] + red[1] + red[2] + red[3]) * (1.0f / Hq);

    float v = 0.0f;
    #pragma unroll
    for (int i = 0; i < 4; i++) { float d = vals[i] - mean; v += d * d; }
    #pragma unroll
    for (int off = 32; off >= 1; off >>= 1) v += __shfl_xor(v, off, 64);
    if (lane == 0) red[4 + wid] = v;
    __syncthreads();
    const float var  = (red[4] + red[5] + red[6] + red[7]) * (1.0f / Hq);
    const float rstd = rsqrtf(var + 1e-12f);

    float4 gm = *(const float4*)(gamma + c0);
    float4 bt = *(const float4*)(beta + c0);
    float4 o;
    o.x = (vals[0] - mean) * rstd * gm.x + bt.x;
    o.y = (vals[1] - mean) * rstd * gm.y + bt.y;
    o.z = (vals[2] - mean) * rstd * gm.z + bt.z;
    o.w = (vals[3] - mean) * rstd * gm.w + bt.w;
    *(float4*)(out + (size_t)row * Hq + c0) = o;
}

// ---------------------------------------------------------------------------
extern "C" void kernel_launch(void* const* d_in, const int* in_sizes, int n_in,
                              void* d_out, int out_size, void* d_ws, size_t ws_size,
                              hipStream_t stream)
{
    const float* hidden = (const float*)d_in[0];
    const float* mask   = (const float*)d_in[1];
    const float* W_qkv  = (const float*)d_in[2];
    const float* b_qkv  = (const float*)d_in[3];
    const float* W_out  = (const float*)d_in[4];
    const float* b_out  = (const float*)d_in[5];
    const float* gamma  = (const float*)d_in[6];
    const float* beta   = (const float*)d_in[7];
    float* out = (float*)d_out;

    const size_t nHid  = (size_t)Mq * Hq;        // 4 M
    const size_t nWq   = (size_t)H3q * Hq;       // 3 M
    const size_t nWo   = (size_t)Hq * Hq;        // 1 M
    const size_t nCtx  = (size_t)Mq * Hq;        // 4 M

    unsigned short* hidden_bf = (unsigned short*)d_ws;
    unsigned short* Wqkv_bf   = hidden_bf + nHid;
    unsigned short* Wout_bf   = Wqkv_bf + nWq;
    unsigned short* qb        = Wout_bf + nWo;          // Q  [4096][1024]
    unsigned short* kd        = qb + nHid;              // K  [4096][1024]
    unsigned short* v5        = kd + nHid;              // V' fragment-packed, 4 M
    unsigned short* ctx_bf    = v5 + nHid;
    unsigned short* x_bf      = ctx_bf + nCtx;
    unsigned short* opart     = x_bf + nHid;            // 2 * 4M bf16 = 16 MB
    float*          lpart     = (float*)(opart + 2 * nHid);  // 2*64K floats
    unsigned short* em2       = (unsigned short*)(lpart + 2 * (size_t)Mq * Nq);

    dim3 blk(256);

    // 0) fused fp32 -> bf16 cast + permuted expmask table (one kernel)
    cvt_all<<<dim3(CVT_BLKS + 2), blk, 0, stream>>>(
        hidden, W_qkv, W_out, mask, hidden_bf, em2);

    // 1) QKV projection (MFMA, depth-2 pipelined staging) -> Qb / Kd / V5
    gemm_mfma_qkv<<<dim3(H3q / TN, Mq / TM), blk, 0, stream>>>(
        hidden_bf, Wqkv_bf, b_qkv, mask, qb, kd, v5, Hq);

    // 2) Pipelined grid-split-K MFMA flash attention -> partial O/l
    attn_mfma<<<dim3(Sq / 128, Bq * Nq, 2), blk, 0, stream>>>(
        qb, kd, v5, em2, opart, lpart);

    // 2b) merge halves -> ctx bf16
    attn_merge<<<dim3((int)(nCtx / 1024)), blk, 0, stream>>>(
        opart, lpart, ctx_bf);

    // 3) Output projection (MFMA, depth-2 pipelined staging) + residual -> x bf16
    gemm_mfma_out<<<dim3(Hq / TN, Mq / TM), blk, 0, stream>>>(
        ctx_bf, Wout_bf, b_out, hidden, x_bf, Mq, Hq, Hq);

    // 4) LayerNorm: bf16 x -> fp32 out
    ln_kernel<<<dim3(Mq), blk, 0, stream>>>(x_bf, gamma, beta, out);
}

// Round 7
// 203.481 us; speedup vs baseline: 1.2400x; 1.0083x over previous
//
#include <hip/hip_runtime.h>
#include <hip/hip_bf16.h>
#include <math.h>

// Problem constants
#define Bq  2
#define Sq  2048
#define Hq  1024
#define Nq  16
#define HNq 64
#define Mq  (Bq*Sq)        // 4096 rows
#define H3q (3*Hq)         // 3072

#define LOG2E 1.44269504088896340736f

typedef __attribute__((ext_vector_type(8))) short           short8;
typedef __attribute__((ext_vector_type(4))) short           short4s;
typedef __attribute__((ext_vector_type(8))) unsigned short  ushortx8;
typedef __attribute__((ext_vector_type(4))) unsigned short  ushortx4;
typedef __attribute__((ext_vector_type(4))) float           floatx4;

__device__ __forceinline__ unsigned short f2bf(float f) {
    union { float f; unsigned int u; } x; x.f = f;
    unsigned int r = (x.u + 0x7fffu + ((x.u >> 16) & 1u)) >> 16;
    return (unsigned short)r;
}

// packed fp32x2 -> bf16x2 (v_cvt_pk_bf16_f32 on gfx950); a in low 16 bits
__device__ __forceinline__ unsigned int pkbf(float a, float b) {
    float2 t; t.x = a; t.y = b;
    __hip_bfloat162 h = __float22bfloat162_rn(t);
    union { __hip_bfloat162 h; unsigned int u; } c; c.h = h;
    return c.u;
}

__device__ __forceinline__ float bf2f(unsigned short v) {
    union { unsigned int u; float f; } x; x.u = (unsigned int)v << 16;
    return x.f;
}

// raw v_exp_f32 (D = 2^S0): ONE transcendental op (libm exp2f is a guarded
// ~10-op sequence without fast-math -- was the hidden VALU hog).
__device__ __forceinline__ float fexp2(float x) {
    float r;
    asm("v_exp_f32 %0, %1" : "=v"(r) : "v"(x));
    return r;
}

// async global->LDS, 16B per lane; LDS dest = wave-uniform base + lane*16
__device__ __forceinline__ void gload16(const unsigned short* g, unsigned short* l) {
    __builtin_amdgcn_global_load_lds(
        (__attribute__((address_space(1))) void*)(unsigned long long)(g),
        (__attribute__((address_space(3))) void*)(unsigned int)(unsigned long long)(l),
        16, 0, 0);
}

// LDS bank swizzle: granule' = granule ^ swz(row mod 16); 2-way max conflict
__device__ __forceinline__ int swz(int r) { return (r ^ (r >> 2)) & 3; }

// ---------------------------------------------------------------------------
// Fused fp32 -> bf16 cast for hidden | W_qkv | W_out + permuted e^mask table
// (mask blocks appended to the same grid: one fewer launch).
// em2[((b*32+kt)*2+ks)*32 + quad*8 + hi*4 + r]
//   = exp(mask[b][kt*64 + (2ks+hi)*16 + quad*4 + r])
// ---------------------------------------------------------------------------
#define N_HID ((size_t)Mq * Hq)          // 4194304
#define N_HW  (N_HID + (size_t)H3q * Hq) // 7340032
#define N_ALL (N_HW + (size_t)Hq * Hq)   // 8388608
#define CVT_BLKS ((int)(N_ALL / 2048))   // 4096

__global__ __launch_bounds__(256) void cvt_all(
    const float* __restrict__ hidden, const float* __restrict__ wqkv,
    const float* __restrict__ wout, const float* __restrict__ mask,
    unsigned short* __restrict__ dst, unsigned short* __restrict__ em2)
{
    const int bid = blockIdx.x;
    if (bid >= CVT_BLKS) {
        // ---- permuted e^mask table (2 blocks, 4096 outputs)
        const int t0   = ((bid - CVT_BLKS) * 256 + threadIdx.x) * 8;
        const int b    = t0 >> 11;
        const int t2   = t0 & 2047;
        const int kt   = t2 >> 6;
        const int t3   = t2 & 63;
        const int ks   = t3 >> 5;
        const int quad = (t3 >> 3) & 3;
        const int kb   = kt * 64 + ks * 32 + quad * 4;
        const float* mp = mask + (size_t)b * Sq + kb;
        float4 m0 = *(const float4*)(mp);
        float4 m1 = *(const float4*)(mp + 16);
        union { unsigned int u[4]; ushortx8 s; } o;
        o.u[0] = pkbf(fexp2(m0.x * LOG2E), fexp2(m0.y * LOG2E));
        o.u[1] = pkbf(fexp2(m0.z * LOG2E), fexp2(m0.w * LOG2E));
        o.u[2] = pkbf(fexp2(m1.x * LOG2E), fexp2(m1.y * LOG2E));
        o.u[3] = pkbf(fexp2(m1.z * LOG2E), fexp2(m1.w * LOG2E));
        *(ushortx8*)(em2 + t0) = o.s;
        return;
    }
    size_t i = ((size_t)bid * 256 + threadIdx.x) * 8;
    const float* src;
    if (i < N_HID)      src = hidden + i;
    else if (i < N_HW)  src = wqkv + (i - N_HID);
    else                src = wout + (i - N_HW);
    float4 a = *(const float4*)(src);
    float4 b = *(const float4*)(src + 4);
    union { unsigned int u[4]; ushortx8 s; } o;
    o.u[0] = pkbf(a.x, a.y); o.u[1] = pkbf(a.z, a.w);
    o.u[2] = pkbf(b.x, b.y); o.u[3] = pkbf(b.z, b.w);
    *(ushortx8*)(dst + i) = o.s;
}

// ---------------------------------------------------------------------------
// MFMA GEMM core: 128x128 tile, BK=32, 4 waves each computing 64x64.
// TRIPLE-buffered LDS, prefetch depth 2 (T3/T4): at the top of iter k the
// tile-k DMAs are TWO compute bodies old (~matches HBM latency), and the
// wait is counted vmcnt(4) -- tile k+1's loads stay in flight across the
// barrier. Buffer (k+2)%3 overwrite is safe: the barrier is reached only
// after all waves consumed buffer (k-1)%3 into registers.
// ---------------------------------------------------------------------------
#define TM 128
#define TN 128
#define TK 32

// GEMM1: QKV projection. Outputs:
//   Qb [row][1024]  Q * 0.125*log2e (bf16)
//   Kd [row][1024]  K (bf16), dense rows for contiguous global_load_lds
//   V5 fragment-packed V'^T (e^mask folded): element (b,n,kt32,s,d) at
//     ((b*16+n)*32+kt32)*4096 + (ks*16+dt*4+q2)*128 + dl*8 + hi*4 + r
//     with kg=s>>2, r=s&3, ks=kg>>3, q2=kg&3, hi=(kg>>2)&1, dt=d>>4, dl=d&15.
//   => attention's PV A-fragments are direct 16B loads in final MFMA order.
__global__ __launch_bounds__(256) void gemm_mfma_qkv(
    const unsigned short* __restrict__ A, const unsigned short* __restrict__ Bw,
    const float* __restrict__ bias, const float* __restrict__ mask,
    unsigned short* __restrict__ Qb, unsigned short* __restrict__ Kd,
    unsigned short* __restrict__ V5, int K)
{
    __shared__ unsigned short As[3][TM][TK];   // 24 KB
    __shared__ unsigned short Bs[3][TN][TK];   // 24 KB

    const int tid = threadIdx.x;
    const int w = tid >> 6, lane = tid & 63;
    const int l15 = lane & 15, quad = lane >> 4;
    const int wr = (w & 1) * 64;
    const int wc = (w >> 1) * 64;
    const int row0 = blockIdx.y * TM;
    const int col0 = blockIdx.x * TN;

    const int srow16 = lane >> 2;
    const int sgd    = lane & 3;
    const int sgsrc  = (sgd ^ swz(srow16)) * 8;

    floatx4 acc[4][4];
    #pragma unroll
    for (int i = 0; i < 4; i++)
        #pragma unroll
        for (int j = 0; j < 4; j++) acc[i][j] = (floatx4){0.f,0.f,0.f,0.f};

    const int aswz = swz(l15) * 8;
    const int NK = K / TK;

    // prologue: stage tiles 0,1 into buffers 0,1
    #pragma unroll
    for (int t = 0; t < 2; t++) {
        #pragma unroll
        for (int c = 0; c < 2; c++) {
            int seg = w * 2 + c;
            int r = seg * 16 + srow16;
            gload16(A  + (size_t)(row0 + r) * K + t * TK + sgsrc, &As[t][seg * 16][0]);
            gload16(Bw + (size_t)(col0 + r) * K + t * TK + sgsrc, &Bs[t][seg * 16][0]);
        }
    }

    #pragma unroll 1
    for (int k = 0; k < NK; ++k) {
        if (k + 1 < NK) asm volatile("s_waitcnt vmcnt(4)" ::: "memory");
        else            asm volatile("s_waitcnt vmcnt(0)" ::: "memory");
        __builtin_amdgcn_s_barrier();
        __builtin_amdgcn_sched_barrier(0);

        const int cur = k % 3;
        if (k + 2 < NK) {                                  // prefetch tile k+2
            const int nb  = (k + 2) % 3;
            const int k0n = (k + 2) * TK;
            #pragma unroll
            for (int c = 0; c < 2; c++) {
                int seg = w * 2 + c;
                int r = seg * 16 + srow16;
                gload16(A  + (size_t)(row0 + r) * K + k0n + sgsrc, &As[nb][seg * 16][0]);
                gload16(Bw + (size_t)(col0 + r) * K + k0n + sgsrc, &Bs[nb][seg * 16][0]);
            }
        }
        __builtin_amdgcn_sched_barrier(0);

        short8 af[4], bf[4];
        #pragma unroll
        for (int i = 0; i < 4; i++)
            af[i] = *(const short8*)&As[cur][wr + i * 16 + l15][(quad * 8) ^ aswz];
        #pragma unroll
        for (int j = 0; j < 4; j++)
            bf[j] = *(const short8*)&Bs[cur][wc + j * 16 + l15][(quad * 8) ^ aswz];
        __builtin_amdgcn_s_setprio(1);
        #pragma unroll
        for (int i = 0; i < 4; i++)
            #pragma unroll
            for (int j = 0; j < 4; j++)
                acc[i][j] = __builtin_amdgcn_mfma_f32_16x16x32_bf16(af[i], bf[j], acc[i][j], 0, 0, 0);
        __builtin_amdgcn_s_setprio(0);
    }

    const int cls = col0 >> 10;    // 0=Q, 1=K, 2=V; uniform per block

    if (cls == 2) {
        #pragma unroll
        for (int i = 0; i < 4; i++) {
            const int rb = row0 + wr + i * 16 + quad * 4;
            const int b  = rb >> 11;
            const int s  = rb & (Sq - 1);
            const int kt32 = s >> 6;
            const int sw   = s & 63;
            const int kg   = sw >> 2;          // s&3 == 0 (rb % 4 == 0)
            const int ks   = kg >> 3;
            const int q2   = kg & 3;
            const int hi   = (kg >> 2) & 1;
            float expm[4];
            #pragma unroll
            for (int rr = 0; rr < 4; rr++)
                expm[rr] = fexp2(mask[(size_t)b * Sq + s + rr] * LOG2E);
            #pragma unroll
            for (int j = 0; j < 4; j++) {
                const int c  = col0 + wc + j * 16 + l15;
                const int c2 = c - 2 * Hq;           // n*64+d
                const int n  = c2 >> 6, d = c2 & 63;
                const int dt = d >> 4, dl = d & 15;
                const float bia = bias[c];
                ushortx4 o;
                #pragma unroll
                for (int rr = 0; rr < 4; rr++)
                    o[rr] = f2bf((acc[i][j][rr] + bia) * expm[rr]);
                const size_t off = (((size_t)(b * Nq + n) * 32 + kt32) << 12)
                                 + (size_t)((ks * 16 + dt * 4 + q2) * 128 + dl * 8 + hi * 4);
                *(ushortx4*)&V5[off] = o;
            }
        }
    } else {
        unsigned short* __restrict__ dst = (cls == 0) ? Qb : Kd;
        const int cshift = (cls == 0) ? 0 : Hq;
        const float qs = (cls == 0) ? (0.125f * LOG2E) : 1.0f;
        #pragma unroll
        for (int i = 0; i < 4; i++) {
            const int rb = row0 + wr + i * 16 + quad * 4;
            #pragma unroll
            for (int j = 0; j < 4; j++) {
                const int c = col0 + wc + j * 16 + l15;
                const float bia = bias[c];
                #pragma unroll
                for (int rr = 0; rr < 4; rr++)
                    dst[(size_t)(rb + rr) * Hq + (c - cshift)] =
                        f2bf((acc[i][j][rr] + bia) * qs);
            }
        }
    }
}

// GEMM2: x = A*Bw^T + bias + residual -> bf16 (LN reads bf16, stats in fp32)
__global__ __launch_bounds__(256) void gemm_mfma_out(
    const unsigned short* __restrict__ A, const unsigned short* __restrict__ Bw,
    const float* __restrict__ bias, const float* __restrict__ res,
    unsigned short* __restrict__ X, int M, int Nd, int K)
{
    __shared__ unsigned short As[3][TM][TK];
    __shared__ unsigned short Bs[3][TN][TK];

    const int tid = threadIdx.x;
    const int w = tid >> 6, lane = tid & 63;
    const int l15 = lane & 15, quad = lane >> 4;
    const int wr = (w & 1) * 64;
    const int wc = (w >> 1) * 64;
    const int row0 = blockIdx.y * TM;
    const int col0 = blockIdx.x * TN;

    const int srow16 = lane >> 2;
    const int sgd    = lane & 3;
    const int sgsrc  = (sgd ^ swz(srow16)) * 8;

    floatx4 acc[4][4];
    #pragma unroll
    for (int i = 0; i < 4; i++)
        #pragma unroll
        for (int j = 0; j < 4; j++) acc[i][j] = (floatx4){0.f,0.f,0.f,0.f};

    const int aswz = swz(l15) * 8;
    const int NK = K / TK;

    #pragma unroll
    for (int t = 0; t < 2; t++) {
        #pragma unroll
        for (int c = 0; c < 2; c++) {
            int seg = w * 2 + c;
            int r = seg * 16 + srow16;
            gload16(A  + (size_t)(row0 + r) * K + t * TK + sgsrc, &As[t][seg * 16][0]);
            gload16(Bw + (size_t)(col0 + r) * K + t * TK + sgsrc, &Bs[t][seg * 16][0]);
        }
    }

    #pragma unroll 1
    for (int k = 0; k < NK; ++k) {
        if (k + 1 < NK) asm volatile("s_waitcnt vmcnt(4)" ::: "memory");
        else            asm volatile("s_waitcnt vmcnt(0)" ::: "memory");
        __builtin_amdgcn_s_barrier();
        __builtin_amdgcn_sched_barrier(0);

        const int cur = k % 3;
        if (k + 2 < NK) {
            const int nb  = (k + 2) % 3;
            const int k0n = (k + 2) * TK;
            #pragma unroll
            for (int c = 0; c < 2; c++) {
                int seg = w * 2 + c;
                int r = seg * 16 + srow16;
                gload16(A  + (size_t)(row0 + r) * K + k0n + sgsrc, &As[nb][seg * 16][0]);
                gload16(Bw + (size_t)(col0 + r) * K + k0n + sgsrc, &Bs[nb][seg * 16][0]);
            }
        }
        __builtin_amdgcn_sched_barrier(0);

        short8 af[4], bf[4];
        #pragma unroll
        for (int i = 0; i < 4; i++)
            af[i] = *(const short8*)&As[cur][wr + i * 16 + l15][(quad * 8) ^ aswz];
        #pragma unroll
        for (int j = 0; j < 4; j++)
            bf[j] = *(const short8*)&Bs[cur][wc + j * 16 + l15][(quad * 8) ^ aswz];
        __builtin_amdgcn_s_setprio(1);
        #pragma unroll
        for (int i = 0; i < 4; i++)
            #pragma unroll
            for (int j = 0; j < 4; j++)
                acc[i][j] = __builtin_amdgcn_mfma_f32_16x16x32_bf16(af[i], bf[j], acc[i][j], 0, 0, 0);
        __builtin_amdgcn_s_setprio(0);
    }

    #pragma unroll
    for (int i = 0; i < 4; i++) {
        const int rb = row0 + wr + i * 16 + quad * 4;
        #pragma unroll
        for (int j = 0; j < 4; j++) {
            const int c = col0 + wc + j * 16 + l15;
            const float bia = bias[c];
            #pragma unroll
            for (int rr = 0; rr < 4; rr++) {
                X[(size_t)(rb + rr) * Nd + c] =
                    f2bf(acc[i][j][rr] + bia + res[(size_t)(rb + rr) * Nd + c]);
            }
        }
    }
}

// ---------------------------------------------------------------------------
// Grid-split-K MFMA flash attention (z=2) with XCD-CLUSTERING block swizzle:
// the 16 qtile-blocks sharing one (b,n,z) group's K/V panels (256 KB) are
// mapped to the SAME XCD (dispatch round-robins linear id % 8 across XCDs),
// co-resident at 4 blocks/CU x 32 CUs/XCD. K/V is fetched from HBM ~once per
// group and served 16x from that XCD's private L2 -- the K-DMA vmcnt wait
// becomes an L2 hit (~200 cy) instead of an HBM miss (~900 cy).
//   linear id i = ((gh*16 + qtile) << 3) | gl8,  group g = gh*8 + gl8,
//   g = bn*2 + z  (64 groups x 16 qtiles = 1024 blocks, bijective).
// Cross-tile software pipeline unchanged from round 5.
// ---------------------------------------------------------------------------
#define KTILES 16   // 64-key tiles per z-half

__device__ __forceinline__ floatx4 mfma16(short8 a, short8 b, floatx4 c) {
    return __builtin_amdgcn_mfma_f32_16x16x32_bf16(a, b, c, 0, 0, 0);
}

// l-MFMA + PV for the PREVIOUS tile (pf/mf/vf all in final fragment order)
__device__ __forceinline__ void do_lpv(
    const short8 (&pf0)[2], const short8 (&pf1)[2], const short8 (&mf)[2],
    const short8 (&vf)[8],
    floatx4 (&oacc0)[4], floatx4 (&oacc1)[4],
    floatx4 &lacc0, floatx4 &lacc1)
{
    __builtin_amdgcn_s_setprio(1);
    lacc0 = mfma16(mf[0], pf0[0], lacc0);
    lacc0 = mfma16(mf[1], pf0[1], lacc0);
    lacc1 = mfma16(mf[0], pf1[0], lacc1);
    lacc1 = mfma16(mf[1], pf1[1], lacc1);
    #pragma unroll
    for (int dt = 0; dt < 4; dt++) {
        oacc0[dt] = mfma16(vf[dt],     pf0[0], oacc0[dt]);
        oacc1[dt] = mfma16(vf[dt],     pf1[0], oacc1[dt]);
        oacc0[dt] = mfma16(vf[4 + dt], pf0[1], oacc0[dt]);
        oacc1[dt] = mfma16(vf[4 + dt], pf1[1], oacc1[dt]);
    }
    __builtin_amdgcn_s_setprio(0);
}

template<bool HAVER, bool PREF, int VWAIT>
__device__ __forceinline__ void attn_body(
    int kt,
    unsigned short (&KsL)[2][64][64],
    const unsigned short* kp, size_t kstep,
    const unsigned short* Vb, const unsigned short* e2b,
    int w, int l15, int quad,
    const short8 (&qf0)[2], const short8 (&qf1)[2],
    short8 (&vf)[8],
    const short8 (&pfR0)[2], const short8 (&pfR1)[2], const short8 (&mfR)[2],
    short8 (&pfW0)[2], short8 (&pfW1)[2], short8 (&mfW)[2],
    floatx4 (&oacc0)[4], floatx4 (&oacc1)[4],
    floatx4 &lacc0, floatx4 &lacc1)
{
    asm volatile("s_waitcnt vmcnt(%0)" :: "i"(VWAIT) : "memory");
    __builtin_amdgcn_s_barrier();
    __builtin_amdgcn_sched_barrier(0);

    const int cur = kt & 1;
    if (PREF) {
        const unsigned short* kpn = kp + (size_t)(kt + 1) * kstep;
        gload16(kpn,                  &KsL[cur ^ 1][w * 16][0]);
        gload16(kpn + (size_t)8 * Hq, &KsL[cur ^ 1][w * 16 + 8][0]);
    }
    __builtin_amdgcn_sched_barrier(0);   // pin K-DMAs as oldest outstanding

    // mf for THIS tile (consumed next body): direct loads, final order
    const unsigned short* ep = e2b + kt * 64;
    mfW[0] = *(const short8*)(ep + quad * 8);
    mfW[1] = *(const short8*)(ep + 32 + quad * 8);

    // ---- QK(kt): S^T = K Q^T for both subtiles
    floatx4 s0[4], s1[4];
    #pragma unroll
    for (int ct = 0; ct < 4; ct++) {
        s0[ct] = (floatx4){0.f,0.f,0.f,0.f};
        s1[ct] = (floatx4){0.f,0.f,0.f,0.f};
    }
    __builtin_amdgcn_s_setprio(1);
    #pragma unroll
    for (int ks = 0; ks < 2; ks++) {
        #pragma unroll
        for (int ct = 0; ct < 4; ct++) {
            short8 af = *(const short8*)&KsL[cur][ct * 16 + l15][((4 * ks + quad) ^ (l15 & 7)) * 8];
            s0[ct] = mfma16(af, qf0[ks], s0[ct]);
            s1[ct] = mfma16(af, qf1[ks], s1[ct]);
        }
    }
    __builtin_amdgcn_s_setprio(0);

    // ---- softmax(kt) -> pfW (exp2-only via raw v_exp_f32; mask in V'/mf)
    #pragma unroll
    for (int ks = 0; ks < 2; ks++) {
        union { unsigned int u[4]; short8 s; } pk;
        #pragma unroll
        for (int h = 0; h < 2; h++) {
            const int ct = ks * 2 + h;
            pk.u[h * 2]     = pkbf(fexp2(s0[ct][0]), fexp2(s0[ct][1]));
            pk.u[h * 2 + 1] = pkbf(fexp2(s0[ct][2]), fexp2(s0[ct][3]));
        }
        pfW0[ks] = pk.s;
    }
    #pragma unroll
    for (int ks = 0; ks < 2; ks++) {
        union { unsigned int u[4]; short8 s; } pk;
        #pragma unroll
        for (int h = 0; h < 2; h++) {
            const int ct = ks * 2 + h;
            pk.u[h * 2]     = pkbf(fexp2(s1[ct][0]), fexp2(s1[ct][1]));
            pk.u[h * 2 + 1] = pkbf(fexp2(s1[ct][2]), fexp2(s1[ct][3]));
        }
        pfW1[ks] = pk.s;
    }

    // ---- l + PV for tile kt-1 (overlaps the exp2 chain above)
    if (HAVER)
        do_lpv(pfR0, pfR1, mfR, vf, oacc0, oacc1, lacc0, lacc1);

    // ---- vf(kt): direct fragment loads (consumed next body => full cover)
    const unsigned short* vt = Vb + (size_t)kt * 4096 + quad * 128 + l15 * 8;
    vf[0] = *(const short8*)(vt);
    vf[1] = *(const short8*)(vt + 512);
    vf[2] = *(const short8*)(vt + 1024);
    vf[3] = *(const short8*)(vt + 1536);
    vf[4] = *(const short8*)(vt + 2048);
    vf[5] = *(const short8*)(vt + 2560);
    vf[6] = *(const short8*)(vt + 3072);
    vf[7] = *(const short8*)(vt + 3584);
}

__global__ __launch_bounds__(256) void attn_mfma(
    const unsigned short* __restrict__ Qb, const unsigned short* __restrict__ Kd,
    const unsigned short* __restrict__ V5, const unsigned short* __restrict__ em2,
    unsigned short* __restrict__ Opart, float* __restrict__ Lpart)
{
    __shared__ unsigned short Ks[2][64][64];   // [buf][key][d], src-granule swizzled

    const int tid  = threadIdx.x;
    const int w    = tid >> 6;
    const int lane = tid & 63;
    const int l15  = lane & 15;
    const int quad = lane >> 4;

    // XCD-clustering decode: all 16 qtiles of group g=(bn,z) share K/V and
    // land on XCD g%8 (dispatch round-robins linear id across 8 XCDs).
    const int i_    = blockIdx.x;
    const int gl8   = i_ & 7;
    const int rest  = i_ >> 3;
    const int qtile = rest & 15;          // 0..15 (128 queries each)
    const int g     = (rest >> 4) * 8 + gl8;   // 0..63
    const int bn    = g >> 1;
    const int z     = g & 1;
    const int n     = bn & 15;
    const int b     = bn >> 4;

    const int kbase = z * (KTILES * 64);

    // Q B-fragments for both subtiles (n=l15 -> query row, k=quad*8+j)
    short8 qf0[2], qf1[2];
    {
        const int qrow0 = qtile * 128 + w * 16 + l15;
        const unsigned short* qp = Qb + (size_t)(b * Sq + qrow0) * Hq + n * HNq + quad * 8;
        qf0[0] = *(const short8*)(qp);
        qf0[1] = *(const short8*)(qp + 32);
        qp += (size_t)64 * Hq;
        qf1[0] = *(const short8*)(qp);
        qf1[1] = *(const short8*)(qp + 32);
    }

    floatx4 oacc0[4], oacc1[4];   // O^T per subtile: d = dt*16+quad*4+r, q=l15
    #pragma unroll
    for (int dt = 0; dt < 4; dt++) {
        oacc0[dt] = (floatx4){0.f,0.f,0.f,0.f};
        oacc1[dt] = (floatx4){0.f,0.f,0.f,0.f};
    }
    floatx4 lacc0 = (floatx4){0.f,0.f,0.f,0.f};
    floatx4 lacc1 = (floatx4){0.f,0.f,0.f,0.f};

    // K DMA geometry: wave w stages rows w*16..w*16+15 via 2 global_load_lds.
    const int krow8 = lane >> 3;               // 0..7
    const int kgr   = (lane & 7) ^ (krow8 & 7);
    const unsigned short* kp = Kd + (size_t)(b * Sq + kbase + w * 16 + krow8) * Hq
                                  + n * HNq + kgr * 8;
    const size_t kstep = (size_t)64 * Hq;

    // prologue: K tile 0 -> Ks[0]
    gload16(kp,                  &Ks[0][w * 16][0]);
    gload16(kp + (size_t)8 * Hq, &Ks[0][w * 16 + 8][0]);

    // fragment-packed V base + permuted mask base
    const unsigned short* Vb  = V5 + ((size_t)(b * Nq + n) * 32 + z * KTILES) * 4096;
    const unsigned short* e2b = em2 + (size_t)(b * 32 + z * KTILES) * 64;

    // pipeline state (two named stages, no dynamic indexing)
    short8 vf[8];
    short8 pfA0[2], pfA1[2], mfA[2];
    short8 pfB0[2], pfB1[2], mfB[2];

    // peel kt=0: fills stage A + vf(0); no PV yet
    attn_body<false, true, 0>(0, Ks, kp, kstep, Vb, e2b, w, l15, quad,
        qf0, qf1, vf, pfB0, pfB1, mfB, pfA0, pfA1, mfA, oacc0, oacc1, lacc0, lacc1);

    #pragma unroll 1
    for (int kt = 1; kt < KTILES - 1; kt += 2) {
        attn_body<true, true, 10>(kt, Ks, kp, kstep, Vb, e2b, w, l15, quad,
            qf0, qf1, vf, pfA0, pfA1, mfA, pfB0, pfB1, mfB, oacc0, oacc1, lacc0, lacc1);
        attn_body<true, true, 10>(kt + 1, Ks, kp, kstep, Vb, e2b, w, l15, quad,
            qf0, qf1, vf, pfB0, pfB1, mfB, pfA0, pfA1, mfA, oacc0, oacc1, lacc0, lacc1);
    }
    // kt = 15 (odd): reads A, writes B, no K prefetch
    attn_body<true, false, 10>(KTILES - 1, Ks, kp, kstep, Vb, e2b, w, l15, quad,
        qf0, qf1, vf, pfA0, pfA1, mfA, pfB0, pfB1, mfB, oacc0, oacc1, lacc0, lacc1);
    // drain: l + PV of the last tile (stage B, vf(15))
    do_lpv(pfB0, pfB1, mfB, vf, oacc0, oacc1, lacc0, lacc1);

    // ---- epilogue: un-normalized partial O (bf16) + per-query l (no shfls:
    // every row of lacc holds l_q for q=l15)
    unsigned short* Ow = Opart + (size_t)z * Mq * Hq;
    #pragma unroll
    for (int sub = 0; sub < 2; sub++) {
        const float l_i = sub ? lacc1[0] : lacc0[0];
        const int qrow = qtile * 128 + sub * 64 + w * 16 + l15;
        if (quad == 0)
            Lpart[(size_t)z * Mq * Nq + (size_t)(b * Sq + qrow) * Nq + n] = l_i;
        #pragma unroll
        for (int dt = 0; dt < 4; dt++) {
            const floatx4 oa = sub ? oacc1[dt] : oacc0[dt];
            union { unsigned int u[2]; ushortx4 s; } o;
            o.u[0] = pkbf(oa[0], oa[1]);
            o.u[1] = pkbf(oa[2], oa[3]);
            const int col = n * HNq + dt * 16 + quad * 4;
            *(ushortx4*)&Ow[(size_t)(b * Sq + qrow) * Hq + col] = o.s;
        }
    }
}

// ---------------------------------------------------------------------------
// Merge the two split-K halves: ctx = (O0 + O1) / (l0 + l1), bf16 out.
// ---------------------------------------------------------------------------
__global__ __launch_bounds__(256) void attn_merge(
    const unsigned short* __restrict__ Opart, const float* __restrict__ Lpart,
    unsigned short* __restrict__ ctx)
{
    const size_t idx = ((size_t)blockIdx.x * 256 + threadIdx.x) * 4;
    const int row = (int)(idx >> 10);          // b*Sq + s
    const int n   = ((int)idx >> 6) & 15;
    const float l = Lpart[(size_t)row * Nq + n]
                  + Lpart[(size_t)Mq * Nq + (size_t)row * Nq + n];
    const float inv = 1.0f / l;
    ushortx4 a = *(const ushortx4*)(Opart + idx);
    ushortx4 c = *(const ushortx4*)(Opart + (size_t)Mq * Hq + idx);
    union { unsigned int u[2]; ushortx4 s; } o;
    o.u[0] = pkbf((bf2f(a[0]) + bf2f(c[0])) * inv, (bf2f(a[1]) + bf2f(c[1])) * inv);
    o.u[1] = pkbf((bf2f(a[2]) + bf2f(c[2])) * inv, (bf2f(a[3]) + bf2f(c[3])) * inv);
    *(ushortx4*)(ctx + idx) = o.s;
}

// ---------------------------------------------------------------------------
// Row LayerNorm over H=1024, bf16 input, fp32 stats, fp32 output.
// ---------------------------------------------------------------------------
__global__ __launch_bounds__(256) void ln_kernel(
    const unsigned short* __restrict__ X, const float* __restrict__ gamma,
    const float* __restrict__ beta, float* __restrict__ out)
{
    const int row = blockIdx.x;
    const int c0  = threadIdx.x * 4;
    ushortx4 xv = *(const ushortx4*)(X + (size_t)row * Hq + c0);
    float vals[4];
    float lsum = 0.0f;
    #pragma unroll
    for (int i = 0; i < 4; i++) { vals[i] = bf2f(xv[i]); lsum += vals[i]; }

    __shared__ float red[8];
    const int wid = threadIdx.x >> 6, lane = threadIdx.x & 63;

    float s = lsum;
    #pragma unroll
    for (int off = 32; off >= 1; off >>= 1) s += __shfl_xor(s, off, 64);
    if (lane == 0) red[wid] = s;
    __syncthreads();
    const float mean = (red[0] + red[1] + red[2] + red[3]) * (1.0f / Hq);

    float v = 0.0f;
    #pragma unroll
    for (int i = 0; i < 4; i++) { float d = vals[i] - mean; v += d * d; }
    #pragma unroll
    for (int off = 32; off >= 1; off >>= 1) v += __shfl_xor(v, off, 64);
    if (lane == 0) red[4 + wid] = v;
    __syncthreads();
    const float var  = (red[4] + red[5] + red[6] + red[7]) * (1.0f / Hq);
    const float rstd = rsqrtf(var + 1e-12f);

    float4 gm = *(const float4*)(gamma + c0);
    float4 bt = *(const float4*)(beta + c0);
    float4 o;
    o.x = (vals[0] - mean) * rstd * gm.x + bt.x;
    o.y = (vals[1] - mean) * rstd * gm.y + bt.y;
    o.z = (vals[2] - mean) * rstd * gm.z + bt.z;
    o.w = (vals[3] - mean) * rstd * gm.w + bt.w;
    *(float4*)(out + (size_t)row * Hq + c0) = o;
}

// ---------------------------------------------------------------------------
extern "C" void kernel_launch(void* const* d_in, const int* in_sizes, int n_in,
                              void* d_out, int out_size, void* d_ws, size_t ws_size,
                              hipStream_t stream)
{
    const float* hidden = (const float*)d_in[0];
    const float* mask   = (const float*)d_in[1];
    const float* W_qkv  = (const float*)d_in[2];
    const float* b_qkv  = (const float*)d_in[3];
    const float* W_out  = (const float*)d_in[4];
    const float* b_out  = (const float*)d_in[5];
    const float* gamma  = (const float*)d_in[6];
    const float* beta   = (const float*)d_in[7];
    float* out = (float*)d_out;

    const size_t nHid  = (size_t)Mq * Hq;        // 4 M
    const size_t nWq   = (size_t)H3q * Hq;       // 3 M
    const size_t nWo   = (size_t)Hq * Hq;        // 1 M
    const size_t nCtx  = (size_t)Mq * Hq;        // 4 M

    unsigned short* hidden_bf = (unsigned short*)d_ws;
    unsigned short* Wqkv_bf   = hidden_bf + nHid;
    unsigned short* Wout_bf   = Wqkv_bf + nWq;
    unsigned short* qb        = Wout_bf + nWo;          // Q  [4096][1024]
    unsigned short* kd        = qb + nHid;              // K  [4096][1024]
    unsigned short* v5        = kd + nHid;              // V' fragment-packed, 4 M
    unsigned short* ctx_bf    = v5 + nHid;
    unsigned short* x_bf      = ctx_bf + nCtx;
    unsigned short* opart     = x_bf + nHid;            // 2 * 4M bf16 = 16 MB
    float*          lpart     = (float*)(opart + 2 * nHid);  // 2*64K floats
    unsigned short* em2       = (unsigned short*)(lpart + 2 * (size_t)Mq * Nq);

    dim3 blk(256);

    // 0) fused fp32 -> bf16 cast + permuted expmask table (one kernel)
    cvt_all<<<dim3(CVT_BLKS + 2), blk, 0, stream>>>(
        hidden, W_qkv, W_out, mask, hidden_bf, em2);

    // 1) QKV projection (MFMA, depth-2 pipelined staging) -> Qb / Kd / V5
    gemm_mfma_qkv<<<dim3(H3q / TN, Mq / TM), blk, 0, stream>>>(
        hidden_bf, Wqkv_bf, b_qkv, mask, qb, kd, v5, Hq);

    // 2) Pipelined flash attention, XCD-clustered 1-D grid -> partial O/l
    attn_mfma<<<dim3(1024), blk, 0, stream>>>(
        qb, kd, v5, em2, opart, lpart);

    // 2b) merge halves -> ctx bf16
    attn_merge<<<dim3((int)(nCtx / 1024)), blk, 0, stream>>>(
        opart, lpart, ctx_bf);

    // 3) Output projection (MFMA, depth-2 pipelined staging) + residual -> x bf16
    gemm_mfma_out<<<dim3(Hq / TN, Mq / TM), blk, 0, stream>>>(
        ctx_bf, Wout_bf, b_out, hidden, x_bf, Mq, Hq, Hq);

    // 4) LayerNorm: bf16 x -> fp32 out
    ln_kernel<<<dim3(Mq), blk, 0, stream>>>(x_bf, gamma, beta, out);
}

// Round 8
// 203.320 us; speedup vs baseline: 1.2410x; 1.0008x over previous
//
#include <hip/hip_runtime.h>
#include <hip/hip_bf16.h>
#include <math.h>

// Problem constants
#define Bq  2
#define Sq  2048
#define Hq  1024
#define Nq  16
#define HNq 64
#define Mq  (Bq*Sq)        // 4096 rows
#define H3q (3*Hq)         // 3072

#define LOG2E 1.44269504088896340736f

typedef __attribute__((ext_vector_type(8))) short           short8;
typedef __attribute__((ext_vector_type(4))) short           short4s;
typedef __attribute__((ext_vector_type(8))) unsigned short  ushortx8;
typedef __attribute__((ext_vector_type(4))) unsigned short  ushortx4;
typedef __attribute__((ext_vector_type(4))) float           floatx4;

__device__ __forceinline__ unsigned short f2bf(float f) {
    union { float f; unsigned int u; } x; x.f = f;
    unsigned int r = (x.u + 0x7fffu + ((x.u >> 16) & 1u)) >> 16;
    return (unsigned short)r;
}

// packed fp32x2 -> bf16x2 (v_cvt_pk_bf16_f32 on gfx950); a in low 16 bits
__device__ __forceinline__ unsigned int pkbf(float a, float b) {
    float2 t; t.x = a; t.y = b;
    __hip_bfloat162 h = __float22bfloat162_rn(t);
    union { __hip_bfloat162 h; unsigned int u; } c; c.h = h;
    return c.u;
}

__device__ __forceinline__ float bf2f(unsigned short v) {
    union { unsigned int u; float f; } x; x.u = (unsigned int)v << 16;
    return x.f;
}

// raw v_exp_f32 (D = 2^S0): ONE transcendental op (libm exp2f is a guarded
// ~10-op sequence without fast-math -- was the hidden VALU hog).
__device__ __forceinline__ float fexp2(float x) {
    float r;
    asm("v_exp_f32 %0, %1" : "=v"(r) : "v"(x));
    return r;
}

// async global->LDS, 16B per lane; LDS dest = wave-uniform base + lane*16
__device__ __forceinline__ void gload16(const unsigned short* g, unsigned short* l) {
    __builtin_amdgcn_global_load_lds(
        (__attribute__((address_space(1))) void*)(unsigned long long)(g),
        (__attribute__((address_space(3))) void*)(unsigned int)(unsigned long long)(l),
        16, 0, 0);
}

// LDS bank swizzle: granule' = granule ^ swz(row mod 16); 2-way max conflict
__device__ __forceinline__ int swz(int r) { return (r ^ (r >> 2)) & 3; }

// ---------------------------------------------------------------------------
// Fused fp32 -> bf16 cast for hidden | W_qkv | W_out + permuted e^mask table
// (mask blocks appended to the same grid: one fewer launch).
// em2[((b*32+kt)*2+ks)*32 + quad*8 + hi*4 + r]
//   = exp(mask[b][kt*64 + (2ks+hi)*16 + quad*4 + r])
// ---------------------------------------------------------------------------
#define N_HID ((size_t)Mq * Hq)          // 4194304
#define N_HW  (N_HID + (size_t)H3q * Hq) // 7340032
#define N_ALL (N_HW + (size_t)Hq * Hq)   // 8388608
#define CVT_BLKS ((int)(N_ALL / 2048))   // 4096

__global__ __launch_bounds__(256) void cvt_all(
    const float* __restrict__ hidden, const float* __restrict__ wqkv,
    const float* __restrict__ wout, const float* __restrict__ mask,
    unsigned short* __restrict__ dst, unsigned short* __restrict__ em2)
{
    const int bid = blockIdx.x;
    if (bid >= CVT_BLKS) {
        // ---- permuted e^mask table (2 blocks, 4096 outputs)
        const int t0   = ((bid - CVT_BLKS) * 256 + threadIdx.x) * 8;
        const int b    = t0 >> 11;
        const int t2   = t0 & 2047;
        const int kt   = t2 >> 6;
        const int t3   = t2 & 63;
        const int ks   = t3 >> 5;
        const int quad = (t3 >> 3) & 3;
        const int kb   = kt * 64 + ks * 32 + quad * 4;
        const float* mp = mask + (size_t)b * Sq + kb;
        float4 m0 = *(const float4*)(mp);
        float4 m1 = *(const float4*)(mp + 16);
        union { unsigned int u[4]; ushortx8 s; } o;
        o.u[0] = pkbf(fexp2(m0.x * LOG2E), fexp2(m0.y * LOG2E));
        o.u[1] = pkbf(fexp2(m0.z * LOG2E), fexp2(m0.w * LOG2E));
        o.u[2] = pkbf(fexp2(m1.x * LOG2E), fexp2(m1.y * LOG2E));
        o.u[3] = pkbf(fexp2(m1.z * LOG2E), fexp2(m1.w * LOG2E));
        *(ushortx8*)(em2 + t0) = o.s;
        return;
    }
    size_t i = ((size_t)bid * 256 + threadIdx.x) * 8;
    const float* src;
    if (i < N_HID)      src = hidden + i;
    else if (i < N_HW)  src = wqkv + (i - N_HID);
    else                src = wout + (i - N_HW);
    float4 a = *(const float4*)(src);
    float4 b = *(const float4*)(src + 4);
    union { unsigned int u[4]; ushortx8 s; } o;
    o.u[0] = pkbf(a.x, a.y); o.u[1] = pkbf(a.z, a.w);
    o.u[2] = pkbf(b.x, b.y); o.u[3] = pkbf(b.z, b.w);
    *(ushortx8*)(dst + i) = o.s;
}

// ---------------------------------------------------------------------------
// MFMA GEMM core: 128x128 tile, BK=32, 4 waves each computing 64x64.
// TRIPLE-buffered LDS, prefetch depth 2 (T3/T4): at the top of iter k the
// tile-k DMAs are TWO compute bodies old (~matches HBM latency), and the
// wait is counted vmcnt(4) -- tile k+1's loads stay in flight across the
// barrier. Buffer (k+2)%3 overwrite is safe: the barrier is reached only
// after all waves consumed buffer (k-1)%3 into registers.
// ---------------------------------------------------------------------------
#define TM 128
#define TN 128
#define TK 32

// GEMM1: QKV projection. Outputs:
//   Qb [row][1024]  Q * 0.125*log2e (bf16)
//   Kd [row][1024]  K (bf16), dense rows for contiguous global_load_lds
//   V5 fragment-packed V'^T (e^mask folded): element (b,n,kt32,s,d) at
//     ((b*16+n)*32+kt32)*4096 + (ks*16+dt*4+q2)*128 + dl*8 + hi*4 + r
//     with kg=s>>2, r=s&3, ks=kg>>3, q2=kg&3, hi=(kg>>2)&1, dt=d>>4, dl=d&15.
//   => per-lane PV fragment offset within a tile is lane*8 shorts (linear),
//      so attention can DMA whole V tiles into LDS and ds_read conflict-free.
__global__ __launch_bounds__(256) void gemm_mfma_qkv(
    const unsigned short* __restrict__ A, const unsigned short* __restrict__ Bw,
    const float* __restrict__ bias, const float* __restrict__ mask,
    unsigned short* __restrict__ Qb, unsigned short* __restrict__ Kd,
    unsigned short* __restrict__ V5, int K)
{
    __shared__ unsigned short As[3][TM][TK];   // 24 KB
    __shared__ unsigned short Bs[3][TN][TK];   // 24 KB

    const int tid = threadIdx.x;
    const int w = tid >> 6, lane = tid & 63;
    const int l15 = lane & 15, quad = lane >> 4;
    const int wr = (w & 1) * 64;
    const int wc = (w >> 1) * 64;
    const int row0 = blockIdx.y * TM;
    const int col0 = blockIdx.x * TN;

    const int srow16 = lane >> 2;
    const int sgd    = lane & 3;
    const int sgsrc  = (sgd ^ swz(srow16)) * 8;

    floatx4 acc[4][4];
    #pragma unroll
    for (int i = 0; i < 4; i++)
        #pragma unroll
        for (int j = 0; j < 4; j++) acc[i][j] = (floatx4){0.f,0.f,0.f,0.f};

    const int aswz = swz(l15) * 8;
    const int NK = K / TK;

    // prologue: stage tiles 0,1 into buffers 0,1
    #pragma unroll
    for (int t = 0; t < 2; t++) {
        #pragma unroll
        for (int c = 0; c < 2; c++) {
            int seg = w * 2 + c;
            int r = seg * 16 + srow16;
            gload16(A  + (size_t)(row0 + r) * K + t * TK + sgsrc, &As[t][seg * 16][0]);
            gload16(Bw + (size_t)(col0 + r) * K + t * TK + sgsrc, &Bs[t][seg * 16][0]);
        }
    }

    #pragma unroll 1
    for (int k = 0; k < NK; ++k) {
        if (k + 1 < NK) asm volatile("s_waitcnt vmcnt(4)" ::: "memory");
        else            asm volatile("s_waitcnt vmcnt(0)" ::: "memory");
        __builtin_amdgcn_s_barrier();
        __builtin_amdgcn_sched_barrier(0);

        const int cur = k % 3;
        if (k + 2 < NK) {                                  // prefetch tile k+2
            const int nb  = (k + 2) % 3;
            const int k0n = (k + 2) * TK;
            #pragma unroll
            for (int c = 0; c < 2; c++) {
                int seg = w * 2 + c;
                int r = seg * 16 + srow16;
                gload16(A  + (size_t)(row0 + r) * K + k0n + sgsrc, &As[nb][seg * 16][0]);
                gload16(Bw + (size_t)(col0 + r) * K + k0n + sgsrc, &Bs[nb][seg * 16][0]);
            }
        }
        __builtin_amdgcn_sched_barrier(0);

        short8 af[4], bf[4];
        #pragma unroll
        for (int i = 0; i < 4; i++)
            af[i] = *(const short8*)&As[cur][wr + i * 16 + l15][(quad * 8) ^ aswz];
        #pragma unroll
        for (int j = 0; j < 4; j++)
            bf[j] = *(const short8*)&Bs[cur][wc + j * 16 + l15][(quad * 8) ^ aswz];
        __builtin_amdgcn_s_setprio(1);
        #pragma unroll
        for (int i = 0; i < 4; i++)
            #pragma unroll
            for (int j = 0; j < 4; j++)
                acc[i][j] = __builtin_amdgcn_mfma_f32_16x16x32_bf16(af[i], bf[j], acc[i][j], 0, 0, 0);
        __builtin_amdgcn_s_setprio(0);
    }

    const int cls = col0 >> 10;    // 0=Q, 1=K, 2=V; uniform per block

    if (cls == 2) {
        #pragma unroll
        for (int i = 0; i < 4; i++) {
            const int rb = row0 + wr + i * 16 + quad * 4;
            const int b  = rb >> 11;
            const int s  = rb & (Sq - 1);
            const int kt32 = s >> 6;
            const int sw   = s & 63;
            const int kg   = sw >> 2;          // s&3 == 0 (rb % 4 == 0)
            const int ks   = kg >> 3;
            const int q2   = kg & 3;
            const int hi   = (kg >> 2) & 1;
            float expm[4];
            #pragma unroll
            for (int rr = 0; rr < 4; rr++)
                expm[rr] = fexp2(mask[(size_t)b * Sq + s + rr] * LOG2E);
            #pragma unroll
            for (int j = 0; j < 4; j++) {
                const int c  = col0 + wc + j * 16 + l15;
                const int c2 = c - 2 * Hq;           // n*64+d
                const int n  = c2 >> 6, d = c2 & 63;
                const int dt = d >> 4, dl = d & 15;
                const float bia = bias[c];
                ushortx4 o;
                #pragma unroll
                for (int rr = 0; rr < 4; rr++)
                    o[rr] = f2bf((acc[i][j][rr] + bia) * expm[rr]);
                const size_t off = (((size_t)(b * Nq + n) * 32 + kt32) << 12)
                                 + (size_t)((ks * 16 + dt * 4 + q2) * 128 + dl * 8 + hi * 4);
                *(ushortx4*)&V5[off] = o;
            }
        }
    } else {
        unsigned short* __restrict__ dst = (cls == 0) ? Qb : Kd;
        const int cshift = (cls == 0) ? 0 : Hq;
        const float qs = (cls == 0) ? (0.125f * LOG2E) : 1.0f;
        #pragma unroll
        for (int i = 0; i < 4; i++) {
            const int rb = row0 + wr + i * 16 + quad * 4;
            #pragma unroll
            for (int j = 0; j < 4; j++) {
                const int c = col0 + wc + j * 16 + l15;
                const float bia = bias[c];
                #pragma unroll
                for (int rr = 0; rr < 4; rr++)
                    dst[(size_t)(rb + rr) * Hq + (c - cshift)] =
                        f2bf((acc[i][j][rr] + bia) * qs);
            }
        }
    }
}

// GEMM2: x = A*Bw^T + bias + residual -> bf16 (LN reads bf16, stats in fp32)
__global__ __launch_bounds__(256) void gemm_mfma_out(
    const unsigned short* __restrict__ A, const unsigned short* __restrict__ Bw,
    const float* __restrict__ bias, const float* __restrict__ res,
    unsigned short* __restrict__ X, int M, int Nd, int K)
{
    __shared__ unsigned short As[3][TM][TK];
    __shared__ unsigned short Bs[3][TN][TK];

    const int tid = threadIdx.x;
    const int w = tid >> 6, lane = tid & 63;
    const int l15 = lane & 15, quad = lane >> 4;
    const int wr = (w & 1) * 64;
    const int wc = (w >> 1) * 64;
    const int row0 = blockIdx.y * TM;
    const int col0 = blockIdx.x * TN;

    const int srow16 = lane >> 2;
    const int sgd    = lane & 3;
    const int sgsrc  = (sgd ^ swz(srow16)) * 8;

    floatx4 acc[4][4];
    #pragma unroll
    for (int i = 0; i < 4; i++)
        #pragma unroll
        for (int j = 0; j < 4; j++) acc[i][j] = (floatx4){0.f,0.f,0.f,0.f};

    const int aswz = swz(l15) * 8;
    const int NK = K / TK;

    #pragma unroll
    for (int t = 0; t < 2; t++) {
        #pragma unroll
        for (int c = 0; c < 2; c++) {
            int seg = w * 2 + c;
            int r = seg * 16 + srow16;
            gload16(A  + (size_t)(row0 + r) * K + t * TK + sgsrc, &As[t][seg * 16][0]);
            gload16(Bw + (size_t)(col0 + r) * K + t * TK + sgsrc, &Bs[t][seg * 16][0]);
        }
    }

    #pragma unroll 1
    for (int k = 0; k < NK; ++k) {
        if (k + 1 < NK) asm volatile("s_waitcnt vmcnt(4)" ::: "memory");
        else            asm volatile("s_waitcnt vmcnt(0)" ::: "memory");
        __builtin_amdgcn_s_barrier();
        __builtin_amdgcn_sched_barrier(0);

        const int cur = k % 3;
        if (k + 2 < NK) {
            const int nb  = (k + 2) % 3;
            const int k0n = (k + 2) * TK;
            #pragma unroll
            for (int c = 0; c < 2; c++) {
                int seg = w * 2 + c;
                int r = seg * 16 + srow16;
                gload16(A  + (size_t)(row0 + r) * K + k0n + sgsrc, &As[nb][seg * 16][0]);
                gload16(Bw + (size_t)(col0 + r) * K + k0n + sgsrc, &Bs[nb][seg * 16][0]);
            }
        }
        __builtin_amdgcn_sched_barrier(0);

        short8 af[4], bf[4];
        #pragma unroll
        for (int i = 0; i < 4; i++)
            af[i] = *(const short8*)&As[cur][wr + i * 16 + l15][(quad * 8) ^ aswz];
        #pragma unroll
        for (int j = 0; j < 4; j++)
            bf[j] = *(const short8*)&Bs[cur][wc + j * 16 + l15][(quad * 8) ^ aswz];
        __builtin_amdgcn_s_setprio(1);
        #pragma unroll
        for (int i = 0; i < 4; i++)
            #pragma unroll
            for (int j = 0; j < 4; j++)
                acc[i][j] = __builtin_amdgcn_mfma_f32_16x16x32_bf16(af[i], bf[j], acc[i][j], 0, 0, 0);
        __builtin_amdgcn_s_setprio(0);
    }

    #pragma unroll
    for (int i = 0; i < 4; i++) {
        const int rb = row0 + wr + i * 16 + quad * 4;
        #pragma unroll
        for (int j = 0; j < 4; j++) {
            const int c = col0 + wc + j * 16 + l15;
            const float bia = bias[c];
            #pragma unroll
            for (int rr = 0; rr < 4; rr++) {
                X[(size_t)(rb + rr) * Nd + c] =
                    f2bf(acc[i][j][rr] + bia + res[(size_t)(rb + rr) * Nd + c]);
            }
        }
    }
}

// ---------------------------------------------------------------------------
// Grid-split-K MFMA flash attention, XCD-clustered, V STAGED THROUGH LDS:
// round 7 showed FETCH 73.8->16.5 MB but time up -- HBM was never the stall;
// the per-wave direct V-fragment loads amplified L2 reads 4x (each of 4
// waves reads the whole 8 KB V tile). Now V tiles are DMA'd once per block
// via global_load_lds (fragment-packed layout is lane-linear: per-lane
// offset = lane*8 shorts), triple-buffered, and PV reads are conflict-free
// ds_read_b128 at base + i*1024B + lane*16B. Block L2 traffic per tile:
// 40 KB -> 16 KB. K path and cross-tile pipeline unchanged.
// Buffer safety: body kt DMAs V(kt+1)->Vs[(kt+1)%3], PV reads Vs[(kt-1)%3],
// QK epoch owns Vs[kt%3] -- pairwise distinct; barrier orders across waves.
// ---------------------------------------------------------------------------
#define KTILES 16   // 64-key tiles per z-half

__device__ __forceinline__ floatx4 mfma16(short8 a, short8 b, floatx4 c) {
    return __builtin_amdgcn_mfma_f32_16x16x32_bf16(a, b, c, 0, 0, 0);
}

// l-MFMA + PV for the PREVIOUS tile; V fragments read from LDS (Vt = tile
// base + lane*8, conflict-free b128 at stride 1024B)
__device__ __forceinline__ void do_lpv(
    const short8 (&pf0)[2], const short8 (&pf1)[2], const short8 (&mf)[2],
    const unsigned short* Vt,
    floatx4 (&oacc0)[4], floatx4 (&oacc1)[4],
    floatx4 &lacc0, floatx4 &lacc1)
{
    __builtin_amdgcn_s_setprio(1);
    lacc0 = mfma16(mf[0], pf0[0], lacc0);
    lacc0 = mfma16(mf[1], pf0[1], lacc0);
    lacc1 = mfma16(mf[0], pf1[0], lacc1);
    lacc1 = mfma16(mf[1], pf1[1], lacc1);
    #pragma unroll
    for (int dt = 0; dt < 4; dt++) {
        short8 vlo = *(const short8*)(Vt + dt * 512);
        short8 vhi = *(const short8*)(Vt + 2048 + dt * 512);
        oacc0[dt] = mfma16(vlo, pf0[0], oacc0[dt]);
        oacc1[dt] = mfma16(vlo, pf1[0], oacc1[dt]);
        oacc0[dt] = mfma16(vhi, pf0[1], oacc0[dt]);
        oacc1[dt] = mfma16(vhi, pf1[1], oacc1[dt]);
    }
    __builtin_amdgcn_s_setprio(0);
}

template<bool HAVER, bool PREF>
__device__ __forceinline__ void attn_body(
    int kt,
    unsigned short (&KsL)[2][64][64],
    unsigned short (&VsL)[3][4096],
    const unsigned short* kp, size_t kstep,
    const unsigned short* Vb, const unsigned short* e2b,
    int w, int l15, int quad, int lane,
    const short8 (&qf0)[2], const short8 (&qf1)[2],
    const short8 (&pfR0)[2], const short8 (&pfR1)[2], const short8 (&mfR)[2],
    short8 (&pfW0)[2], short8 (&pfW1)[2], short8 (&mfW)[2],
    floatx4 (&oacc0)[4], floatx4 (&oacc1)[4],
    floatx4 &lacc0, floatx4 &lacc1)
{
    asm volatile("s_waitcnt vmcnt(0)" ::: "memory");   // K(kt),V(kt) landed
    __builtin_amdgcn_s_barrier();                      // all waves' DMAs landed
    __builtin_amdgcn_sched_barrier(0);

    if (PREF) {
        // K(kt+1): wave w stages its 16 rows (2 x 1KB)
        const unsigned short* kpn = kp + (size_t)(kt + 1) * kstep;
        gload16(kpn,                  &KsL[(kt + 1) & 1][w * 16][0]);
        gload16(kpn + (size_t)8 * Hq, &KsL[(kt + 1) & 1][w * 16 + 8][0]);
        // V(kt+1): wave w stages its 2KB quarter (linear copy of V5 tile)
        const unsigned short* vpn = Vb + (size_t)(kt + 1) * 4096 + w * 1024 + lane * 8;
        unsigned short* vd = &VsL[(kt + 1) % 3][w * 1024];
        gload16(vpn,       vd);
        gload16(vpn + 512, vd + 512);
    }
    __builtin_amdgcn_sched_barrier(0);   // pin DMAs as oldest outstanding

    // mf for THIS tile (consumed next body): direct loads, final order
    const unsigned short* ep = e2b + kt * 64;
    mfW[0] = *(const short8*)(ep + quad * 8);
    mfW[1] = *(const short8*)(ep + 32 + quad * 8);

    // ---- QK(kt): S^T = K Q^T for both subtiles
    floatx4 s0[4], s1[4];
    #pragma unroll
    for (int ct = 0; ct < 4; ct++) {
        s0[ct] = (floatx4){0.f,0.f,0.f,0.f};
        s1[ct] = (floatx4){0.f,0.f,0.f,0.f};
    }
    __builtin_amdgcn_s_setprio(1);
    #pragma unroll
    for (int ks = 0; ks < 2; ks++) {
        #pragma unroll
        for (int ct = 0; ct < 4; ct++) {
            short8 af = *(const short8*)&KsL[kt & 1][ct * 16 + l15][((4 * ks + quad) ^ (l15 & 7)) * 8];
            s0[ct] = mfma16(af, qf0[ks], s0[ct]);
            s1[ct] = mfma16(af, qf1[ks], s1[ct]);
        }
    }
    __builtin_amdgcn_s_setprio(0);

    // ---- softmax(kt) -> pfW (exp2-only via raw v_exp_f32; mask in V'/mf)
    #pragma unroll
    for (int ks = 0; ks < 2; ks++) {
        union { unsigned int u[4]; short8 s; } pk;
        #pragma unroll
        for (int h = 0; h < 2; h++) {
            const int ct = ks * 2 + h;
            pk.u[h * 2]     = pkbf(fexp2(s0[ct][0]), fexp2(s0[ct][1]));
            pk.u[h * 2 + 1] = pkbf(fexp2(s0[ct][2]), fexp2(s0[ct][3]));
        }
        pfW0[ks] = pk.s;
    }
    #pragma unroll
    for (int ks = 0; ks < 2; ks++) {
        union { unsigned int u[4]; short8 s; } pk;
        #pragma unroll
        for (int h = 0; h < 2; h++) {
            const int ct = ks * 2 + h;
            pk.u[h * 2]     = pkbf(fexp2(s1[ct][0]), fexp2(s1[ct][1]));
            pk.u[h * 2 + 1] = pkbf(fexp2(s1[ct][2]), fexp2(s1[ct][3]));
        }
        pfW1[ks] = pk.s;
    }

    // ---- l + PV for tile kt-1 from LDS (overlaps the exp2 chain above)
    if (HAVER)
        do_lpv(pfR0, pfR1, mfR, &VsL[(kt - 1) % 3][0] + lane * 8,
               oacc0, oacc1, lacc0, lacc1);
}

__global__ __launch_bounds__(256) void attn_mfma(
    const unsigned short* __restrict__ Qb, const unsigned short* __restrict__ Kd,
    const unsigned short* __restrict__ V5, const unsigned short* __restrict__ em2,
    unsigned short* __restrict__ Opart, float* __restrict__ Lpart)
{
    __shared__ unsigned short Ks[2][64][64];   // 16 KB [buf][key][d], src-swizzled
    __shared__ unsigned short Vs[3][4096];     // 24 KB fragment-packed V tiles

    const int tid  = threadIdx.x;
    const int w    = tid >> 6;
    const int lane = tid & 63;
    const int l15  = lane & 15;
    const int quad = lane >> 4;

    // XCD-clustering decode: all 16 qtiles of group g=(bn,z) share K/V and
    // land on XCD g%8 (dispatch round-robins linear id across 8 XCDs).
    const int i_    = blockIdx.x;
    const int gl8   = i_ & 7;
    const int rest  = i_ >> 3;
    const int qtile = rest & 15;          // 0..15 (128 queries each)
    const int g     = (rest >> 4) * 8 + gl8;   // 0..63
    const int bn    = g >> 1;
    const int z     = g & 1;
    const int n     = bn & 15;
    const int b     = bn >> 4;

    const int kbase = z * (KTILES * 64);

    // Q B-fragments for both subtiles (n=l15 -> query row, k=quad*8+j)
    short8 qf0[2], qf1[2];
    {
        const int qrow0 = qtile * 128 + w * 16 + l15;
        const unsigned short* qp = Qb + (size_t)(b * Sq + qrow0) * Hq + n * HNq + quad * 8;
        qf0[0] = *(const short8*)(qp);
        qf0[1] = *(const short8*)(qp + 32);
        qp += (size_t)64 * Hq;
        qf1[0] = *(const short8*)(qp);
        qf1[1] = *(const short8*)(qp + 32);
    }

    floatx4 oacc0[4], oacc1[4];   // O^T per subtile: d = dt*16+quad*4+r, q=l15
    #pragma unroll
    for (int dt = 0; dt < 4; dt++) {
        oacc0[dt] = (floatx4){0.f,0.f,0.f,0.f};
        oacc1[dt] = (floatx4){0.f,0.f,0.f,0.f};
    }
    floatx4 lacc0 = (floatx4){0.f,0.f,0.f,0.f};
    floatx4 lacc1 = (floatx4){0.f,0.f,0.f,0.f};

    // K DMA geometry: wave w stages rows w*16..w*16+15 via 2 global_load_lds.
    const int krow8 = lane >> 3;               // 0..7
    const int kgr   = (lane & 7) ^ (krow8 & 7);
    const unsigned short* kp = Kd + (size_t)(b * Sq + kbase + w * 16 + krow8) * Hq
                                  + n * HNq + kgr * 8;
    const size_t kstep = (size_t)64 * Hq;

    // fragment-packed V base + permuted mask base
    const unsigned short* Vb  = V5 + ((size_t)(b * Nq + n) * 32 + z * KTILES) * 4096;
    const unsigned short* e2b = em2 + (size_t)(b * 32 + z * KTILES) * 64;

    // prologue: K(0) -> Ks[0], V(0) -> Vs[0]
    gload16(kp,                  &Ks[0][w * 16][0]);
    gload16(kp + (size_t)8 * Hq, &Ks[0][w * 16 + 8][0]);
    {
        const unsigned short* vp0 = Vb + w * 1024 + lane * 8;
        gload16(vp0,       &Vs[0][w * 1024]);
        gload16(vp0 + 512, &Vs[0][w * 1024] + 512);
    }

    // pipeline state (two named stages, no dynamic indexing)
    short8 pfA0[2], pfA1[2], mfA[2];
    short8 pfB0[2], pfB1[2], mfB[2];

    // peel kt=0: fills stage A; no PV yet
    attn_body<false, true>(0, Ks, Vs, kp, kstep, Vb, e2b, w, l15, quad, lane,
        qf0, qf1, pfB0, pfB1, mfB, pfA0, pfA1, mfA, oacc0, oacc1, lacc0, lacc1);

    #pragma unroll 1
    for (int kt = 1; kt < KTILES - 1; kt += 2) {
        attn_body<true, true>(kt, Ks, Vs, kp, kstep, Vb, e2b, w, l15, quad, lane,
            qf0, qf1, pfA0, pfA1, mfA, pfB0, pfB1, mfB, oacc0, oacc1, lacc0, lacc1);
        attn_body<true, true>(kt + 1, Ks, Vs, kp, kstep, Vb, e2b, w, l15, quad, lane,
            qf0, qf1, pfB0, pfB1, mfB, pfA0, pfA1, mfA, oacc0, oacc1, lacc0, lacc1);
    }
    // kt = 15 (odd): reads A, writes B, no prefetch
    attn_body<true, false>(KTILES - 1, Ks, Vs, kp, kstep, Vb, e2b, w, l15, quad, lane,
        qf0, qf1, pfA0, pfA1, mfA, pfB0, pfB1, mfB, oacc0, oacc1, lacc0, lacc1);
    // drain: l + PV of tile 15 (stage B, V(15) in Vs[15%3 = 0])
    do_lpv(pfB0, pfB1, mfB, &Vs[(KTILES - 1) % 3][0] + lane * 8,
           oacc0, oacc1, lacc0, lacc1);

    // ---- epilogue: un-normalized partial O (bf16) + per-query l (no shfls:
    // every row of lacc holds l_q for q=l15)
    unsigned short* Ow = Opart + (size_t)z * Mq * Hq;
    #pragma unroll
    for (int sub = 0; sub < 2; sub++) {
        const float l_i = sub ? lacc1[0] : lacc0[0];
        const int qrow = qtile * 128 + sub * 64 + w * 16 + l15;
        if (quad == 0)
            Lpart[(size_t)z * Mq * Nq + (size_t)(b * Sq + qrow) * Nq + n] = l_i;
        #pragma unroll
        for (int dt = 0; dt < 4; dt++) {
            const floatx4 oa = sub ? oacc1[dt] : oacc0[dt];
            union { unsigned int u[2]; ushortx4 s; } o;
            o.u[0] = pkbf(oa[0], oa[1]);
            o.u[1] = pkbf(oa[2], oa[3]);
            const int col = n * HNq + dt * 16 + quad * 4;
            *(ushortx4*)&Ow[(size_t)(b * Sq + qrow) * Hq + col] = o.s;
        }
    }
}

// ---------------------------------------------------------------------------
// Merge the two split-K halves: ctx = (O0 + O1) / (l0 + l1), bf16 out.
// ---------------------------------------------------------------------------
__global__ __launch_bounds__(256) void attn_merge(
    const unsigned short* __restrict__ Opart, const float* __restrict__ Lpart,
    unsigned short* __restrict__ ctx)
{
    const size_t idx = ((size_t)blockIdx.x * 256 + threadIdx.x) * 4;
    const int row = (int)(idx >> 10);          // b*Sq + s
    const int n   = ((int)idx >> 6) & 15;
    const float l = Lpart[(size_t)row * Nq + n]
                  + Lpart[(size_t)Mq * Nq + (size_t)row * Nq + n];
    const float inv = 1.0f / l;
    ushortx4 a = *(const ushortx4*)(Opart + idx);
    ushortx4 c = *(const ushortx4*)(Opart + (size_t)Mq * Hq + idx);
    union { unsigned int u[2]; ushortx4 s; } o;
    o.u[0] = pkbf((bf2f(a[0]) + bf2f(c[0])) * inv, (bf2f(a[1]) + bf2f(c[1])) * inv);
    o.u[1] = pkbf((bf2f(a[2]) + bf2f(c[2])) * inv, (bf2f(a[3]) + bf2f(c[3])) * inv);
    *(ushortx4*)(ctx + idx) = o.s;
}

// ---------------------------------------------------------------------------
// Row LayerNorm over H=1024, bf16 input, fp32 stats, fp32 output.
// ---------------------------------------------------------------------------
__global__ __launch_bounds__(256) void ln_kernel(
    const unsigned short* __restrict__ X, const float* __restrict__ gamma,
    const float* __restrict__ beta, float* __restrict__ out)
{
    const int row = blockIdx.x;
    const int c0  = threadIdx.x * 4;
    ushortx4 xv = *(const ushortx4*)(X + (size_t)row * Hq + c0);
    float vals[4];
    float lsum = 0.0f;
    #pragma unroll
    for (int i = 0; i < 4; i++) { vals[i] = bf2f(xv[i]); lsum += vals[i]; }

    __shared__ float red[8];
    const int wid = threadIdx.x >> 6, lane = threadIdx.x & 63;

    float s = lsum;
    #pragma unroll
    for (int off = 32; off >= 1; off >>= 1) s += __shfl_xor(s, off, 64);
    if (lane == 0) red[wid] = s;
    __syncthreads();
    const float mean = (red[0] + red[1] + red[2] + red[3]) * (1.0f / Hq);

    float v = 0.0f;
    #pragma unroll
    for (int i = 0; i < 4; i++) { float d = vals[i] - mean; v += d * d; }
    #pragma unroll
    for (int off = 32; off >= 1; off >>= 1) v += __shfl_xor(v, off, 64);
    if (lane == 0) red[4 + wid] = v;
    __syncthreads();
    const float var  = (red[4] + red[5] + red[6] + red[7]) * (1.0f / Hq);
    const float rstd = rsqrtf(var + 1e-12f);

    float4 gm = *(const float4*)(gamma + c0);
    float4 bt = *(const float4*)(beta + c0);
    float4 o;
    o.x = (vals[0] - mean) * rstd * gm.x + bt.x;
    o.y = (vals[1] - mean) * rstd * gm.y + bt.y;
    o.z = (vals[2] - mean) * rstd * gm.z + bt.z;
    o.w = (vals[3] - mean) * rstd * gm.w + bt.w;
    *(float4*)(out + (size_t)row * Hq + c0) = o;
}

// ---------------------------------------------------------------------------
extern "C" void kernel_launch(void* const* d_in, const int* in_sizes, int n_in,
                              void* d_out, int out_size, void* d_ws, size_t ws_size,
                              hipStream_t stream)
{
    const float* hidden = (const float*)d_in[0];
    const float* mask   = (const float*)d_in[1];
    const float* W_qkv  = (const float*)d_in[2];
    const float* b_qkv  = (const float*)d_in[3];
    const float* W_out  = (const float*)d_in[4];
    const float* b_out  = (const float*)d_in[5];
    const float* gamma  = (const float*)d_in[6];
    const float* beta   = (const float*)d_in[7];
    float* out = (float*)d_out;

    const size_t nHid  = (size_t)Mq * Hq;        // 4 M
    const size_t nWq   = (size_t)H3q * Hq;       // 3 M
    const size_t nWo   = (size_t)Hq * Hq;        // 1 M
    const size_t nCtx  = (size_t)Mq * Hq;        // 4 M

    unsigned short* hidden_bf = (unsigned short*)d_ws;
    unsigned short* Wqkv_bf   = hidden_bf + nHid;
    unsigned short* Wout_bf   = Wqkv_bf + nWq;
    unsigned short* qb        = Wout_bf + nWo;          // Q  [4096][1024]
    unsigned short* kd        = qb + nHid;              // K  [4096][1024]
    unsigned short* v5        = kd + nHid;              // V' fragment-packed, 4 M
    unsigned short* ctx_bf    = v5 + nHid;
    unsigned short* x_bf      = ctx_bf + nCtx;
    unsigned short* opart     = x_bf + nHid;            // 2 * 4M bf16 = 16 MB
    float*          lpart     = (float*)(opart + 2 * nHid);  // 2*64K floats
    unsigned short* em2       = (unsigned short*)(lpart + 2 * (size_t)Mq * Nq);

    dim3 blk(256);

    // 0) fused fp32 -> bf16 cast + permuted expmask table (one kernel)
    cvt_all<<<dim3(CVT_BLKS + 2), blk, 0, stream>>>(
        hidden, W_qkv, W_out, mask, hidden_bf, em2);

    // 1) QKV projection (MFMA, depth-2 pipelined staging) -> Qb / Kd / V5
    gemm_mfma_qkv<<<dim3(H3q / TN, Mq / TM), blk, 0, stream>>>(
        hidden_bf, Wqkv_bf, b_qkv, mask, qb, kd, v5, Hq);

    // 2) Pipelined flash attention, XCD-clustered, V via LDS -> partial O/l
    attn_mfma<<<dim3(1024), blk, 0, stream>>>(
        qb, kd, v5, em2, opart, lpart);

    // 2b) merge halves -> ctx bf16
    attn_merge<<<dim3((int)(nCtx / 1024)), blk, 0, stream>>>(
        opart, lpart, ctx_bf);

    // 3) Output projection (MFMA, depth-2 pipelined staging) + residual -> x bf16
    gemm_mfma_out<<<dim3(Hq / TN, Mq / TM), blk, 0, stream>>>(
        ctx_bf, Wout_bf, b_out, hidden, x_bf, Mq, Hq, Hq);

    // 4) LayerNorm: bf16 x -> fp32 out
    ln_kernel<<<dim3(Mq), blk, 0, stream>>>(x_bf, gamma, beta, out);
}

// Round 9
// 202.760 us; speedup vs baseline: 1.2444x; 1.0028x over previous
//
#include <hip/hip_runtime.h>
#include <hip/hip_bf16.h>
#include <math.h>

// Problem constants
#define Bq  2
#define Sq  2048
#define Hq  1024
#define Nq  16
#define HNq 64
#define Mq  (Bq*Sq)        // 4096 rows
#define H3q (3*Hq)         // 3072

#define LOG2E 1.44269504088896340736f

typedef __attribute__((ext_vector_type(8))) short           short8;
typedef __attribute__((ext_vector_type(4))) short           short4s;
typedef __attribute__((ext_vector_type(8))) unsigned short  ushortx8;
typedef __attribute__((ext_vector_type(4))) unsigned short  ushortx4;
typedef __attribute__((ext_vector_type(4))) float           floatx4;

__device__ __forceinline__ unsigned short f2bf(float f) {
    union { float f; unsigned int u; } x; x.f = f;
    unsigned int r = (x.u + 0x7fffu + ((x.u >> 16) & 1u)) >> 16;
    return (unsigned short)r;
}

// packed fp32x2 -> bf16x2 (v_cvt_pk_bf16_f32 on gfx950); a in low 16 bits
__device__ __forceinline__ unsigned int pkbf(float a, float b) {
    float2 t; t.x = a; t.y = b;
    __hip_bfloat162 h = __float22bfloat162_rn(t);
    union { __hip_bfloat162 h; unsigned int u; } c; c.h = h;
    return c.u;
}

__device__ __forceinline__ float bf2f(unsigned short v) {
    union { unsigned int u; float f; } x; x.u = (unsigned int)v << 16;
    return x.f;
}

// raw v_exp_f32 (D = 2^S0): ONE transcendental op (libm exp2f is a guarded
// ~10-op sequence without fast-math -- was the hidden VALU hog).
__device__ __forceinline__ float fexp2(float x) {
    float r;
    asm("v_exp_f32 %0, %1" : "=v"(r) : "v"(x));
    return r;
}

// async global->LDS, 16B per lane; LDS dest = wave-uniform base + lane*16
__device__ __forceinline__ void gload16(const unsigned short* g, unsigned short* l) {
    __builtin_amdgcn_global_load_lds(
        (__attribute__((address_space(1))) void*)(unsigned long long)(g),
        (__attribute__((address_space(3))) void*)(unsigned int)(unsigned long long)(l),
        16, 0, 0);
}

// LDS bank swizzle: granule' = granule ^ swz(row mod 16); 2-way max conflict
__device__ __forceinline__ int swz(int r) { return (r ^ (r >> 2)) & 3; }

// ---------------------------------------------------------------------------
// Fused fp32 -> bf16 cast for hidden | W_qkv | W_out + permuted e^mask table
// em2[((b*32+kt)*2+ks)*32 + quad*8 + hi*4 + r]
//   = exp(mask[b][kt*64 + (2ks+hi)*16 + quad*4 + r])
// ---------------------------------------------------------------------------
#define N_HID ((size_t)Mq * Hq)          // 4194304
#define N_HW  (N_HID + (size_t)H3q * Hq) // 7340032
#define N_ALL (N_HW + (size_t)Hq * Hq)   // 8388608
#define CVT_BLKS ((int)(N_ALL / 2048))   // 4096

__global__ __launch_bounds__(256) void cvt_all(
    const float* __restrict__ hidden, const float* __restrict__ wqkv,
    const float* __restrict__ wout, const float* __restrict__ mask,
    unsigned short* __restrict__ dst, unsigned short* __restrict__ em2)
{
    const int bid = blockIdx.x;
    if (bid >= CVT_BLKS) {
        // ---- permuted e^mask table (2 blocks, 4096 outputs)
        const int t0   = ((bid - CVT_BLKS) * 256 + threadIdx.x) * 8;
        const int b    = t0 >> 11;
        const int t2   = t0 & 2047;
        const int kt   = t2 >> 6;
        const int t3   = t2 & 63;
        const int ks   = t3 >> 5;
        const int quad = (t3 >> 3) & 3;
        const int kb   = kt * 64 + ks * 32 + quad * 4;
        const float* mp = mask + (size_t)b * Sq + kb;
        float4 m0 = *(const float4*)(mp);
        float4 m1 = *(const float4*)(mp + 16);
        union { unsigned int u[4]; ushortx8 s; } o;
        o.u[0] = pkbf(fexp2(m0.x * LOG2E), fexp2(m0.y * LOG2E));
        o.u[1] = pkbf(fexp2(m0.z * LOG2E), fexp2(m0.w * LOG2E));
        o.u[2] = pkbf(fexp2(m1.x * LOG2E), fexp2(m1.y * LOG2E));
        o.u[3] = pkbf(fexp2(m1.z * LOG2E), fexp2(m1.w * LOG2E));
        *(ushortx8*)(em2 + t0) = o.s;
        return;
    }
    size_t i = ((size_t)bid * 256 + threadIdx.x) * 8;
    const float* src;
    if (i < N_HID)      src = hidden + i;
    else if (i < N_HW)  src = wqkv + (i - N_HID);
    else                src = wout + (i - N_HW);
    float4 a = *(const float4*)(src);
    float4 b = *(const float4*)(src + 4);
    union { unsigned int u[4]; ushortx8 s; } o;
    o.u[0] = pkbf(a.x, a.y); o.u[1] = pkbf(a.z, a.w);
    o.u[2] = pkbf(b.x, b.y); o.u[3] = pkbf(b.z, b.w);
    *(ushortx8*)(dst + i) = o.s;
}

// ---------------------------------------------------------------------------
// GEMM1: 256x128 tile, BK=32, 8 waves (512 thr) each computing 64x64.
// +33% arithmetic intensity vs 128^2 (outputs 256x128 per (256+128)x32
// staging); 3 gload16/wave/step; triple-buffered LDS (72 KB -> 2 blocks/CU,
// all 384 blocks co-resident); depth-2 prefetch with counted vmcnt(3).
// Outputs:
//   Qb [row][1024]  Q * 0.125*log2e (bf16), dense
//   K5 packed PRE-SWIZZLED K tiles: [b][n][kt32][r 64][g'*8+e] where
//     g' = (d>>3) ^ (r&7), d = g'*8+e column. Attention's K-DMA is then a
//     LINEAR lane*16B copy (same shape as V) and the LDS image is identical
//     to the old XOR-source-swizzled one, so the QK ds_read side is unchanged.
//   V5 fragment-packed V'^T (e^mask folded), lane-linear per tile.
// ---------------------------------------------------------------------------
#define TM 128
#define TN 128
#define TK 32
#define G1M 256

__global__ __launch_bounds__(512) void gemm_mfma_qkv(
    const unsigned short* __restrict__ A, const unsigned short* __restrict__ Bw,
    const float* __restrict__ bias, const float* __restrict__ mask,
    unsigned short* __restrict__ Qb, unsigned short* __restrict__ K5,
    unsigned short* __restrict__ V5, int K)
{
    __shared__ unsigned short As[3][G1M][TK];   // 48 KB
    __shared__ unsigned short Bs[3][TN][TK];    // 24 KB

    const int tid = threadIdx.x;
    const int w = tid >> 6, lane = tid & 63;
    const int l15 = lane & 15, quad = lane >> 4;
    const int wr = (w & 3) * 64;
    const int wc = (w >> 2) * 64;
    const int row0 = blockIdx.y * G1M;
    const int col0 = blockIdx.x * TN;

    const int srow16 = lane >> 2;
    const int sgd    = lane & 3;
    const int sgsrc  = (sgd ^ swz(srow16)) * 8;

    floatx4 acc[4][4];
    #pragma unroll
    for (int i = 0; i < 4; i++)
        #pragma unroll
        for (int j = 0; j < 4; j++) acc[i][j] = (floatx4){0.f,0.f,0.f,0.f};

    const int aswz = swz(l15) * 8;
    const int NK = K / TK;

    // prologue: stage tiles 0,1 (A: 2 segs/wave, B: 1 seg/wave)
    #pragma unroll
    for (int t = 0; t < 2; t++) {
        #pragma unroll
        for (int c = 0; c < 2; c++) {
            int seg = w * 2 + c;
            int r = seg * 16 + srow16;
            gload16(A + (size_t)(row0 + r) * K + t * TK + sgsrc, &As[t][seg * 16][0]);
        }
        int rB = w * 16 + srow16;
        gload16(Bw + (size_t)(col0 + rB) * K + t * TK + sgsrc, &Bs[t][w * 16][0]);
    }

    #pragma unroll 1
    for (int k = 0; k < NK; ++k) {
        if (k + 1 < NK) asm volatile("s_waitcnt vmcnt(3)" ::: "memory");
        else            asm volatile("s_waitcnt vmcnt(0)" ::: "memory");
        __builtin_amdgcn_s_barrier();
        __builtin_amdgcn_sched_barrier(0);

        const int cur = k % 3;
        if (k + 2 < NK) {                                  // prefetch tile k+2
            const int nb  = (k + 2) % 3;
            const int k0n = (k + 2) * TK;
            #pragma unroll
            for (int c = 0; c < 2; c++) {
                int seg = w * 2 + c;
                int r = seg * 16 + srow16;
                gload16(A + (size_t)(row0 + r) * K + k0n + sgsrc, &As[nb][seg * 16][0]);
            }
            int rB = w * 16 + srow16;
            gload16(Bw + (size_t)(col0 + rB) * K + k0n + sgsrc, &Bs[nb][w * 16][0]);
        }
        __builtin_amdgcn_sched_barrier(0);

        short8 af[4], bf[4];
        #pragma unroll
        for (int i = 0; i < 4; i++)
            af[i] = *(const short8*)&As[cur][wr + i * 16 + l15][(quad * 8) ^ aswz];
        #pragma unroll
        for (int j = 0; j < 4; j++)
            bf[j] = *(const short8*)&Bs[cur][wc + j * 16 + l15][(quad * 8) ^ aswz];
        __builtin_amdgcn_s_setprio(1);
        #pragma unroll
        for (int i = 0; i < 4; i++)
            #pragma unroll
            for (int j = 0; j < 4; j++)
                acc[i][j] = __builtin_amdgcn_mfma_f32_16x16x32_bf16(af[i], bf[j], acc[i][j], 0, 0, 0);
        __builtin_amdgcn_s_setprio(0);
    }

    const int cls = col0 >> 10;    // 0=Q, 1=K, 2=V; uniform per block

    if (cls == 2) {
        #pragma unroll
        for (int i = 0; i < 4; i++) {
            const int rb = row0 + wr + i * 16 + quad * 4;
            const int b  = rb >> 11;
            const int s  = rb & (Sq - 1);
            const int kt32 = s >> 6;
            const int sw   = s & 63;
            const int kg   = sw >> 2;          // s&3 == 0 (rb % 4 == 0)
            const int ks   = kg >> 3;
            const int q2   = kg & 3;
            const int hi   = (kg >> 2) & 1;
            float expm[4];
            #pragma unroll
            for (int rr = 0; rr < 4; rr++)
                expm[rr] = fexp2(mask[(size_t)b * Sq + s + rr] * LOG2E);
            #pragma unroll
            for (int j = 0; j < 4; j++) {
                const int c  = col0 + wc + j * 16 + l15;
                const int c2 = c - 2 * Hq;           // n*64+d
                const int n  = c2 >> 6, d = c2 & 63;
                const int dt = d >> 4, dl = d & 15;
                const float bia = bias[c];
                ushortx4 o;
                #pragma unroll
                for (int rr = 0; rr < 4; rr++)
                    o[rr] = f2bf((acc[i][j][rr] + bia) * expm[rr]);
                const size_t off = (((size_t)(b * Nq + n) * 32 + kt32) << 12)
                                 + (size_t)((ks * 16 + dt * 4 + q2) * 128 + dl * 8 + hi * 4);
                *(ushortx4*)&V5[off] = o;
            }
        }
    } else if (cls == 1) {
        // K packed pre-swizzled: K5[(b*16+n)*32+kt32][r][((d>>3)^(r&7))*8+(d&7)]
        #pragma unroll
        for (int i = 0; i < 4; i++) {
            const int rb = row0 + wr + i * 16 + quad * 4;
            #pragma unroll
            for (int j = 0; j < 4; j++) {
                const int c  = col0 + wc + j * 16 + l15;
                const int c2 = c - Hq;               // n*64+d
                const int n  = c2 >> 6, d = c2 & 63;
                const float bia = bias[c];
                #pragma unroll
                for (int rr = 0; rr < 4; rr++) {
                    const int srow = rb + rr;
                    const int b    = srow >> 11;
                    const int s    = srow & (Sq - 1);
                    const int kt32 = s >> 6;
                    const int r    = s & 63;
                    const size_t off = (((size_t)(b * Nq + n) * 32 + kt32) << 12)
                                     + (size_t)(r * 64 + (((d >> 3) ^ (r & 7)) * 8 + (d & 7)));
                    K5[off] = f2bf(acc[i][j][rr] + bia);
                }
            }
        }
    } else {
        const float qs = 0.125f * LOG2E;
        #pragma unroll
        for (int i = 0; i < 4; i++) {
            const int rb = row0 + wr + i * 16 + quad * 4;
            #pragma unroll
            for (int j = 0; j < 4; j++) {
                const int c = col0 + wc + j * 16 + l15;
                const float bia = bias[c];
                #pragma unroll
                for (int rr = 0; rr < 4; rr++)
                    Qb[(size_t)(rb + rr) * Hq + c] =
                        f2bf((acc[i][j][rr] + bia) * qs);
            }
        }
    }
}

// GEMM2: x = A*Bw^T + bias + residual -> bf16 (unchanged 128^2 depth-2)
__global__ __launch_bounds__(256) void gemm_mfma_out(
    const unsigned short* __restrict__ A, const unsigned short* __restrict__ Bw,
    const float* __restrict__ bias, const float* __restrict__ res,
    unsigned short* __restrict__ X, int M, int Nd, int K)
{
    __shared__ unsigned short As[3][TM][TK];
    __shared__ unsigned short Bs[3][TN][TK];

    const int tid = threadIdx.x;
    const int w = tid >> 6, lane = tid & 63;
    const int l15 = lane & 15, quad = lane >> 4;
    const int wr = (w & 1) * 64;
    const int wc = (w >> 1) * 64;
    const int row0 = blockIdx.y * TM;
    const int col0 = blockIdx.x * TN;

    const int srow16 = lane >> 2;
    const int sgd    = lane & 3;
    const int sgsrc  = (sgd ^ swz(srow16)) * 8;

    floatx4 acc[4][4];
    #pragma unroll
    for (int i = 0; i < 4; i++)
        #pragma unroll
        for (int j = 0; j < 4; j++) acc[i][j] = (floatx4){0.f,0.f,0.f,0.f};

    const int aswz = swz(l15) * 8;
    const int NK = K / TK;

    #pragma unroll
    for (int t = 0; t < 2; t++) {
        #pragma unroll
        for (int c = 0; c < 2; c++) {
            int seg = w * 2 + c;
            int r = seg * 16 + srow16;
            gload16(A  + (size_t)(row0 + r) * K + t * TK + sgsrc, &As[t][seg * 16][0]);
            gload16(Bw + (size_t)(col0 + r) * K + t * TK + sgsrc, &Bs[t][seg * 16][0]);
        }
    }

    #pragma unroll 1
    for (int k = 0; k < NK; ++k) {
        if (k + 1 < NK) asm volatile("s_waitcnt vmcnt(4)" ::: "memory");
        else            asm volatile("s_waitcnt vmcnt(0)" ::: "memory");
        __builtin_amdgcn_s_barrier();
        __builtin_amdgcn_sched_barrier(0);

        const int cur = k % 3;
        if (k + 2 < NK) {
            const int nb  = (k + 2) % 3;
            const int k0n = (k + 2) * TK;
            #pragma unroll
            for (int c = 0; c < 2; c++) {
                int seg = w * 2 + c;
                int r = seg * 16 + srow16;
                gload16(A  + (size_t)(row0 + r) * K + k0n + sgsrc, &As[nb][seg * 16][0]);
                gload16(Bw + (size_t)(col0 + r) * K + k0n + sgsrc, &Bs[nb][seg * 16][0]);
            }
        }
        __builtin_amdgcn_sched_barrier(0);

        short8 af[4], bf[4];
        #pragma unroll
        for (int i = 0; i < 4; i++)
            af[i] = *(const short8*)&As[cur][wr + i * 16 + l15][(quad * 8) ^ aswz];
        #pragma unroll
        for (int j = 0; j < 4; j++)
            bf[j] = *(const short8*)&Bs[cur][wc + j * 16 + l15][(quad * 8) ^ aswz];
        __builtin_amdgcn_s_setprio(1);
        #pragma unroll
        for (int i = 0; i < 4; i++)
            #pragma unroll
            for (int j = 0; j < 4; j++)
                acc[i][j] = __builtin_amdgcn_mfma_f32_16x16x32_bf16(af[i], bf[j], acc[i][j], 0, 0, 0);
        __builtin_amdgcn_s_setprio(0);
    }

    #pragma unroll
    for (int i = 0; i < 4; i++) {
        const int rb = row0 + wr + i * 16 + quad * 4;
        #pragma unroll
        for (int j = 0; j < 4; j++) {
            const int c = col0 + wc + j * 16 + l15;
            const float bia = bias[c];
            #pragma unroll
            for (int rr = 0; rr < 4; rr++) {
                X[(size_t)(rb + rr) * Nd + c] =
                    f2bf(acc[i][j][rr] + bia + res[(size_t)(rb + rr) * Nd + c]);
            }
        }
    }
}

// ---------------------------------------------------------------------------
// Grid-split-K MFMA flash attention, XCD-clustered, K AND V staged via
// linear-lane global_load_lds from packed pre-swizzled tiles. K-DMA is now
// byte-identical in shape to the (working) V-DMA: contiguous 8 KB tile,
// per-lane addr = base + w*1024 + lane*8 (+512). LDS image is unchanged from
// the old XOR-source scheme, so QK ds_read addressing is untouched.
// ---------------------------------------------------------------------------
#define KTILES 16   // 64-key tiles per z-half

__device__ __forceinline__ floatx4 mfma16(short8 a, short8 b, floatx4 c) {
    return __builtin_amdgcn_mfma_f32_16x16x32_bf16(a, b, c, 0, 0, 0);
}

// l-MFMA + PV for the PREVIOUS tile; V fragments read from LDS (Vt = tile
// base + lane*8, conflict-free b128 at stride 1024B)
__device__ __forceinline__ void do_lpv(
    const short8 (&pf0)[2], const short8 (&pf1)[2], const short8 (&mf)[2],
    const unsigned short* Vt,
    floatx4 (&oacc0)[4], floatx4 (&oacc1)[4],
    floatx4 &lacc0, floatx4 &lacc1)
{
    __builtin_amdgcn_s_setprio(1);
    lacc0 = mfma16(mf[0], pf0[0], lacc0);
    lacc0 = mfma16(mf[1], pf0[1], lacc0);
    lacc1 = mfma16(mf[0], pf1[0], lacc1);
    lacc1 = mfma16(mf[1], pf1[1], lacc1);
    #pragma unroll
    for (int dt = 0; dt < 4; dt++) {
        short8 vlo = *(const short8*)(Vt + dt * 512);
        short8 vhi = *(const short8*)(Vt + 2048 + dt * 512);
        oacc0[dt] = mfma16(vlo, pf0[0], oacc0[dt]);
        oacc1[dt] = mfma16(vlo, pf1[0], oacc1[dt]);
        oacc0[dt] = mfma16(vhi, pf0[1], oacc0[dt]);
        oacc1[dt] = mfma16(vhi, pf1[1], oacc1[dt]);
    }
    __builtin_amdgcn_s_setprio(0);
}

template<bool HAVER, bool PREF>
__device__ __forceinline__ void attn_body(
    int kt,
    unsigned short (&KsL)[2][64][64],
    unsigned short (&VsL)[3][4096],
    const unsigned short* Kb, const unsigned short* Vb, const unsigned short* e2b,
    int w, int l15, int quad, int lane,
    const short8 (&qf0)[2], const short8 (&qf1)[2],
    const short8 (&pfR0)[2], const short8 (&pfR1)[2], const short8 (&mfR)[2],
    short8 (&pfW0)[2], short8 (&pfW1)[2], short8 (&mfW)[2],
    floatx4 (&oacc0)[4], floatx4 (&oacc1)[4],
    floatx4 &lacc0, floatx4 &lacc1)
{
    asm volatile("s_waitcnt vmcnt(0)" ::: "memory");   // K(kt),V(kt) landed
    __builtin_amdgcn_s_barrier();                      // all waves' DMAs landed
    __builtin_amdgcn_sched_barrier(0);

    if (PREF) {
        // K(kt+1): linear lane copy of packed pre-swizzled tile
        const unsigned short* kpn = Kb + (size_t)(kt + 1) * 4096 + w * 1024 + lane * 8;
        gload16(kpn,       &KsL[(kt + 1) & 1][w * 16][0]);
        gload16(kpn + 512, &KsL[(kt + 1) & 1][w * 16 + 8][0]);
        // V(kt+1): linear lane copy of fragment-packed tile
        const unsigned short* vpn = Vb + (size_t)(kt + 1) * 4096 + w * 1024 + lane * 8;
        unsigned short* vd = &VsL[(kt + 1) % 3][w * 1024];
        gload16(vpn,       vd);
        gload16(vpn + 512, vd + 512);
    }
    __builtin_amdgcn_sched_barrier(0);   // pin DMAs as oldest outstanding

    // mf for THIS tile (consumed next body): direct loads, final order
    const unsigned short* ep = e2b + kt * 64;
    mfW[0] = *(const short8*)(ep + quad * 8);
    mfW[1] = *(const short8*)(ep + 32 + quad * 8);

    // ---- QK(kt): S^T = K Q^T for both subtiles
    floatx4 s0[4], s1[4];
    #pragma unroll
    for (int ct = 0; ct < 4; ct++) {
        s0[ct] = (floatx4){0.f,0.f,0.f,0.f};
        s1[ct] = (floatx4){0.f,0.f,0.f,0.f};
    }
    __builtin_amdgcn_s_setprio(1);
    #pragma unroll
    for (int ks = 0; ks < 2; ks++) {
        #pragma unroll
        for (int ct = 0; ct < 4; ct++) {
            short8 af = *(const short8*)&KsL[kt & 1][ct * 16 + l15][((4 * ks + quad) ^ (l15 & 7)) * 8];
            s0[ct] = mfma16(af, qf0[ks], s0[ct]);
            s1[ct] = mfma16(af, qf1[ks], s1[ct]);
        }
    }
    __builtin_amdgcn_s_setprio(0);

    // ---- softmax(kt) -> pfW (exp2-only via raw v_exp_f32; mask in V'/mf)
    #pragma unroll
    for (int ks = 0; ks < 2; ks++) {
        union { unsigned int u[4]; short8 s; } pk;
        #pragma unroll
        for (int h = 0; h < 2; h++) {
            const int ct = ks * 2 + h;
            pk.u[h * 2]     = pkbf(fexp2(s0[ct][0]), fexp2(s0[ct][1]));
            pk.u[h * 2 + 1] = pkbf(fexp2(s0[ct][2]), fexp2(s0[ct][3]));
        }
        pfW0[ks] = pk.s;
    }
    #pragma unroll
    for (int ks = 0; ks < 2; ks++) {
        union { unsigned int u[4]; short8 s; } pk;
        #pragma unroll
        for (int h = 0; h < 2; h++) {
            const int ct = ks * 2 + h;
            pk.u[h * 2]     = pkbf(fexp2(s1[ct][0]), fexp2(s1[ct][1]));
            pk.u[h * 2 + 1] = pkbf(fexp2(s1[ct][2]), fexp2(s1[ct][3]));
        }
        pfW1[ks] = pk.s;
    }

    // ---- l + PV for tile kt-1 from LDS (overlaps the exp2 chain above)
    if (HAVER)
        do_lpv(pfR0, pfR1, mfR, &VsL[(kt - 1) % 3][0] + lane * 8,
               oacc0, oacc1, lacc0, lacc1);
}

__global__ __launch_bounds__(256) void attn_mfma(
    const unsigned short* __restrict__ Qb, const unsigned short* __restrict__ K5,
    const unsigned short* __restrict__ V5, const unsigned short* __restrict__ em2,
    unsigned short* __restrict__ Opart, float* __restrict__ Lpart)
{
    __shared__ unsigned short Ks[2][64][64];   // 16 KB [buf][key][d], swizzled image
    __shared__ unsigned short Vs[3][4096];     // 24 KB fragment-packed V tiles

    const int tid  = threadIdx.x;
    const int w    = tid >> 6;
    const int lane = tid & 63;
    const int l15  = lane & 15;
    const int quad = lane >> 4;

    // XCD-clustering decode: all 16 qtiles of group g=(bn,z) share K/V and
    // land on XCD g%8 (dispatch round-robins linear id across 8 XCDs).
    const int i_    = blockIdx.x;
    const int gl8   = i_ & 7;
    const int rest  = i_ >> 3;
    const int qtile = rest & 15;          // 0..15 (128 queries each)
    const int g     = (rest >> 4) * 8 + gl8;   // 0..63
    const int bn    = g >> 1;
    const int z     = g & 1;
    const int n     = bn & 15;
    const int b     = bn >> 4;

    // Q B-fragments for both subtiles (n=l15 -> query row, k=quad*8+j)
    short8 qf0[2], qf1[2];
    {
        const int qrow0 = qtile * 128 + w * 16 + l15;
        const unsigned short* qp = Qb + (size_t)(b * Sq + qrow0) * Hq + n * HNq + quad * 8;
        qf0[0] = *(const short8*)(qp);
        qf0[1] = *(const short8*)(qp + 32);
        qp += (size_t)64 * Hq;
        qf1[0] = *(const short8*)(qp);
        qf1[1] = *(const short8*)(qp + 32);
    }

    floatx4 oacc0[4], oacc1[4];   // O^T per subtile: d = dt*16+quad*4+r, q=l15
    #pragma unroll
    for (int dt = 0; dt < 4; dt++) {
        oacc0[dt] = (floatx4){0.f,0.f,0.f,0.f};
        oacc1[dt] = (floatx4){0.f,0.f,0.f,0.f};
    }
    floatx4 lacc0 = (floatx4){0.f,0.f,0.f,0.f};
    floatx4 lacc1 = (floatx4){0.f,0.f,0.f,0.f};

    // packed K/V tile bases + permuted mask base
    const unsigned short* Kb  = K5 + ((size_t)(b * Nq + n) * 32 + z * KTILES) * 4096;
    const unsigned short* Vb  = V5 + ((size_t)(b * Nq + n) * 32 + z * KTILES) * 4096;
    const unsigned short* e2b = em2 + (size_t)(b * 32 + z * KTILES) * 64;

    // prologue: K(0) -> Ks[0], V(0) -> Vs[0] (all linear lane copies)
    {
        const unsigned short* kp0 = Kb + w * 1024 + lane * 8;
        gload16(kp0,       &Ks[0][w * 16][0]);
        gload16(kp0 + 512, &Ks[0][w * 16 + 8][0]);
        const unsigned short* vp0 = Vb + w * 1024 + lane * 8;
        gload16(vp0,       &Vs[0][w * 1024]);
        gload16(vp0 + 512, &Vs[0][w * 1024] + 512);
    }

    // pipeline state (two named stages, no dynamic indexing)
    short8 pfA0[2], pfA1[2], mfA[2];
    short8 pfB0[2], pfB1[2], mfB[2];

    // peel kt=0: fills stage A; no PV yet
    attn_body<false, true>(0, Ks, Vs, Kb, Vb, e2b, w, l15, quad, lane,
        qf0, qf1, pfB0, pfB1, mfB, pfA0, pfA1, mfA, oacc0, oacc1, lacc0, lacc1);

    #pragma unroll 1
    for (int kt = 1; kt < KTILES - 1; kt += 2) {
        attn_body<true, true>(kt, Ks, Vs, Kb, Vb, e2b, w, l15, quad, lane,
            qf0, qf1, pfA0, pfA1, mfA, pfB0, pfB1, mfB, oacc0, oacc1, lacc0, lacc1);
        attn_body<true, true>(kt + 1, Ks, Vs, Kb, Vb, e2b, w, l15, quad, lane,
            qf0, qf1, pfB0, pfB1, mfB, pfA0, pfA1, mfA, oacc0, oacc1, lacc0, lacc1);
    }
    // kt = 15 (odd): reads A, writes B, no prefetch
    attn_body<true, false>(KTILES - 1, Ks, Vs, Kb, Vb, e2b, w, l15, quad, lane,
        qf0, qf1, pfA0, pfA1, mfA, pfB0, pfB1, mfB, oacc0, oacc1, lacc0, lacc1);
    // drain: l + PV of tile 15 (stage B, V(15) in Vs[15%3 = 0])
    do_lpv(pfB0, pfB1, mfB, &Vs[(KTILES - 1) % 3][0] + lane * 8,
           oacc0, oacc1, lacc0, lacc1);

    // ---- epilogue: un-normalized partial O (bf16) + per-query l (no shfls:
    // every row of lacc holds l_q for q=l15)
    unsigned short* Ow = Opart + (size_t)z * Mq * Hq;
    #pragma unroll
    for (int sub = 0; sub < 2; sub++) {
        const float l_i = sub ? lacc1[0] : lacc0[0];
        const int qrow = qtile * 128 + sub * 64 + w * 16 + l15;
        if (quad == 0)
            Lpart[(size_t)z * Mq * Nq + (size_t)(b * Sq + qrow) * Nq + n] = l_i;
        #pragma unroll
        for (int dt = 0; dt < 4; dt++) {
            const floatx4 oa = sub ? oacc1[dt] : oacc0[dt];
            union { unsigned int u[2]; ushortx4 s; } o;
            o.u[0] = pkbf(oa[0], oa[1]);
            o.u[1] = pkbf(oa[2], oa[3]);
            const int col = n * HNq + dt * 16 + quad * 4;
            *(ushortx4*)&Ow[(size_t)(b * Sq + qrow) * Hq + col] = o.s;
        }
    }
}

// ---------------------------------------------------------------------------
// Merge the two split-K halves: ctx = (O0 + O1) / (l0 + l1), bf16 out.
// ---------------------------------------------------------------------------
__global__ __launch_bounds__(256) void attn_merge(
    const unsigned short* __restrict__ Opart, const float* __restrict__ Lpart,
    unsigned short* __restrict__ ctx)
{
    const size_t idx = ((size_t)blockIdx.x * 256 + threadIdx.x) * 4;
    const int row = (int)(idx >> 10);          // b*Sq + s
    const int n   = ((int)idx >> 6) & 15;
    const float l = Lpart[(size_t)row * Nq + n]
                  + Lpart[(size_t)Mq * Nq + (size_t)row * Nq + n];
    const float inv = 1.0f / l;
    ushortx4 a = *(const ushortx4*)(Opart + idx);
    ushortx4 c = *(const ushortx4*)(Opart + (size_t)Mq * Hq + idx);
    union { unsigned int u[2]; ushortx4 s; } o;
    o.u[0] = pkbf((bf2f(a[0]) + bf2f(c[0])) * inv, (bf2f(a[1]) + bf2f(c[1])) * inv);
    o.u[1] = pkbf((bf2f(a[2]) + bf2f(c[2])) * inv, (bf2f(a[3]) + bf2f(c[3])) * inv);
    *(ushortx4*)(ctx + idx) = o.s;
}

// ---------------------------------------------------------------------------
// Row LayerNorm over H=1024, bf16 input, fp32 stats, fp32 output.
// ---------------------------------------------------------------------------
__global__ __launch_bounds__(256) void ln_kernel(
    const unsigned short* __restrict__ X, const float* __restrict__ gamma,
    const float* __restrict__ beta, float* __restrict__ out)
{
    const int row = blockIdx.x;
    const int c0  = threadIdx.x * 4;
    ushortx4 xv = *(const ushortx4*)(X + (size_t)row * Hq + c0);
    float vals[4];
    float lsum = 0.0f;
    #pragma unroll
    for (int i = 0; i < 4; i++) { vals[i] = bf2f(xv[i]); lsum += vals[i]; }

    __shared__ float red[8];
    const int wid = threadIdx.x >> 6, lane = threadIdx.x & 63;

    float s = lsum;
    #pragma unroll
    for (int off = 32; off >= 1; off >>= 1) s += __shfl_xor(s, off, 64);
    if (lane == 0) red[wid] = s;
    __syncthreads();
    const float mean = (red[0] + red[1] + red[2] + red[3]) * (1.0f / Hq);

    float v = 0.0f;
    #pragma unroll
    for (int i = 0; i < 4; i++) { float d = vals[i] - mean; v += d * d; }
    #pragma unroll
    for (int off = 32; off >= 1; off >>= 1) v += __shfl_xor(v, off, 64);
    if (lane == 0) red[4 + wid] = v;
    __syncthreads();
    const float var  = (red[4] + red[5] + red[6] + red[7]) * (1.0f / Hq);
    const float rstd = rsqrtf(var + 1e-12f);

    float4 gm = *(const float4*)(gamma + c0);
    float4 bt = *(const float4*)(beta + c0);
    float4 o;
    o.x = (vals[0] - mean) * rstd * gm.x + bt.x;
    o.y = (vals[1] - mean) * rstd * gm.y + bt.y;
    o.z = (vals[2] - mean) * rstd * gm.z + bt.z;
    o.w = (vals[3] - mean) * rstd * gm.w + bt.w;
    *(float4*)(out + (size_t)row * Hq + c0) = o;
}

// ---------------------------------------------------------------------------
extern "C" void kernel_launch(void* const* d_in, const int* in_sizes, int n_in,
                              void* d_out, int out_size, void* d_ws, size_t ws_size,
                              hipStream_t stream)
{
    const float* hidden = (const float*)d_in[0];
    const float* mask   = (const float*)d_in[1];
    const float* W_qkv  = (const float*)d_in[2];
    const float* b_qkv  = (const float*)d_in[3];
    const float* W_out  = (const float*)d_in[4];
    const float* b_out  = (const float*)d_in[5];
    const float* gamma  = (const float*)d_in[6];
    const float* beta   = (const float*)d_in[7];
    float* out = (float*)d_out;

    const size_t nHid  = (size_t)Mq * Hq;        // 4 M
    const size_t nWq   = (size_t)H3q * Hq;       // 3 M
    const size_t nWo   = (size_t)Hq * Hq;        // 1 M
    const size_t nCtx  = (size_t)Mq * Hq;        // 4 M

    unsigned short* hidden_bf = (unsigned short*)d_ws;
    unsigned short* Wqkv_bf   = hidden_bf + nHid;
    unsigned short* Wout_bf   = Wqkv_bf + nWq;
    unsigned short* qb        = Wout_bf + nWo;          // Q  [4096][1024]
    unsigned short* k5        = qb + nHid;              // K packed pre-swizzled, 4 M
    unsigned short* v5        = k5 + nHid;              // V' fragment-packed, 4 M
    unsigned short* ctx_bf    = v5 + nHid;
    unsigned short* x_bf      = ctx_bf + nCtx;
    unsigned short* opart     = x_bf + nHid;            // 2 * 4M bf16 = 16 MB
    float*          lpart     = (float*)(opart + 2 * nHid);  // 2*64K floats
    unsigned short* em2       = (unsigned short*)(lpart + 2 * (size_t)Mq * Nq);

    dim3 blk(256);

    // 0) fused fp32 -> bf16 cast + permuted expmask table (one kernel)
    cvt_all<<<dim3(CVT_BLKS + 2), blk, 0, stream>>>(
        hidden, W_qkv, W_out, mask, hidden_bf, em2);

    // 1) QKV projection (MFMA, 256x128 tile, depth-2) -> Qb / K5 / V5
    gemm_mfma_qkv<<<dim3(H3q / TN, Mq / G1M), dim3(512), 0, stream>>>(
        hidden_bf, Wqkv_bf, b_qkv, mask, qb, k5, v5, Hq);

    // 2) Pipelined flash attention, XCD-clustered, K+V via linear LDS DMA
    attn_mfma<<<dim3(1024), blk, 0, stream>>>(
        qb, k5, v5, em2, opart, lpart);

    // 2b) merge halves -> ctx bf16
    attn_merge<<<dim3((int)(nCtx / 1024)), blk, 0, stream>>>(
        opart, lpart, ctx_bf);

    // 3) Output projection (MFMA, depth-2 pipelined staging) + residual -> x bf16
    gemm_mfma_out<<<dim3(Hq / TN, Mq / TM), blk, 0, stream>>>(
        ctx_bf, Wout_bf, b_out, hidden, x_bf, Mq, Hq, Hq);

    // 4) LayerNorm: bf16 x -> fp32 out
    ln_kernel<<<dim3(Mq), blk, 0, stream>>>(x_bf, gamma, beta, out);
}

// Round 10
// 199.914 us; speedup vs baseline: 1.2621x; 1.0142x over previous
//
#include <hip/hip_runtime.h>
#include <hip/hip_bf16.h>
#include <math.h>

// Problem constants
#define Bq  2
#define Sq  2048
#define Hq  1024
#define Nq  16
#define HNq 64
#define Mq  (Bq*Sq)        // 4096 rows
#define H3q (3*Hq)         // 3072

#define LOG2E 1.44269504088896340736f

typedef __attribute__((ext_vector_type(8))) short           short8;
typedef __attribute__((ext_vector_type(4))) short           short4s;
typedef __attribute__((ext_vector_type(8))) unsigned short  ushortx8;
typedef __attribute__((ext_vector_type(4))) unsigned short  ushortx4;
typedef __attribute__((ext_vector_type(4))) float           floatx4;

__device__ __forceinline__ unsigned short f2bf(float f) {
    union { float f; unsigned int u; } x; x.f = f;
    unsigned int r = (x.u + 0x7fffu + ((x.u >> 16) & 1u)) >> 16;
    return (unsigned short)r;
}

// packed fp32x2 -> bf16x2 (v_cvt_pk_bf16_f32 on gfx950); a in low 16 bits
__device__ __forceinline__ unsigned int pkbf(float a, float b) {
    float2 t; t.x = a; t.y = b;
    __hip_bfloat162 h = __float22bfloat162_rn(t);
    union { __hip_bfloat162 h; unsigned int u; } c; c.h = h;
    return c.u;
}

__device__ __forceinline__ float bf2f(unsigned short v) {
    union { unsigned int u; float f; } x; x.u = (unsigned int)v << 16;
    return x.f;
}

// raw v_exp_f32 (D = 2^S0): ONE transcendental op (libm exp2f is a guarded
// ~10-op sequence without fast-math -- was the hidden VALU hog).
__device__ __forceinline__ float fexp2(float x) {
    float r;
    asm("v_exp_f32 %0, %1" : "=v"(r) : "v"(x));
    return r;
}

// async global->LDS, 16B per lane; LDS dest = wave-uniform base + lane*16
__device__ __forceinline__ void gload16(const unsigned short* g, unsigned short* l) {
    __builtin_amdgcn_global_load_lds(
        (__attribute__((address_space(1))) void*)(unsigned long long)(g),
        (__attribute__((address_space(3))) void*)(unsigned int)(unsigned long long)(l),
        16, 0, 0);
}

// LDS bank swizzle: granule' = granule ^ swz(row mod 16); 2-way max conflict
__device__ __forceinline__ int swz(int r) { return (r ^ (r >> 2)) & 3; }

// ---------------------------------------------------------------------------
// Fused fp32 -> bf16 cast for hidden | W_qkv | W_out + permuted e^mask table
// em2[((b*32+kt)*2+ks)*32 + quad*8 + hi*4 + r]
//   = exp(mask[b][kt*64 + (2ks+hi)*16 + quad*4 + r])
// ---------------------------------------------------------------------------
#define N_HID ((size_t)Mq * Hq)          // 4194304
#define N_HW  (N_HID + (size_t)H3q * Hq) // 7340032
#define N_ALL (N_HW + (size_t)Hq * Hq)   // 8388608
#define CVT_BLKS ((int)(N_ALL / 2048))   // 4096

__global__ __launch_bounds__(256) void cvt_all(
    const float* __restrict__ hidden, const float* __restrict__ wqkv,
    const float* __restrict__ wout, const float* __restrict__ mask,
    unsigned short* __restrict__ dst, unsigned short* __restrict__ em2)
{
    const int bid = blockIdx.x;
    if (bid >= CVT_BLKS) {
        // ---- permuted e^mask table (2 blocks, 4096 outputs)
        const int t0   = ((bid - CVT_BLKS) * 256 + threadIdx.x) * 8;
        const int b    = t0 >> 11;
        const int t2   = t0 & 2047;
        const int kt   = t2 >> 6;
        const int t3   = t2 & 63;
        const int ks   = t3 >> 5;
        const int quad = (t3 >> 3) & 3;
        const int kb   = kt * 64 + ks * 32 + quad * 4;
        const float* mp = mask + (size_t)b * Sq + kb;
        float4 m0 = *(const float4*)(mp);
        float4 m1 = *(const float4*)(mp + 16);
        union { unsigned int u[4]; ushortx8 s; } o;
        o.u[0] = pkbf(fexp2(m0.x * LOG2E), fexp2(m0.y * LOG2E));
        o.u[1] = pkbf(fexp2(m0.z * LOG2E), fexp2(m0.w * LOG2E));
        o.u[2] = pkbf(fexp2(m1.x * LOG2E), fexp2(m1.y * LOG2E));
        o.u[3] = pkbf(fexp2(m1.z * LOG2E), fexp2(m1.w * LOG2E));
        *(ushortx8*)(em2 + t0) = o.s;
        return;
    }
    size_t i = ((size_t)bid * 256 + threadIdx.x) * 8;
    const float* src;
    if (i < N_HID)      src = hidden + i;
    else if (i < N_HW)  src = wqkv + (i - N_HID);
    else                src = wout + (i - N_HW);
    float4 a = *(const float4*)(src);
    float4 b = *(const float4*)(src + 4);
    union { unsigned int u[4]; ushortx8 s; } o;
    o.u[0] = pkbf(a.x, a.y); o.u[1] = pkbf(a.z, a.w);
    o.u[2] = pkbf(b.x, b.y); o.u[3] = pkbf(b.z, b.w);
    *(ushortx8*)(dst + i) = o.s;
}

// ---------------------------------------------------------------------------
// GEMM1: 256x128 tile, BK=32, 8 waves (512 thr) each computing 64x64.
// Triple-buffered LDS, depth-2 prefetch, counted vmcnt(3).
// Outputs (round-8 formats, feeding the measured-best attn):
//   Qb [row][1024]  Q * 0.125*log2e (bf16), dense
//   Kd [row][1024]  K (bf16), dense rows
//   V5 fragment-packed V'^T (e^mask folded), lane-linear per tile
// ---------------------------------------------------------------------------
#define TM 128
#define TN 128
#define TK 32
#define G1M 256

__global__ __launch_bounds__(512) void gemm_mfma_qkv(
    const unsigned short* __restrict__ A, const unsigned short* __restrict__ Bw,
    const float* __restrict__ bias, const float* __restrict__ mask,
    unsigned short* __restrict__ Qb, unsigned short* __restrict__ Kd,
    unsigned short* __restrict__ V5, int K)
{
    __shared__ unsigned short As[3][G1M][TK];   // 48 KB
    __shared__ unsigned short Bs[3][TN][TK];    // 24 KB

    const int tid = threadIdx.x;
    const int w = tid >> 6, lane = tid & 63;
    const int l15 = lane & 15, quad = lane >> 4;
    const int wr = (w & 3) * 64;
    const int wc = (w >> 2) * 64;
    const int row0 = blockIdx.y * G1M;
    const int col0 = blockIdx.x * TN;

    const int srow16 = lane >> 2;
    const int sgd    = lane & 3;
    const int sgsrc  = (sgd ^ swz(srow16)) * 8;

    floatx4 acc[4][4];
    #pragma unroll
    for (int i = 0; i < 4; i++)
        #pragma unroll
        for (int j = 0; j < 4; j++) acc[i][j] = (floatx4){0.f,0.f,0.f,0.f};

    const int aswz = swz(l15) * 8;
    const int NK = K / TK;

    // prologue: stage tiles 0,1 (A: 2 segs/wave, B: 1 seg/wave)
    #pragma unroll
    for (int t = 0; t < 2; t++) {
        #pragma unroll
        for (int c = 0; c < 2; c++) {
            int seg = w * 2 + c;
            int r = seg * 16 + srow16;
            gload16(A + (size_t)(row0 + r) * K + t * TK + sgsrc, &As[t][seg * 16][0]);
        }
        int rB = w * 16 + srow16;
        gload16(Bw + (size_t)(col0 + rB) * K + t * TK + sgsrc, &Bs[t][w * 16][0]);
    }

    #pragma unroll 1
    for (int k = 0; k < NK; ++k) {
        if (k + 1 < NK) asm volatile("s_waitcnt vmcnt(3)" ::: "memory");
        else            asm volatile("s_waitcnt vmcnt(0)" ::: "memory");
        __builtin_amdgcn_s_barrier();
        __builtin_amdgcn_sched_barrier(0);

        const int cur = k % 3;
        if (k + 2 < NK) {                                  // prefetch tile k+2
            const int nb  = (k + 2) % 3;
            const int k0n = (k + 2) * TK;
            #pragma unroll
            for (int c = 0; c < 2; c++) {
                int seg = w * 2 + c;
                int r = seg * 16 + srow16;
                gload16(A + (size_t)(row0 + r) * K + k0n + sgsrc, &As[nb][seg * 16][0]);
            }
            int rB = w * 16 + srow16;
            gload16(Bw + (size_t)(col0 + rB) * K + k0n + sgsrc, &Bs[nb][w * 16][0]);
        }
        __builtin_amdgcn_sched_barrier(0);

        short8 af[4], bf[4];
        #pragma unroll
        for (int i = 0; i < 4; i++)
            af[i] = *(const short8*)&As[cur][wr + i * 16 + l15][(quad * 8) ^ aswz];
        #pragma unroll
        for (int j = 0; j < 4; j++)
            bf[j] = *(const short8*)&Bs[cur][wc + j * 16 + l15][(quad * 8) ^ aswz];
        __builtin_amdgcn_s_setprio(1);
        #pragma unroll
        for (int i = 0; i < 4; i++)
            #pragma unroll
            for (int j = 0; j < 4; j++)
                acc[i][j] = __builtin_amdgcn_mfma_f32_16x16x32_bf16(af[i], bf[j], acc[i][j], 0, 0, 0);
        __builtin_amdgcn_s_setprio(0);
    }

    const int cls = col0 >> 10;    // 0=Q, 1=K, 2=V; uniform per block

    if (cls == 2) {
        #pragma unroll
        for (int i = 0; i < 4; i++) {
            const int rb = row0 + wr + i * 16 + quad * 4;
            const int b  = rb >> 11;
            const int s  = rb & (Sq - 1);
            const int kt32 = s >> 6;
            const int sw   = s & 63;
            const int kg   = sw >> 2;          // s&3 == 0 (rb % 4 == 0)
            const int ks   = kg >> 3;
            const int q2   = kg & 3;
            const int hi   = (kg >> 2) & 1;
            float expm[4];
            #pragma unroll
            for (int rr = 0; rr < 4; rr++)
                expm[rr] = fexp2(mask[(size_t)b * Sq + s + rr] * LOG2E);
            #pragma unroll
            for (int j = 0; j < 4; j++) {
                const int c  = col0 + wc + j * 16 + l15;
                const int c2 = c - 2 * Hq;           // n*64+d
                const int n  = c2 >> 6, d = c2 & 63;
                const int dt = d >> 4, dl = d & 15;
                const float bia = bias[c];
                ushortx4 o;
                #pragma unroll
                for (int rr = 0; rr < 4; rr++)
                    o[rr] = f2bf((acc[i][j][rr] + bia) * expm[rr]);
                const size_t off = (((size_t)(b * Nq + n) * 32 + kt32) << 12)
                                 + (size_t)((ks * 16 + dt * 4 + q2) * 128 + dl * 8 + hi * 4);
                *(ushortx4*)&V5[off] = o;
            }
        }
    } else {
        unsigned short* __restrict__ dst = (cls == 0) ? Qb : Kd;
        const int cshift = (cls == 0) ? 0 : Hq;
        const float qs = (cls == 0) ? (0.125f * LOG2E) : 1.0f;
        #pragma unroll
        for (int i = 0; i < 4; i++) {
            const int rb = row0 + wr + i * 16 + quad * 4;
            #pragma unroll
            for (int j = 0; j < 4; j++) {
                const int c = col0 + wc + j * 16 + l15;
                const float bia = bias[c];
                #pragma unroll
                for (int rr = 0; rr < 4; rr++)
                    dst[(size_t)(rb + rr) * Hq + (c - cshift)] =
                        f2bf((acc[i][j][rr] + bia) * qs);
            }
        }
    }
}

// ---------------------------------------------------------------------------
// GEMM2: x = A*Bw^T + bias + residual -> bf16.
// NEW: 64x128 tile => grid 8x64 = 512 blocks (was 256 = 1 block/CU with zero
// wave-level latency hiding). 4 waves each compute a 32x64 sub-tile
// (acc[2][4]); 3 gload16/wave/step (A:1 seg, B:2 segs); triple-buffered LDS
// (36 KB), depth-2 prefetch, counted vmcnt(3). Cost: B re-read x64 instead
// of x32 (~+3 us of L2 traffic) for 2x block parallelism.
// ---------------------------------------------------------------------------
#define T2M 64
#define T2N 128

__global__ __launch_bounds__(256) void gemm_mfma_out(
    const unsigned short* __restrict__ A, const unsigned short* __restrict__ Bw,
    const float* __restrict__ bias, const float* __restrict__ res,
    unsigned short* __restrict__ X, int M, int Nd, int K)
{
    __shared__ unsigned short As[3][T2M][TK];   // 12 KB
    __shared__ unsigned short Bs[3][T2N][TK];   // 24 KB

    const int tid = threadIdx.x;
    const int w = tid >> 6, lane = tid & 63;
    const int l15 = lane & 15, quad = lane >> 4;
    const int wr = (w & 1) * 32;
    const int wc = (w >> 1) * 64;
    const int row0 = blockIdx.y * T2M;
    const int col0 = blockIdx.x * T2N;

    const int srow16 = lane >> 2;
    const int sgd    = lane & 3;
    const int sgsrc  = (sgd ^ swz(srow16)) * 8;

    floatx4 acc[2][4];
    #pragma unroll
    for (int i = 0; i < 2; i++)
        #pragma unroll
        for (int j = 0; j < 4; j++) acc[i][j] = (floatx4){0.f,0.f,0.f,0.f};

    const int aswz = swz(l15) * 8;
    const int NK = K / TK;

    // prologue: stage tiles 0,1 (A: 1 seg/wave, B: 2 segs/wave)
    #pragma unroll
    for (int t = 0; t < 2; t++) {
        int rA = w * 16 + srow16;
        gload16(A + (size_t)(row0 + rA) * K + t * TK + sgsrc, &As[t][w * 16][0]);
        #pragma unroll
        for (int c = 0; c < 2; c++) {
            int seg = w * 2 + c;
            int rB = seg * 16 + srow16;
            gload16(Bw + (size_t)(col0 + rB) * K + t * TK + sgsrc, &Bs[t][seg * 16][0]);
        }
    }

    #pragma unroll 1
    for (int k = 0; k < NK; ++k) {
        if (k + 1 < NK) asm volatile("s_waitcnt vmcnt(3)" ::: "memory");
        else            asm volatile("s_waitcnt vmcnt(0)" ::: "memory");
        __builtin_amdgcn_s_barrier();
        __builtin_amdgcn_sched_barrier(0);

        const int cur = k % 3;
        if (k + 2 < NK) {
            const int nb  = (k + 2) % 3;
            const int k0n = (k + 2) * TK;
            int rA = w * 16 + srow16;
            gload16(A + (size_t)(row0 + rA) * K + k0n + sgsrc, &As[nb][w * 16][0]);
            #pragma unroll
            for (int c = 0; c < 2; c++) {
                int seg = w * 2 + c;
                int rB = seg * 16 + srow16;
                gload16(Bw + (size_t)(col0 + rB) * K + k0n + sgsrc, &Bs[nb][seg * 16][0]);
            }
        }
        __builtin_amdgcn_sched_barrier(0);

        short8 af[2], bf[4];
        #pragma unroll
        for (int i = 0; i < 2; i++)
            af[i] = *(const short8*)&As[cur][wr + i * 16 + l15][(quad * 8) ^ aswz];
        #pragma unroll
        for (int j = 0; j < 4; j++)
            bf[j] = *(const short8*)&Bs[cur][wc + j * 16 + l15][(quad * 8) ^ aswz];
        __builtin_amdgcn_s_setprio(1);
        #pragma unroll
        for (int i = 0; i < 2; i++)
            #pragma unroll
            for (int j = 0; j < 4; j++)
                acc[i][j] = __builtin_amdgcn_mfma_f32_16x16x32_bf16(af[i], bf[j], acc[i][j], 0, 0, 0);
        __builtin_amdgcn_s_setprio(0);
    }

    #pragma unroll
    for (int i = 0; i < 2; i++) {
        const int rb = row0 + wr + i * 16 + quad * 4;
        #pragma unroll
        for (int j = 0; j < 4; j++) {
            const int c = col0 + wc + j * 16 + l15;
            const float bia = bias[c];
            #pragma unroll
            for (int rr = 0; rr < 4; rr++) {
                X[(size_t)(rb + rr) * Nd + c] =
                    f2bf(acc[i][j][rr] + bia + res[(size_t)(rb + rr) * Nd + c]);
            }
        }
    }
}

// ---------------------------------------------------------------------------
// Grid-split-K MFMA flash attention -- ROUND-8 VERSION VERBATIM (measured
// best, 55.6 us): XCD-clustered, K from dense Kd via scattered-source
// global_load_lds (XOR-swizzled), V staged through LDS from fragment-packed
// V5 (lane-linear DMA), triple-buffered V, cross-tile software pipeline.
// (Round 9's packed-K5 linear DMA regressed to 64.8 us -- suspected L2
// set-aliasing between same-offset K5/V5 tiles; reverted.)
// ---------------------------------------------------------------------------
#define KTILES 16   // 64-key tiles per z-half

__device__ __forceinline__ floatx4 mfma16(short8 a, short8 b, floatx4 c) {
    return __builtin_amdgcn_mfma_f32_16x16x32_bf16(a, b, c, 0, 0, 0);
}

// l-MFMA + PV for the PREVIOUS tile; V fragments read from LDS (Vt = tile
// base + lane*8, conflict-free b128 at stride 1024B)
__device__ __forceinline__ void do_lpv(
    const short8 (&pf0)[2], const short8 (&pf1)[2], const short8 (&mf)[2],
    const unsigned short* Vt,
    floatx4 (&oacc0)[4], floatx4 (&oacc1)[4],
    floatx4 &lacc0, floatx4 &lacc1)
{
    __builtin_amdgcn_s_setprio(1);
    lacc0 = mfma16(mf[0], pf0[0], lacc0);
    lacc0 = mfma16(mf[1], pf0[1], lacc0);
    lacc1 = mfma16(mf[0], pf1[0], lacc1);
    lacc1 = mfma16(mf[1], pf1[1], lacc1);
    #pragma unroll
    for (int dt = 0; dt < 4; dt++) {
        short8 vlo = *(const short8*)(Vt + dt * 512);
        short8 vhi = *(const short8*)(Vt + 2048 + dt * 512);
        oacc0[dt] = mfma16(vlo, pf0[0], oacc0[dt]);
        oacc1[dt] = mfma16(vlo, pf1[0], oacc1[dt]);
        oacc0[dt] = mfma16(vhi, pf0[1], oacc0[dt]);
        oacc1[dt] = mfma16(vhi, pf1[1], oacc1[dt]);
    }
    __builtin_amdgcn_s_setprio(0);
}

template<bool HAVER, bool PREF>
__device__ __forceinline__ void attn_body(
    int kt,
    unsigned short (&KsL)[2][64][64],
    unsigned short (&VsL)[3][4096],
    const unsigned short* kp, size_t kstep,
    const unsigned short* Vb, const unsigned short* e2b,
    int w, int l15, int quad, int lane,
    const short8 (&qf0)[2], const short8 (&qf1)[2],
    const short8 (&pfR0)[2], const short8 (&pfR1)[2], const short8 (&mfR)[2],
    short8 (&pfW0)[2], short8 (&pfW1)[2], short8 (&mfW)[2],
    floatx4 (&oacc0)[4], floatx4 (&oacc1)[4],
    floatx4 &lacc0, floatx4 &lacc1)
{
    asm volatile("s_waitcnt vmcnt(0)" ::: "memory");   // K(kt),V(kt) landed
    __builtin_amdgcn_s_barrier();                      // all waves' DMAs landed
    __builtin_amdgcn_sched_barrier(0);

    if (PREF) {
        // K(kt+1): wave w stages its 16 rows (2 x 1KB)
        const unsigned short* kpn = kp + (size_t)(kt + 1) * kstep;
        gload16(kpn,                  &KsL[(kt + 1) & 1][w * 16][0]);
        gload16(kpn + (size_t)8 * Hq, &KsL[(kt + 1) & 1][w * 16 + 8][0]);
        // V(kt+1): wave w stages its 2KB quarter (linear copy of V5 tile)
        const unsigned short* vpn = Vb + (size_t)(kt + 1) * 4096 + w * 1024 + lane * 8;
        unsigned short* vd = &VsL[(kt + 1) % 3][w * 1024];
        gload16(vpn,       vd);
        gload16(vpn + 512, vd + 512);
    }
    __builtin_amdgcn_sched_barrier(0);   // pin DMAs as oldest outstanding

    // mf for THIS tile (consumed next body): direct loads, final order
    const unsigned short* ep = e2b + kt * 64;
    mfW[0] = *(const short8*)(ep + quad * 8);
    mfW[1] = *(const short8*)(ep + 32 + quad * 8);

    // ---- QK(kt): S^T = K Q^T for both subtiles
    floatx4 s0[4], s1[4];
    #pragma unroll
    for (int ct = 0; ct < 4; ct++) {
        s0[ct] = (floatx4){0.f,0.f,0.f,0.f};
        s1[ct] = (floatx4){0.f,0.f,0.f,0.f};
    }
    __builtin_amdgcn_s_setprio(1);
    #pragma unroll
    for (int ks = 0; ks < 2; ks++) {
        #pragma unroll
        for (int ct = 0; ct < 4; ct++) {
            short8 af = *(const short8*)&KsL[kt & 1][ct * 16 + l15][((4 * ks + quad) ^ (l15 & 7)) * 8];
            s0[ct] = mfma16(af, qf0[ks], s0[ct]);
            s1[ct] = mfma16(af, qf1[ks], s1[ct]);
        }
    }
    __builtin_amdgcn_s_setprio(0);

    // ---- softmax(kt) -> pfW (exp2-only via raw v_exp_f32; mask in V'/mf)
    #pragma unroll
    for (int ks = 0; ks < 2; ks++) {
        union { unsigned int u[4]; short8 s; } pk;
        #pragma unroll
        for (int h = 0; h < 2; h++) {
            const int ct = ks * 2 + h;
            pk.u[h * 2]     = pkbf(fexp2(s0[ct][0]), fexp2(s0[ct][1]));
            pk.u[h * 2 + 1] = pkbf(fexp2(s0[ct][2]), fexp2(s0[ct][3]));
        }
        pfW0[ks] = pk.s;
    }
    #pragma unroll
    for (int ks = 0; ks < 2; ks++) {
        union { unsigned int u[4]; short8 s; } pk;
        #pragma unroll
        for (int h = 0; h < 2; h++) {
            const int ct = ks * 2 + h;
            pk.u[h * 2]     = pkbf(fexp2(s1[ct][0]), fexp2(s1[ct][1]));
            pk.u[h * 2 + 1] = pkbf(fexp2(s1[ct][2]), fexp2(s1[ct][3]));
        }
        pfW1[ks] = pk.s;
    }

    // ---- l + PV for tile kt-1 from LDS (overlaps the exp2 chain above)
    if (HAVER)
        do_lpv(pfR0, pfR1, mfR, &VsL[(kt - 1) % 3][0] + lane * 8,
               oacc0, oacc1, lacc0, lacc1);
}

__global__ __launch_bounds__(256) void attn_mfma(
    const unsigned short* __restrict__ Qb, const unsigned short* __restrict__ Kd,
    const unsigned short* __restrict__ V5, const unsigned short* __restrict__ em2,
    unsigned short* __restrict__ Opart, float* __restrict__ Lpart)
{
    __shared__ unsigned short Ks[2][64][64];   // 16 KB [buf][key][d], src-swizzled
    __shared__ unsigned short Vs[3][4096];     // 24 KB fragment-packed V tiles

    const int tid  = threadIdx.x;
    const int w    = tid >> 6;
    const int lane = tid & 63;
    const int l15  = lane & 15;
    const int quad = lane >> 4;

    // XCD-clustering decode: all 16 qtiles of group g=(bn,z) share K/V and
    // land on XCD g%8 (dispatch round-robins linear id across 8 XCDs).
    const int i_    = blockIdx.x;
    const int gl8   = i_ & 7;
    const int rest  = i_ >> 3;
    const int qtile = rest & 15;          // 0..15 (128 queries each)
    const int g     = (rest >> 4) * 8 + gl8;   // 0..63
    const int bn    = g >> 1;
    const int z     = g & 1;
    const int n     = bn & 15;
    const int b     = bn >> 4;

    const int kbase = z * (KTILES * 64);

    // Q B-fragments for both subtiles (n=l15 -> query row, k=quad*8+j)
    short8 qf0[2], qf1[2];
    {
        const int qrow0 = qtile * 128 + w * 16 + l15;
        const unsigned short* qp = Qb + (size_t)(b * Sq + qrow0) * Hq + n * HNq + quad * 8;
        qf0[0] = *(const short8*)(qp);
        qf0[1] = *(const short8*)(qp + 32);
        qp += (size_t)64 * Hq;
        qf1[0] = *(const short8*)(qp);
        qf1[1] = *(const short8*)(qp + 32);
    }

    floatx4 oacc0[4], oacc1[4];   // O^T per subtile: d = dt*16+quad*4+r, q=l15
    #pragma unroll
    for (int dt = 0; dt < 4; dt++) {
        oacc0[dt] = (floatx4){0.f,0.f,0.f,0.f};
        oacc1[dt] = (floatx4){0.f,0.f,0.f,0.f};
    }
    floatx4 lacc0 = (floatx4){0.f,0.f,0.f,0.f};
    floatx4 lacc1 = (floatx4){0.f,0.f,0.f,0.f};

    // K DMA geometry: wave w stages rows w*16..w*16+15 via 2 global_load_lds.
    const int krow8 = lane >> 3;               // 0..7
    const int kgr   = (lane & 7) ^ (krow8 & 7);
    const unsigned short* kp = Kd + (size_t)(b * Sq + kbase + w * 16 + krow8) * Hq
                                  + n * HNq + kgr * 8;
    const size_t kstep = (size_t)64 * Hq;

    // fragment-packed V base + permuted mask base
    const unsigned short* Vb  = V5 + ((size_t)(b * Nq + n) * 32 + z * KTILES) * 4096;
    const unsigned short* e2b = em2 + (size_t)(b * 32 + z * KTILES) * 64;

    // prologue: K(0) -> Ks[0], V(0) -> Vs[0]
    gload16(kp,                  &Ks[0][w * 16][0]);
    gload16(kp + (size_t)8 * Hq, &Ks[0][w * 16 + 8][0]);
    {
        const unsigned short* vp0 = Vb + w * 1024 + lane * 8;
        gload16(vp0,       &Vs[0][w * 1024]);
        gload16(vp0 + 512, &Vs[0][w * 1024] + 512);
    }

    // pipeline state (two named stages, no dynamic indexing)
    short8 pfA0[2], pfA1[2], mfA[2];
    short8 pfB0[2], pfB1[2], mfB[2];

    // peel kt=0: fills stage A; no PV yet
    attn_body<false, true>(0, Ks, Vs, kp, kstep, Vb, e2b, w, l15, quad, lane,
        qf0, qf1, pfB0, pfB1, mfB, pfA0, pfA1, mfA, oacc0, oacc1, lacc0, lacc1);

    #pragma unroll 1
    for (int kt = 1; kt < KTILES - 1; kt += 2) {
        attn_body<true, true>(kt, Ks, Vs, kp, kstep, Vb, e2b, w, l15, quad, lane,
            qf0, qf1, pfA0, pfA1, mfA, pfB0, pfB1, mfB, oacc0, oacc1, lacc0, lacc1);
        attn_body<true, true>(kt + 1, Ks, Vs, kp, kstep, Vb, e2b, w, l15, quad, lane,
            qf0, qf1, pfB0, pfB1, mfB, pfA0, pfA1, mfA, oacc0, oacc1, lacc0, lacc1);
    }
    // kt = 15 (odd): reads A, writes B, no prefetch
    attn_body<true, false>(KTILES - 1, Ks, Vs, kp, kstep, Vb, e2b, w, l15, quad, lane,
        qf0, qf1, pfA0, pfA1, mfA, pfB0, pfB1, mfB, oacc0, oacc1, lacc0, lacc1);
    // drain: l + PV of tile 15 (stage B, V(15) in Vs[15%3 = 0])
    do_lpv(pfB0, pfB1, mfB, &Vs[(KTILES - 1) % 3][0] + lane * 8,
           oacc0, oacc1, lacc0, lacc1);

    // ---- epilogue: un-normalized partial O (bf16) + per-query l (no shfls:
    // every row of lacc holds l_q for q=l15)
    unsigned short* Ow = Opart + (size_t)z * Mq * Hq;
    #pragma unroll
    for (int sub = 0; sub < 2; sub++) {
        const float l_i = sub ? lacc1[0] : lacc0[0];
        const int qrow = qtile * 128 + sub * 64 + w * 16 + l15;
        if (quad == 0)
            Lpart[(size_t)z * Mq * Nq + (size_t)(b * Sq + qrow) * Nq + n] = l_i;
        #pragma unroll
        for (int dt = 0; dt < 4; dt++) {
            const floatx4 oa = sub ? oacc1[dt] : oacc0[dt];
            union { unsigned int u[2]; ushortx4 s; } o;
            o.u[0] = pkbf(oa[0], oa[1]);
            o.u[1] = pkbf(oa[2], oa[3]);
            const int col = n * HNq + dt * 16 + quad * 4;
            *(ushortx4*)&Ow[(size_t)(b * Sq + qrow) * Hq + col] = o.s;
        }
    }
}

// ---------------------------------------------------------------------------
// Merge the two split-K halves: ctx = (O0 + O1) / (l0 + l1), bf16 out.
// ---------------------------------------------------------------------------
__global__ __launch_bounds__(256) void attn_merge(
    const unsigned short* __restrict__ Opart, const float* __restrict__ Lpart,
    unsigned short* __restrict__ ctx)
{
    const size_t idx = ((size_t)blockIdx.x * 256 + threadIdx.x) * 4;
    const int row = (int)(idx >> 10);          // b*Sq + s
    const int n   = ((int)idx >> 6) & 15;
    const float l = Lpart[(size_t)row * Nq + n]
                  + Lpart[(size_t)Mq * Nq + (size_t)row * Nq + n];
    const float inv = 1.0f / l;
    ushortx4 a = *(const ushortx4*)(Opart + idx);
    ushortx4 c = *(const ushortx4*)(Opart + (size_t)Mq * Hq + idx);
    union { unsigned int u[2]; ushortx4 s; } o;
    o.u[0] = pkbf((bf2f(a[0]) + bf2f(c[0])) * inv, (bf2f(a[1]) + bf2f(c[1])) * inv);
    o.u[1] = pkbf((bf2f(a[2]) + bf2f(c[2])) * inv, (bf2f(a[3]) + bf2f(c[3])) * inv);
    *(ushortx4*)(ctx + idx) = o.s;
}

// ---------------------------------------------------------------------------
// Row LayerNorm over H=1024, bf16 input, fp32 stats, fp32 output.
// ---------------------------------------------------------------------------
__global__ __launch_bounds__(256) void ln_kernel(
    const unsigned short* __restrict__ X, const float* __restrict__ gamma,
    const float* __restrict__ beta, float* __restrict__ out)
{
    const int row = blockIdx.x;
    const int c0  = threadIdx.x * 4;
    ushortx4 xv = *(const ushortx4*)(X + (size_t)row * Hq + c0);
    float vals[4];
    float lsum = 0.0f;
    #pragma unroll
    for (int i = 0; i < 4; i++) { vals[i] = bf2f(xv[i]); lsum += vals[i]; }

    __shared__ float red[8];
    const int wid = threadIdx.x >> 6, lane = threadIdx.x & 63;

    float s = lsum;
    #pragma unroll
    for (int off = 32; off >= 1; off >>= 1) s += __shfl_xor(s, off, 64);
    if (lane == 0) red[wid] = s;
    __syncthreads();
    const float mean = (red[0] + red[1] + red[2] + red[3]) * (1.0f / Hq);

    float v = 0.0f;
    #pragma unroll
    for (int i = 0; i < 4; i++) { float d = vals[i] - mean; v += d * d; }
    #pragma unroll
    for (int off = 32; off >= 1; off >>= 1) v += __shfl_xor(v, off, 64);
    if (lane == 0) red[4 + wid] = v;
    __syncthreads();
    const float var  = (red[4] + red[5] + red[6] + red[7]) * (1.0f / Hq);
    const float rstd = rsqrtf(var + 1e-12f);

    float4 gm = *(const float4*)(gamma + c0);
    float4 bt = *(const float4*)(beta + c0);
    float4 o;
    o.x = (vals[0] - mean) * rstd * gm.x + bt.x;
    o.y = (vals[1] - mean) * rstd * gm.y + bt.y;
    o.z = (vals[2] - mean) * rstd * gm.z + bt.z;
    o.w = (vals[3] - mean) * rstd * gm.w + bt.w;
    *(float4*)(out + (size_t)row * Hq + c0) = o;
}

// ---------------------------------------------------------------------------
extern "C" void kernel_launch(void* const* d_in, const int* in_sizes, int n_in,
                              void* d_out, int out_size, void* d_ws, size_t ws_size,
                              hipStream_t stream)
{
    const float* hidden = (const float*)d_in[0];
    const float* mask   = (const float*)d_in[1];
    const float* W_qkv  = (const float*)d_in[2];
    const float* b_qkv  = (const float*)d_in[3];
    const float* W_out  = (const float*)d_in[4];
    const float* b_out  = (const float*)d_in[5];
    const float* gamma  = (const float*)d_in[6];
    const float* beta   = (const float*)d_in[7];
    float* out = (float*)d_out;

    const size_t nHid  = (size_t)Mq * Hq;        // 4 M
    const size_t nWq   = (size_t)H3q * Hq;       // 3 M
    const size_t nWo   = (size_t)Hq * Hq;        // 1 M
    const size_t nCtx  = (size_t)Mq * Hq;        // 4 M

    unsigned short* hidden_bf = (unsigned short*)d_ws;
    unsigned short* Wqkv_bf   = hidden_bf + nHid;
    unsigned short* Wout_bf   = Wqkv_bf + nWq;
    unsigned short* qb        = Wout_bf + nWo;          // Q  [4096][1024]
    unsigned short* kd        = qb + nHid;              // K  [4096][1024]
    unsigned short* v5        = kd + nHid;              // V' fragment-packed, 4 M
    unsigned short* ctx_bf    = v5 + nHid;
    unsigned short* x_bf      = ctx_bf + nCtx;
    unsigned short* opart     = x_bf + nHid;            // 2 * 4M bf16 = 16 MB
    float*          lpart     = (float*)(opart + 2 * nHid);  // 2*64K floats
    unsigned short* em2       = (unsigned short*)(lpart + 2 * (size_t)Mq * Nq);

    dim3 blk(256);

    // 0) fused fp32 -> bf16 cast + permuted expmask table (one kernel)
    cvt_all<<<dim3(CVT_BLKS + 2), blk, 0, stream>>>(
        hidden, W_qkv, W_out, mask, hidden_bf, em2);

    // 1) QKV projection (MFMA, 256x128 tile, depth-2) -> Qb / Kd / V5
    gemm_mfma_qkv<<<dim3(H3q / TN, Mq / G1M), dim3(512), 0, stream>>>(
        hidden_bf, Wqkv_bf, b_qkv, mask, qb, kd, v5, Hq);

    // 2) Pipelined flash attention (round-8 config) -> partial O/l
    attn_mfma<<<dim3(1024), blk, 0, stream>>>(
        qb, kd, v5, em2, opart, lpart);

    // 2b) merge halves -> ctx bf16
    attn_merge<<<dim3((int)(nCtx / 1024)), blk, 0, stream>>>(
        opart, lpart, ctx_bf);

    // 3) Output projection (MFMA, 64x128 tile, 512 blocks) + residual -> x bf16
    gemm_mfma_out<<<dim3(Hq / T2N, Mq / T2M), blk, 0, stream>>>(
        ctx_bf, Wout_bf, b_out, hidden, x_bf, Mq, Hq, Hq);

    // 4) LayerNorm: bf16 x -> fp32 out
    ln_kernel<<<dim3(Mq), blk, 0, stream>>>(x_bf, gamma, beta, out);
}

// Round 11
// 193.666 us; speedup vs baseline: 1.3028x; 1.0323x over previous
//
#include <hip/hip_runtime.h>
#include <hip/hip_bf16.h>
#include <math.h>

// Problem constants
#define Bq  2
#define Sq  2048
#define Hq  1024
#define Nq  16
#define HNq 64
#define Mq  (Bq*Sq)        // 4096 rows
#define H3q (3*Hq)         // 3072

#define LOG2E 1.44269504088896340736f

typedef __attribute__((ext_vector_type(8))) short           short8;
typedef __attribute__((ext_vector_type(4))) short           short4s;
typedef __attribute__((ext_vector_type(8))) unsigned short  ushortx8;
typedef __attribute__((ext_vector_type(4))) unsigned short  ushortx4;
typedef __attribute__((ext_vector_type(4))) float           floatx4;

__device__ __forceinline__ unsigned short f2bf(float f) {
    union { float f; unsigned int u; } x; x.f = f;
    unsigned int r = (x.u + 0x7fffu + ((x.u >> 16) & 1u)) >> 16;
    return (unsigned short)r;
}

// packed fp32x2 -> bf16x2 (v_cvt_pk_bf16_f32 on gfx950); a in low 16 bits
__device__ __forceinline__ unsigned int pkbf(float a, float b) {
    float2 t; t.x = a; t.y = b;
    __hip_bfloat162 h = __float22bfloat162_rn(t);
    union { __hip_bfloat162 h; unsigned int u; } c; c.h = h;
    return c.u;
}

__device__ __forceinline__ float bf2f(unsigned short v) {
    union { unsigned int u; float f; } x; x.u = (unsigned int)v << 16;
    return x.f;
}

// raw v_exp_f32 (D = 2^S0): ONE transcendental op (libm exp2f is a guarded
// ~10-op sequence without fast-math -- was the hidden VALU hog).
__device__ __forceinline__ float fexp2(float x) {
    float r;
    asm("v_exp_f32 %0, %1" : "=v"(r) : "v"(x));
    return r;
}

// async global->LDS, 16B per lane; LDS dest = wave-uniform base + lane*16
__device__ __forceinline__ void gload16(const unsigned short* g, unsigned short* l) {
    __builtin_amdgcn_global_load_lds(
        (__attribute__((address_space(1))) void*)(unsigned long long)(g),
        (__attribute__((address_space(3))) void*)(unsigned int)(unsigned long long)(l),
        16, 0, 0);
}

// LDS bank swizzle: granule' = granule ^ swz(row mod 16); 2-way max conflict
__device__ __forceinline__ int swz(int r) { return (r ^ (r >> 2)) & 3; }

// ---------------------------------------------------------------------------
// Fused fp32 -> bf16 cast for hidden | W_qkv | W_out + permuted e^mask table
// em2[((b*32+kt)*2+ks)*32 + quad*8 + hi*4 + r]
//   = exp(mask[b][kt*64 + (2ks+hi)*16 + quad*4 + r])
// ---------------------------------------------------------------------------
#define N_HID ((size_t)Mq * Hq)          // 4194304
#define N_HW  (N_HID + (size_t)H3q * Hq) // 7340032
#define N_ALL (N_HW + (size_t)Hq * Hq)   // 8388608
#define CVT_BLKS ((int)(N_ALL / 2048))   // 4096

__global__ __launch_bounds__(256) void cvt_all(
    const float* __restrict__ hidden, const float* __restrict__ wqkv,
    const float* __restrict__ wout, const float* __restrict__ mask,
    unsigned short* __restrict__ dst, unsigned short* __restrict__ em2)
{
    const int bid = blockIdx.x;
    if (bid >= CVT_BLKS) {
        // ---- permuted e^mask table (2 blocks, 4096 outputs)
        const int t0   = ((bid - CVT_BLKS) * 256 + threadIdx.x) * 8;
        const int b    = t0 >> 11;
        const int t2   = t0 & 2047;
        const int kt   = t2 >> 6;
        const int t3   = t2 & 63;
        const int ks   = t3 >> 5;
        const int quad = (t3 >> 3) & 3;
        const int kb   = kt * 64 + ks * 32 + quad * 4;
        const float* mp = mask + (size_t)b * Sq + kb;
        float4 m0 = *(const float4*)(mp);
        float4 m1 = *(const float4*)(mp + 16);
        union { unsigned int u[4]; ushortx8 s; } o;
        o.u[0] = pkbf(fexp2(m0.x * LOG2E), fexp2(m0.y * LOG2E));
        o.u[1] = pkbf(fexp2(m0.z * LOG2E), fexp2(m0.w * LOG2E));
        o.u[2] = pkbf(fexp2(m1.x * LOG2E), fexp2(m1.y * LOG2E));
        o.u[3] = pkbf(fexp2(m1.z * LOG2E), fexp2(m1.w * LOG2E));
        *(ushortx8*)(em2 + t0) = o.s;
        return;
    }
    size_t i = ((size_t)bid * 256 + threadIdx.x) * 8;
    const float* src;
    if (i < N_HID)      src = hidden + i;
    else if (i < N_HW)  src = wqkv + (i - N_HID);
    else                src = wout + (i - N_HW);
    float4 a = *(const float4*)(src);
    float4 b = *(const float4*)(src + 4);
    union { unsigned int u[4]; ushortx8 s; } o;
    o.u[0] = pkbf(a.x, a.y); o.u[1] = pkbf(a.z, a.w);
    o.u[2] = pkbf(b.x, b.y); o.u[3] = pkbf(b.z, b.w);
    *(ushortx8*)(dst + i) = o.s;
}

// ---------------------------------------------------------------------------
// GEMM1: 256x128 tile, BK=32, 8 waves (512 thr) each computing 64x64.
// Triple-buffered LDS, depth-2 prefetch, counted vmcnt(3).
// Outputs:
//   Qb [row][1024]  Q * 0.125*log2e (bf16), dense
//   KV5 INTERLEAVED packed tiles per (b,n): 32 tiles x 8192 shorts =
//     [K tile 4096 | V tile 4096]. K half is PRE-SWIZZLED
//     [r 64][((d>>3)^(r&7))*8 + (d&7)] (LDS image identical to the verified
//     XOR-source scheme); V half fragment-packed (e^mask folded). Attention
//     DMA for both is a LINEAR lane*16B copy of one contiguous 16KB tile,
//     and K/V lines are adjacent (no 8MB-stride L2 set-aliasing -- the
//     suspected round-9 regression cause).
// ---------------------------------------------------------------------------
#define TM 128
#define TN 128
#define TK 32
#define G1M 256

__global__ __launch_bounds__(512) void gemm_mfma_qkv(
    const unsigned short* __restrict__ A, const unsigned short* __restrict__ Bw,
    const float* __restrict__ bias, const float* __restrict__ mask,
    unsigned short* __restrict__ Qb, unsigned short* __restrict__ KV5, int K)
{
    __shared__ unsigned short As[3][G1M][TK];   // 48 KB
    __shared__ unsigned short Bs[3][TN][TK];    // 24 KB

    const int tid = threadIdx.x;
    const int w = tid >> 6, lane = tid & 63;
    const int l15 = lane & 15, quad = lane >> 4;
    const int wr = (w & 3) * 64;
    const int wc = (w >> 2) * 64;
    const int row0 = blockIdx.y * G1M;
    const int col0 = blockIdx.x * TN;

    const int srow16 = lane >> 2;
    const int sgd    = lane & 3;
    const int sgsrc  = (sgd ^ swz(srow16)) * 8;

    floatx4 acc[4][4];
    #pragma unroll
    for (int i = 0; i < 4; i++)
        #pragma unroll
        for (int j = 0; j < 4; j++) acc[i][j] = (floatx4){0.f,0.f,0.f,0.f};

    const int aswz = swz(l15) * 8;
    const int NK = K / TK;

    // prologue: stage tiles 0,1 (A: 2 segs/wave, B: 1 seg/wave)
    #pragma unroll
    for (int t = 0; t < 2; t++) {
        #pragma unroll
        for (int c = 0; c < 2; c++) {
            int seg = w * 2 + c;
            int r = seg * 16 + srow16;
            gload16(A + (size_t)(row0 + r) * K + t * TK + sgsrc, &As[t][seg * 16][0]);
        }
        int rB = w * 16 + srow16;
        gload16(Bw + (size_t)(col0 + rB) * K + t * TK + sgsrc, &Bs[t][w * 16][0]);
    }

    #pragma unroll 1
    for (int k = 0; k < NK; ++k) {
        if (k + 1 < NK) asm volatile("s_waitcnt vmcnt(3)" ::: "memory");
        else            asm volatile("s_waitcnt vmcnt(0)" ::: "memory");
        __builtin_amdgcn_s_barrier();
        __builtin_amdgcn_sched_barrier(0);

        const int cur = k % 3;
        if (k + 2 < NK) {                                  // prefetch tile k+2
            const int nb  = (k + 2) % 3;
            const int k0n = (k + 2) * TK;
            #pragma unroll
            for (int c = 0; c < 2; c++) {
                int seg = w * 2 + c;
                int r = seg * 16 + srow16;
                gload16(A + (size_t)(row0 + r) * K + k0n + sgsrc, &As[nb][seg * 16][0]);
            }
            int rB = w * 16 + srow16;
            gload16(Bw + (size_t)(col0 + rB) * K + k0n + sgsrc, &Bs[nb][w * 16][0]);
        }
        __builtin_amdgcn_sched_barrier(0);

        short8 af[4], bf[4];
        #pragma unroll
        for (int i = 0; i < 4; i++)
            af[i] = *(const short8*)&As[cur][wr + i * 16 + l15][(quad * 8) ^ aswz];
        #pragma unroll
        for (int j = 0; j < 4; j++)
            bf[j] = *(const short8*)&Bs[cur][wc + j * 16 + l15][(quad * 8) ^ aswz];
        __builtin_amdgcn_s_setprio(1);
        #pragma unroll
        for (int i = 0; i < 4; i++)
            #pragma unroll
            for (int j = 0; j < 4; j++)
                acc[i][j] = __builtin_amdgcn_mfma_f32_16x16x32_bf16(af[i], bf[j], acc[i][j], 0, 0, 0);
        __builtin_amdgcn_s_setprio(0);
    }

    const int cls = col0 >> 10;    // 0=Q, 1=K, 2=V; uniform per block

    if (cls == 2) {
        #pragma unroll
        for (int i = 0; i < 4; i++) {
            const int rb = row0 + wr + i * 16 + quad * 4;
            const int b  = rb >> 11;
            const int s  = rb & (Sq - 1);
            const int kt32 = s >> 6;
            const int sw   = s & 63;
            const int kg   = sw >> 2;          // s&3 == 0 (rb % 4 == 0)
            const int ks   = kg >> 3;
            const int q2   = kg & 3;
            const int hi   = (kg >> 2) & 1;
            float expm[4];
            #pragma unroll
            for (int rr = 0; rr < 4; rr++)
                expm[rr] = fexp2(mask[(size_t)b * Sq + s + rr] * LOG2E);
            #pragma unroll
            for (int j = 0; j < 4; j++) {
                const int c  = col0 + wc + j * 16 + l15;
                const int c2 = c - 2 * Hq;           // n*64+d
                const int n  = c2 >> 6, d = c2 & 63;
                const int dt = d >> 4, dl = d & 15;
                const float bia = bias[c];
                ushortx4 o;
                #pragma unroll
                for (int rr = 0; rr < 4; rr++)
                    o[rr] = f2bf((acc[i][j][rr] + bia) * expm[rr]);
                const size_t off = (((size_t)(b * Nq + n) * 32 + kt32) << 13) + 4096
                                 + (size_t)((ks * 16 + dt * 4 + q2) * 128 + dl * 8 + hi * 4);
                *(ushortx4*)&KV5[off] = o;
            }
        }
    } else if (cls == 1) {
        // K half, pre-swizzled rows (verified round-9 image)
        #pragma unroll
        for (int i = 0; i < 4; i++) {
            const int rb = row0 + wr + i * 16 + quad * 4;
            #pragma unroll
            for (int j = 0; j < 4; j++) {
                const int c  = col0 + wc + j * 16 + l15;
                const int c2 = c - Hq;               // n*64+d
                const int n  = c2 >> 6, d = c2 & 63;
                const float bia = bias[c];
                #pragma unroll
                for (int rr = 0; rr < 4; rr++) {
                    const int srow = rb + rr;
                    const int b    = srow >> 11;
                    const int s    = srow & (Sq - 1);
                    const int kt32 = s >> 6;
                    const int r    = s & 63;
                    const size_t off = (((size_t)(b * Nq + n) * 32 + kt32) << 13)
                                     + (size_t)(r * 64 + (((d >> 3) ^ (r & 7)) * 8 + (d & 7)));
                    KV5[off] = f2bf(acc[i][j][rr] + bia);
                }
            }
        }
    } else {
        const float qs = 0.125f * LOG2E;
        #pragma unroll
        for (int i = 0; i < 4; i++) {
            const int rb = row0 + wr + i * 16 + quad * 4;
            #pragma unroll
            for (int j = 0; j < 4; j++) {
                const int c = col0 + wc + j * 16 + l15;
                const float bia = bias[c];
                #pragma unroll
                for (int rr = 0; rr < 4; rr++)
                    Qb[(size_t)(rb + rr) * Hq + c] =
                        f2bf((acc[i][j][rr] + bia) * qs);
            }
        }
    }
}

// ---------------------------------------------------------------------------
// GEMM2: x = A*Bw^T + bias + residual -> bf16. 64x128 tile, 512 blocks
// (round-10 config, banked). Triple-buffered, depth-2, counted vmcnt(3).
// ---------------------------------------------------------------------------
#define T2M 64
#define T2N 128

__global__ __launch_bounds__(256) void gemm_mfma_out(
    const unsigned short* __restrict__ A, const unsigned short* __restrict__ Bw,
    const float* __restrict__ bias, const float* __restrict__ res,
    unsigned short* __restrict__ X, int M, int Nd, int K)
{
    __shared__ unsigned short As[3][T2M][TK];   // 12 KB
    __shared__ unsigned short Bs[3][T2N][TK];   // 24 KB

    const int tid = threadIdx.x;
    const int w = tid >> 6, lane = tid & 63;
    const int l15 = lane & 15, quad = lane >> 4;
    const int wr = (w & 1) * 32;
    const int wc = (w >> 1) * 64;
    const int row0 = blockIdx.y * T2M;
    const int col0 = blockIdx.x * T2N;

    const int srow16 = lane >> 2;
    const int sgd    = lane & 3;
    const int sgsrc  = (sgd ^ swz(srow16)) * 8;

    floatx4 acc[2][4];
    #pragma unroll
    for (int i = 0; i < 2; i++)
        #pragma unroll
        for (int j = 0; j < 4; j++) acc[i][j] = (floatx4){0.f,0.f,0.f,0.f};

    const int aswz = swz(l15) * 8;
    const int NK = K / TK;

    #pragma unroll
    for (int t = 0; t < 2; t++) {
        int rA = w * 16 + srow16;
        gload16(A + (size_t)(row0 + rA) * K + t * TK + sgsrc, &As[t][w * 16][0]);
        #pragma unroll
        for (int c = 0; c < 2; c++) {
            int seg = w * 2 + c;
            int rB = seg * 16 + srow16;
            gload16(Bw + (size_t)(col0 + rB) * K + t * TK + sgsrc, &Bs[t][seg * 16][0]);
        }
    }

    #pragma unroll 1
    for (int k = 0; k < NK; ++k) {
        if (k + 1 < NK) asm volatile("s_waitcnt vmcnt(3)" ::: "memory");
        else            asm volatile("s_waitcnt vmcnt(0)" ::: "memory");
        __builtin_amdgcn_s_barrier();
        __builtin_amdgcn_sched_barrier(0);

        const int cur = k % 3;
        if (k + 2 < NK) {
            const int nb  = (k + 2) % 3;
            const int k0n = (k + 2) * TK;
            int rA = w * 16 + srow16;
            gload16(A + (size_t)(row0 + rA) * K + k0n + sgsrc, &As[nb][w * 16][0]);
            #pragma unroll
            for (int c = 0; c < 2; c++) {
                int seg = w * 2 + c;
                int rB = seg * 16 + srow16;
                gload16(Bw + (size_t)(col0 + rB) * K + k0n + sgsrc, &Bs[nb][seg * 16][0]);
            }
        }
        __builtin_amdgcn_sched_barrier(0);

        short8 af[2], bf[4];
        #pragma unroll
        for (int i = 0; i < 2; i++)
            af[i] = *(const short8*)&As[cur][wr + i * 16 + l15][(quad * 8) ^ aswz];
        #pragma unroll
        for (int j = 0; j < 4; j++)
            bf[j] = *(const short8*)&Bs[cur][wc + j * 16 + l15][(quad * 8) ^ aswz];
        __builtin_amdgcn_s_setprio(1);
        #pragma unroll
        for (int i = 0; i < 2; i++)
            #pragma unroll
            for (int j = 0; j < 4; j++)
                acc[i][j] = __builtin_amdgcn_mfma_f32_16x16x32_bf16(af[i], bf[j], acc[i][j], 0, 0, 0);
        __builtin_amdgcn_s_setprio(0);
    }

    #pragma unroll
    for (int i = 0; i < 2; i++) {
        const int rb = row0 + wr + i * 16 + quad * 4;
        #pragma unroll
        for (int j = 0; j < 4; j++) {
            const int c = col0 + wc + j * 16 + l15;
            const float bia = bias[c];
            #pragma unroll
            for (int rr = 0; rr < 4; rr++) {
                X[(size_t)(rb + rr) * Nd + c] =
                    f2bf(acc[i][j][rr] + bia + res[(size_t)(rb + rr) * Nd + c]);
            }
        }
    }
}

// ---------------------------------------------------------------------------
// Full-K (z=1) MFMA flash attention, XCD-clustered, KV-interleaved tiles:
// 512 blocks x 32 tiles (was 1024 x 16): prologue/drain amortized 2x, the
// merge kernel is ELIMINATED (l is complete per block => normalize in the
// epilogue, write ctx directly: 8MB instead of 18.4MB partials), and both
// K and V DMAs are linear lane*16B copies of one contiguous 16KB tile
// (K scattered-row gather removed; K/V lines adjacent => no L2 set-alias).
// Risk accepted: block residency 4->2 per CU (occupancy counter will tell).
// ---------------------------------------------------------------------------
#define KTILES 32   // 64-key tiles, full sequence

__device__ __forceinline__ floatx4 mfma16(short8 a, short8 b, floatx4 c) {
    return __builtin_amdgcn_mfma_f32_16x16x32_bf16(a, b, c, 0, 0, 0);
}

// l-MFMA + PV for the PREVIOUS tile; V fragments read from LDS (Vt = tile
// base + lane*8, conflict-free b128 at stride 1024B)
__device__ __forceinline__ void do_lpv(
    const short8 (&pf0)[2], const short8 (&pf1)[2], const short8 (&mf)[2],
    const unsigned short* Vt,
    floatx4 (&oacc0)[4], floatx4 (&oacc1)[4],
    floatx4 &lacc0, floatx4 &lacc1)
{
    __builtin_amdgcn_s_setprio(1);
    lacc0 = mfma16(mf[0], pf0[0], lacc0);
    lacc0 = mfma16(mf[1], pf0[1], lacc0);
    lacc1 = mfma16(mf[0], pf1[0], lacc1);
    lacc1 = mfma16(mf[1], pf1[1], lacc1);
    #pragma unroll
    for (int dt = 0; dt < 4; dt++) {
        short8 vlo = *(const short8*)(Vt + dt * 512);
        short8 vhi = *(const short8*)(Vt + 2048 + dt * 512);
        oacc0[dt] = mfma16(vlo, pf0[0], oacc0[dt]);
        oacc1[dt] = mfma16(vlo, pf1[0], oacc1[dt]);
        oacc0[dt] = mfma16(vhi, pf0[1], oacc0[dt]);
        oacc1[dt] = mfma16(vhi, pf1[1], oacc1[dt]);
    }
    __builtin_amdgcn_s_setprio(0);
}

template<bool HAVER, bool PREF>
__device__ __forceinline__ void attn_body(
    int kt,
    unsigned short (&KsL)[2][64][64],
    unsigned short (&VsL)[3][4096],
    const unsigned short* KVb, const unsigned short* e2b,
    int w, int l15, int quad, int lane,
    const short8 (&qf0)[2], const short8 (&qf1)[2],
    const short8 (&pfR0)[2], const short8 (&pfR1)[2], const short8 (&mfR)[2],
    short8 (&pfW0)[2], short8 (&pfW1)[2], short8 (&mfW)[2],
    floatx4 (&oacc0)[4], floatx4 (&oacc1)[4],
    floatx4 &lacc0, floatx4 &lacc1)
{
    asm volatile("s_waitcnt vmcnt(0)" ::: "memory");   // K(kt),V(kt) landed
    __builtin_amdgcn_s_barrier();                      // all waves' DMAs landed
    __builtin_amdgcn_sched_barrier(0);

    if (PREF) {
        // KV(kt+1): linear lane copies of one contiguous 16KB tile
        const unsigned short* tb = KVb + (size_t)(kt + 1) * 8192 + w * 1024 + lane * 8;
        gload16(tb,        &KsL[(kt + 1) & 1][w * 16][0]);
        gload16(tb + 512,  &KsL[(kt + 1) & 1][w * 16 + 8][0]);
        unsigned short* vd = &VsL[(kt + 1) % 3][w * 1024];
        gload16(tb + 4096,       vd);
        gload16(tb + 4096 + 512, vd + 512);
    }
    __builtin_amdgcn_sched_barrier(0);   // pin DMAs as oldest outstanding

    // mf for THIS tile (consumed next body): direct loads, final order
    const unsigned short* ep = e2b + kt * 64;
    mfW[0] = *(const short8*)(ep + quad * 8);
    mfW[1] = *(const short8*)(ep + 32 + quad * 8);

    // ---- QK(kt): S^T = K Q^T for both subtiles
    floatx4 s0[4], s1[4];
    #pragma unroll
    for (int ct = 0; ct < 4; ct++) {
        s0[ct] = (floatx4){0.f,0.f,0.f,0.f};
        s1[ct] = (floatx4){0.f,0.f,0.f,0.f};
    }
    __builtin_amdgcn_s_setprio(1);
    #pragma unroll
    for (int ks = 0; ks < 2; ks++) {
        #pragma unroll
        for (int ct = 0; ct < 4; ct++) {
            short8 af = *(const short8*)&KsL[kt & 1][ct * 16 + l15][((4 * ks + quad) ^ (l15 & 7)) * 8];
            s0[ct] = mfma16(af, qf0[ks], s0[ct]);
            s1[ct] = mfma16(af, qf1[ks], s1[ct]);
        }
    }
    __builtin_amdgcn_s_setprio(0);

    // ---- softmax(kt) -> pfW (exp2-only via raw v_exp_f32; mask in V'/mf)
    #pragma unroll
    for (int ks = 0; ks < 2; ks++) {
        union { unsigned int u[4]; short8 s; } pk;
        #pragma unroll
        for (int h = 0; h < 2; h++) {
            const int ct = ks * 2 + h;
            pk.u[h * 2]     = pkbf(fexp2(s0[ct][0]), fexp2(s0[ct][1]));
            pk.u[h * 2 + 1] = pkbf(fexp2(s0[ct][2]), fexp2(s0[ct][3]));
        }
        pfW0[ks] = pk.s;
    }
    #pragma unroll
    for (int ks = 0; ks < 2; ks++) {
        union { unsigned int u[4]; short8 s; } pk;
        #pragma unroll
        for (int h = 0; h < 2; h++) {
            const int ct = ks * 2 + h;
            pk.u[h * 2]     = pkbf(fexp2(s1[ct][0]), fexp2(s1[ct][1]));
            pk.u[h * 2 + 1] = pkbf(fexp2(s1[ct][2]), fexp2(s1[ct][3]));
        }
        pfW1[ks] = pk.s;
    }

    // ---- l + PV for tile kt-1 from LDS (overlaps the exp2 chain above)
    if (HAVER)
        do_lpv(pfR0, pfR1, mfR, &VsL[(kt - 1) % 3][0] + lane * 8,
               oacc0, oacc1, lacc0, lacc1);
}

__global__ __launch_bounds__(256) void attn_mfma(
    const unsigned short* __restrict__ Qb, const unsigned short* __restrict__ KV5,
    const unsigned short* __restrict__ em2, unsigned short* __restrict__ ctx)
{
    __shared__ unsigned short Ks[2][64][64];   // 16 KB [buf][key][d], swizzled image
    __shared__ unsigned short Vs[3][4096];     // 24 KB fragment-packed V tiles

    const int tid  = threadIdx.x;
    const int w    = tid >> 6;
    const int lane = tid & 63;
    const int l15  = lane & 15;
    const int quad = lane >> 4;

    // XCD-clustering decode: all 16 qtiles of group g=bn share K/V and land
    // on XCD g%8 (dispatch round-robins linear id across 8 XCDs). 512 blocks.
    const int i_    = blockIdx.x;
    const int gl8   = i_ & 7;
    const int rest  = i_ >> 3;
    const int qtile = rest & 15;               // 0..15 (128 queries each)
    const int g     = (rest >> 4) * 8 + gl8;   // 0..31 = bn
    const int n     = g & 15;
    const int b     = g >> 4;

    // Q B-fragments for both subtiles (n=l15 -> query row, k=quad*8+j)
    short8 qf0[2], qf1[2];
    {
        const int qrow0 = qtile * 128 + w * 16 + l15;
        const unsigned short* qp = Qb + (size_t)(b * Sq + qrow0) * Hq + n * HNq + quad * 8;
        qf0[0] = *(const short8*)(qp);
        qf0[1] = *(const short8*)(qp + 32);
        qp += (size_t)64 * Hq;
        qf1[0] = *(const short8*)(qp);
        qf1[1] = *(const short8*)(qp + 32);
    }

    floatx4 oacc0[4], oacc1[4];   // O^T per subtile: d = dt*16+quad*4+r, q=l15
    #pragma unroll
    for (int dt = 0; dt < 4; dt++) {
        oacc0[dt] = (floatx4){0.f,0.f,0.f,0.f};
        oacc1[dt] = (floatx4){0.f,0.f,0.f,0.f};
    }
    floatx4 lacc0 = (floatx4){0.f,0.f,0.f,0.f};
    floatx4 lacc1 = (floatx4){0.f,0.f,0.f,0.f};

    // interleaved KV tile base + permuted mask base
    const unsigned short* KVb = KV5 + (size_t)(b * Nq + n) * 32 * 8192;
    const unsigned short* e2b = em2 + (size_t)b * 32 * 64;

    // prologue: KV(0) -> Ks[0] / Vs[0] (linear lane copies)
    {
        const unsigned short* tb = KVb + w * 1024 + lane * 8;
        gload16(tb,        &Ks[0][w * 16][0]);
        gload16(tb + 512,  &Ks[0][w * 16 + 8][0]);
        gload16(tb + 4096,       &Vs[0][w * 1024]);
        gload16(tb + 4096 + 512, &Vs[0][w * 1024] + 512);
    }

    // pipeline state (two named stages, no dynamic indexing)
    short8 pfA0[2], pfA1[2], mfA[2];
    short8 pfB0[2], pfB1[2], mfB[2];

    // peel kt=0: fills stage A; no PV yet
    attn_body<false, true>(0, Ks, Vs, KVb, e2b, w, l15, quad, lane,
        qf0, qf1, pfB0, pfB1, mfB, pfA0, pfA1, mfA, oacc0, oacc1, lacc0, lacc1);

    #pragma unroll 1
    for (int kt = 1; kt < KTILES - 1; kt += 2) {
        attn_body<true, true>(kt, Ks, Vs, KVb, e2b, w, l15, quad, lane,
            qf0, qf1, pfA0, pfA1, mfA, pfB0, pfB1, mfB, oacc0, oacc1, lacc0, lacc1);
        attn_body<true, true>(kt + 1, Ks, Vs, KVb, e2b, w, l15, quad, lane,
            qf0, qf1, pfB0, pfB1, mfB, pfA0, pfA1, mfA, oacc0, oacc1, lacc0, lacc1);
    }
    // kt = 31 (odd): reads A, writes B, no prefetch
    attn_body<true, false>(KTILES - 1, Ks, Vs, KVb, e2b, w, l15, quad, lane,
        qf0, qf1, pfA0, pfA1, mfA, pfB0, pfB1, mfB, oacc0, oacc1, lacc0, lacc1);
    // drain: l + PV of tile 31 (stage B, V(31) in Vs[31%3 = 1])
    do_lpv(pfB0, pfB1, mfB, &Vs[(KTILES - 1) % 3][0] + lane * 8,
           oacc0, oacc1, lacc0, lacc1);

    // ---- epilogue: l is COMPLETE (z=1) -> normalize in fp32, write ctx
    // directly (no partials, no merge kernel). Every row of lacc holds l_q.
    #pragma unroll
    for (int sub = 0; sub < 2; sub++) {
        const float inv = 1.0f / (sub ? lacc1[0] : lacc0[0]);
        const int qrow = qtile * 128 + sub * 64 + w * 16 + l15;
        #pragma unroll
        for (int dt = 0; dt < 4; dt++) {
            const floatx4 oa = sub ? oacc1[dt] : oacc0[dt];
            union { unsigned int u[2]; ushortx4 s; } o;
            o.u[0] = pkbf(oa[0] * inv, oa[1] * inv);
            o.u[1] = pkbf(oa[2] * inv, oa[3] * inv);
            const int col = n * HNq + dt * 16 + quad * 4;
            *(ushortx4*)&ctx[(size_t)(b * Sq + qrow) * Hq + col] = o.s;
        }
    }
}

// ---------------------------------------------------------------------------
// Row LayerNorm over H=1024, bf16 input, fp32 stats, fp32 output.
// ---------------------------------------------------------------------------
__global__ __launch_bounds__(256) void ln_kernel(
    const unsigned short* __restrict__ X, const float* __restrict__ gamma,
    const float* __restrict__ beta, float* __restrict__ out)
{
    const int row = blockIdx.x;
    const int c0  = threadIdx.x * 4;
    ushortx4 xv = *(const ushortx4*)(X + (size_t)row * Hq + c0);
    float vals[4];
    float lsum = 0.0f;
    #pragma unroll
    for (int i = 0; i < 4; i++) { vals[i] = bf2f(xv[i]); lsum += vals[i]; }

    __shared__ float red[8];
    const int wid = threadIdx.x >> 6, lane = threadIdx.x & 63;

    float s = lsum;
    #pragma unroll
    for (int off = 32; off >= 1; off >>= 1) s += __shfl_xor(s, off, 64);
    if (lane == 0) red[wid] = s;
    __syncthreads();
    const float mean = (red[0] + red[1] + red[2] + red[3]) * (1.0f / Hq);

    float v = 0.0f;
    #pragma unroll
    for (int i = 0; i < 4; i++) { float d = vals[i] - mean; v += d * d; }
    #pragma unroll
    for (int off = 32; off >= 1; off >>= 1) v += __shfl_xor(v, off, 64);
    if (lane == 0) red[4 + wid] = v;
    __syncthreads();
    const float var  = (red[4] + red[5] + red[6] + red[7]) * (1.0f / Hq);
    const float rstd = rsqrtf(var + 1e-12f);

    float4 gm = *(const float4*)(gamma + c0);
    float4 bt = *(const float4*)(beta + c0);
    float4 o;
    o.x = (vals[0] - mean) * rstd * gm.x + bt.x;
    o.y = (vals[1] - mean) * rstd * gm.y + bt.y;
    o.z = (vals[2] - mean) * rstd * gm.z + bt.z;
    o.w = (vals[3] - mean) * rstd * gm.w + bt.w;
    *(float4*)(out + (size_t)row * Hq + c0) = o;
}

// ---------------------------------------------------------------------------
// Workspace (56 MB): hidden_bf | Wqkv_bf | Wout_bf | Qb | KV5(8M) | ctx |
// x_bf | em2. Five kernels (merge eliminated).
// ---------------------------------------------------------------------------
extern "C" void kernel_launch(void* const* d_in, const int* in_sizes, int n_in,
                              void* d_out, int out_size, void* d_ws, size_t ws_size,
                              hipStream_t stream)
{
    const float* hidden = (const float*)d_in[0];
    const float* mask   = (const float*)d_in[1];
    const float* W_qkv  = (const float*)d_in[2];
    const float* b_qkv  = (const float*)d_in[3];
    const float* W_out  = (const float*)d_in[4];
    const float* b_out  = (const float*)d_in[5];
    const float* gamma  = (const float*)d_in[6];
    const float* beta   = (const float*)d_in[7];
    float* out = (float*)d_out;

    const size_t nHid  = (size_t)Mq * Hq;        // 4 M
    const size_t nWq   = (size_t)H3q * Hq;       // 3 M
    const size_t nWo   = (size_t)Hq * Hq;        // 1 M

    unsigned short* hidden_bf = (unsigned short*)d_ws;
    unsigned short* Wqkv_bf   = hidden_bf + nHid;
    unsigned short* Wout_bf   = Wqkv_bf + nWq;
    unsigned short* qb        = Wout_bf + nWo;          // Q  [4096][1024]
    unsigned short* kv5       = qb + nHid;              // interleaved K|V, 8 M
    unsigned short* ctx_bf    = kv5 + 2 * nHid;
    unsigned short* x_bf      = ctx_bf + nHid;
    unsigned short* em2       = x_bf + nHid;            // 8 KB

    dim3 blk(256);

    // 0) fused fp32 -> bf16 cast + permuted expmask table (one kernel)
    cvt_all<<<dim3(CVT_BLKS + 2), blk, 0, stream>>>(
        hidden, W_qkv, W_out, mask, hidden_bf, em2);

    // 1) QKV projection (MFMA, 256x128 tile, depth-2) -> Qb / KV5
    gemm_mfma_qkv<<<dim3(H3q / TN, Mq / G1M), dim3(512), 0, stream>>>(
        hidden_bf, Wqkv_bf, b_qkv, mask, qb, kv5, Hq);

    // 2) Full-K flash attention (z=1, KV-interleaved) -> normalized ctx
    attn_mfma<<<dim3(512), blk, 0, stream>>>(
        qb, kv5, em2, ctx_bf);

    // 3) Output projection (MFMA, 64x128 tile, 512 blocks) + residual -> x bf16
    gemm_mfma_out<<<dim3(Hq / T2N, Mq / T2M), blk, 0, stream>>>(
        ctx_bf, Wout_bf, b_out, hidden, x_bf, Mq, Hq, Hq);

    // 4) LayerNorm: bf16 x -> fp32 out
    ln_kernel<<<dim3(Mq), blk, 0, stream>>>(x_bf, gamma, beta, out);
}